// Round 1
// baseline (1740.084 us; speedup 1.0000x reference)
//
#include <hip/hip_runtime.h>
#include <cstddef>

// Problem constants
#define BB    2
#define CC    256
#define HH    128
#define WW    128
#define NN    (HH*WW)          // 16384
#define NHh   8
#define HDd   32
#define NPp   4
#define FFNN  512
#define Mtot  (BB*NN)          // 32768

// ---------------- GEMM: C[M,Nc] = A[M,K] @ W[K,Nc] (+bias) with epilogues ----
// ALOAD: 0 = row-major A[m*K+k]
//        1 = bev-transposed: A[(b*K + k)*NN + sp], m = b*NN+sp
//        2 = implicit conv: K = 9*512, k=(tap*512+ci); A from cam_att/sat_att
// EPI:   0 none, 1 relu, 2 bn+relu, 3 sigmoid-gate, 4 add-residual
#define EPI_NONE    0
#define EPI_RELU    1
#define EPI_BNRELU  2
#define EPI_SIGGATE 3
#define EPI_ADDRES  4

#define Bb_M 64
#define Bb_N 64
#define Bb_K 16

template<int ALOAD, int EPI>
__global__ __launch_bounds__(256)
void gemm_k(const float* __restrict__ A, const float* __restrict__ W,
            const float* __restrict__ bias, float* __restrict__ out,
            int M, int K, int Nc,
            const float* __restrict__ pA0, const float* __restrict__ pA1,
            const float* __restrict__ pE0, const float* __restrict__ pE1)
{
    __shared__ __align__(16) float As[Bb_K][Bb_M + 4];
    __shared__ __align__(16) float Bs[Bb_K][Bb_N + 4];

    const int m0 = blockIdx.y * Bb_M;
    const int n0 = blockIdx.x * Bb_N;
    const int tid = threadIdx.x;
    const int tx = tid & 15, ty = tid >> 4;

    float acc[4][4] = {};

    for (int k0 = 0; k0 < K; k0 += Bb_K) {
        // ---- load B tile (16 x 64), contiguous along n ----
        {
            int kl = tid >> 4;            // 0..15
            int nl = (tid & 15) * 4;      // 0..60
            int n  = n0 + nl;
            float4 bv;
            if (n + 3 < Nc) {
                bv = *(const float4*)&W[(size_t)(k0 + kl) * Nc + n];
            } else {
                float t0 = (n + 0 < Nc) ? W[(size_t)(k0 + kl) * Nc + n + 0] : 0.f;
                float t1 = (n + 1 < Nc) ? W[(size_t)(k0 + kl) * Nc + n + 1] : 0.f;
                float t2 = (n + 2 < Nc) ? W[(size_t)(k0 + kl) * Nc + n + 2] : 0.f;
                float t3 = (n + 3 < Nc) ? W[(size_t)(k0 + kl) * Nc + n + 3] : 0.f;
                bv = make_float4(t0, t1, t2, t3);
            }
            *(float4*)&Bs[kl][nl] = bv;
        }
        // ---- load A tile (64 x 16) ----
        if constexpr (ALOAD == 1) {
            // bev layout (B, C, N): contiguous along m (spatial)
            int kl = tid >> 4;            // 0..15
            int ml = (tid & 15) * 4;      // 0..60
            int m  = m0 + ml;
            int b  = m >> 14, sp = m & (NN - 1);
            float4 av = *(const float4*)&A[((size_t)(b * K + k0 + kl)) * NN + sp];
            *(float4*)&As[kl][ml] = av;
        } else if constexpr (ALOAD == 0) {
            int ml = tid >> 2;            // 0..63
            int kq = (tid & 3) * 4;       // 0,4,8,12
            float4 av = *(const float4*)&A[(size_t)(m0 + ml) * K + k0 + kq];
            As[kq + 0][ml] = av.x; As[kq + 1][ml] = av.y;
            As[kq + 2][ml] = av.z; As[kq + 3][ml] = av.w;
        } else {
            // conv: k = tap*512 + ci ; ci<256 -> cam_att ; else sat_att
            int ml = tid >> 2;
            int kq = (tid & 3) * 4;
            int m  = m0 + ml;
            int b  = m >> 14, sp = m & (NN - 1);
            int y  = sp >> 7, x = sp & 127;
            int k  = k0 + kq;
            int tap = k >> 9;
            int ci  = k & 511;
            int yy = y + (tap / 3) - 1;
            int xx = x + (tap % 3) - 1;
            bool valid = (yy >= 0 && yy < HH && xx >= 0 && xx < WW);
            const float* src = (ci < 256) ? pA0 : pA1;
            int c8 = ci & 255;
            float4 av = make_float4(0.f, 0.f, 0.f, 0.f);
            if (valid)
                av = *(const float4*)&src[((size_t)(b * NN + yy * WW + xx)) * CC + c8];
            As[kq + 0][ml] = av.x; As[kq + 1][ml] = av.y;
            As[kq + 2][ml] = av.z; As[kq + 3][ml] = av.w;
        }
        __syncthreads();

        #pragma unroll
        for (int kk = 0; kk < Bb_K; ++kk) {
            float av[4], bv[4];
            *(float4*)av = *(const float4*)&As[kk][ty * 4];
            *(float4*)bv = *(const float4*)&Bs[kk][tx * 4];
            #pragma unroll
            for (int i = 0; i < 4; ++i)
                #pragma unroll
                for (int j = 0; j < 4; ++j)
                    acc[i][j] += av[i] * bv[j];
        }
        __syncthreads();
    }

    // ---- epilogue ----
    const float bnscale = rsqrtf(1.0f + 1e-5f);
    const int mbase = m0 + ty * 4;
    const int nbase = n0 + tx * 4;
    #pragma unroll
    for (int i = 0; i < 4; ++i) {
        int m = mbase + i;
        #pragma unroll
        for (int j = 0; j < 4; ++j) {
            int n = nbase + j;
            if (n >= Nc) continue;
            float v = acc[i][j];
            if (bias) v += bias[n];
            size_t oi = (size_t)m * Nc + n;
            if constexpr (EPI == EPI_NONE) {
                out[oi] = v;
            } else if constexpr (EPI == EPI_RELU) {
                out[oi] = fmaxf(v, 0.f);
            } else if constexpr (EPI == EPI_BNRELU) {
                out[oi] = fmaxf(v * bnscale * pE0[n] + pE1[n], 0.f);
            } else if constexpr (EPI == EPI_SIGGATE) {
                float gv = 1.f / (1.f + expf(-v));
                size_t ai = (size_t)m * CC + n;
                out[oi] = gv * pE0[ai] + (1.f - gv) * pE1[ai];
            } else if constexpr (EPI == EPI_ADDRES) {
                out[oi] = v + pE0[oi];
            }
        }
    }
}

// ---------------- deformable sampling (softmax over NP fused) ----------------
// thread t -> d = t&31, h = (t>>5)&7, row = t>>8 (= b*N+n)
__global__ __launch_bounds__(256)
void sample_k(const float* __restrict__ val, const float* __restrict__ off,
              const float* __restrict__ lg, float* __restrict__ out)
{
    int t = blockIdx.x * 256 + threadIdx.x;
    int d = t & 31;
    int h = (t >> 5) & 7;
    int rn = t >> 8;               // b*N + n
    int n = rn & (NN - 1);
    int b = rn >> 14;
    int ypix = n >> 7, xpix = n & 127;

    const float* ofp = off + (size_t)rn * (NHh * NPp * 2) + h * (NPp * 2);
    const float* lgp = lg + (size_t)rn * (NHh * NPp) + h * NPp;

    float l0 = lgp[0], l1 = lgp[1], l2 = lgp[2], l3 = lgp[3];
    float mx = fmaxf(fmaxf(l0, l1), fmaxf(l2, l3));
    float e0 = expf(l0 - mx), e1 = expf(l1 - mx), e2 = expf(l2 - mx), e3 = expf(l3 - mx);
    float inv = 1.f / (e0 + e1 + e2 + e3);
    float aw[4] = { e0 * inv, e1 * inv, e2 * inv, e3 * inv };

    const float* vb = val + (size_t)b * NN * CC + h * HDd + d;
    float acc = 0.f;
    #pragma unroll
    for (int p = 0; p < NPp; ++p) {
        float xs = (float)xpix + ofp[p * 2 + 0];
        float ys = (float)ypix + ofp[p * 2 + 1];
        float x0f = floorf(xs), y0f = floorf(ys);
        float lx = xs - x0f, ly = ys - y0f;
        int x0 = (int)x0f, y0 = (int)y0f;
        float sv = 0.f;
        {
            int xi = x0, yi = y0; float w = (1.f - lx) * (1.f - ly);
            if (xi >= 0 && xi < WW && yi >= 0 && yi < HH) sv += w * vb[(size_t)(yi * WW + xi) * CC];
        }
        {
            int xi = x0 + 1, yi = y0; float w = lx * (1.f - ly);
            if (xi >= 0 && xi < WW && yi >= 0 && yi < HH) sv += w * vb[(size_t)(yi * WW + xi) * CC];
        }
        {
            int xi = x0, yi = y0 + 1; float w = (1.f - lx) * ly;
            if (xi >= 0 && xi < WW && yi >= 0 && yi < HH) sv += w * vb[(size_t)(yi * WW + xi) * CC];
        }
        {
            int xi = x0 + 1, yi = y0 + 1; float w = lx * ly;
            if (xi >= 0 && xi < WW && yi >= 0 && yi < HH) sv += w * vb[(size_t)(yi * WW + xi) * CC];
        }
        acc += aw[p] * sv;
    }
    out[(size_t)rn * CC + h * HDd + d] = acc;
}

// ---------------- LayerNorm kernels ----------------
__device__ __forceinline__ void blk_reduce2(float& s, float& s2, float* sA, float* sB)
{
    #pragma unroll
    for (int o = 1; o < 64; o <<= 1) {
        s  += __shfl_xor(s,  o, 64);
        s2 += __shfl_xor(s2, o, 64);
    }
    int wid = threadIdx.x >> 6;
    if ((threadIdx.x & 63) == 0) { sA[wid] = s; sB[wid] = s2; }
    __syncthreads();
    s  = sA[0] + sA[1] + sA[2] + sA[3];
    s2 = sB[0] + sB[1] + sB[2] + sB[3];
}

// in-place: x[row] = LN(x[row] + bevT[row]) * g + b
__global__ __launch_bounds__(256)
void ln_res_bev_k(float* __restrict__ x, const float* __restrict__ bev,
                  const float* __restrict__ g, const float* __restrict__ bb)
{
    __shared__ float sA[4], sB[4];
    int row = blockIdx.x;
    int c = threadIdx.x;
    int b = row >> 14, sp = row & (NN - 1);
    float v = x[(size_t)row * CC + c] + bev[((size_t)b * CC + c) * NN + sp];
    float s = v, s2 = v * v;
    blk_reduce2(s, s2, sA, sB);
    float mean = s * (1.f / CC);
    float var  = s2 * (1.f / CC) - mean * mean;
    float r = rsqrtf(var + 1e-5f);
    x[(size_t)row * CC + c] = (v - mean) * r * g[c] + bb[c];
}

// out (B,C,N) = LN(t[row]) * g + b + cam_bev
__global__ __launch_bounds__(256)
void ln_final_k(const float* __restrict__ t, const float* __restrict__ cam,
                const float* __restrict__ g, const float* __restrict__ bb,
                float* __restrict__ out)
{
    __shared__ float sA[4], sB[4];
    int row = blockIdx.x;
    int c = threadIdx.x;
    int b = row >> 14, sp = row & (NN - 1);
    float v = t[(size_t)row * CC + c];
    float s = v, s2 = v * v;
    blk_reduce2(s, s2, sA, sB);
    float mean = s * (1.f / CC);
    float var  = s2 * (1.f / CC) - mean * mean;
    float r = rsqrtf(var + 1e-5f);
    size_t oi = ((size_t)b * CC + c) * NN + sp;
    out[oi] = (v - mean) * r * g[c] + bb[c] + cam[oi];
}

// ---------------- weight repacks ----------------
__global__ void repack_conv_w(const float* __restrict__ g1, float* __restrict__ w2)
{
    int i = blockIdx.x * 256 + threadIdx.x;    // over 4608*128
    if (i >= 4608 * 128) return;
    int co = i & 127;
    int k  = i >> 7;
    int tap = k >> 9;
    int ci  = k & 511;
    w2[i] = g1[(size_t)(co * 512 + ci) * 9 + tap];
}
__global__ void repack_g2(const float* __restrict__ g2w, float* __restrict__ g2t)
{
    int i = blockIdx.x * 256 + threadIdx.x;    // over 128*256
    if (i >= 128 * 256) return;
    int o = i & 255;
    int k = i >> 8;
    g2t[i] = g2w[(size_t)o * 128 + k];
}

// ---------------- launch ----------------
extern "C" void kernel_launch(void* const* d_in, const int* in_sizes, int n_in,
                              void* d_out, int out_size, void* d_ws, size_t ws_size,
                              hipStream_t stream)
{
    const float* cam_bev  = (const float*)d_in[0];
    const float* sat_bev  = (const float*)d_in[1];
    const float* c2s_off_w  = (const float*)d_in[2];
    const float* c2s_off_b  = (const float*)d_in[3];
    const float* c2s_attw_w = (const float*)d_in[4];
    const float* c2s_attw_b = (const float*)d_in[5];
    const float* c2s_vp_w   = (const float*)d_in[6];
    const float* c2s_vp_b   = (const float*)d_in[7];
    const float* c2s_op_w   = (const float*)d_in[8];
    const float* c2s_op_b   = (const float*)d_in[9];
    const float* s2c_off_w  = (const float*)d_in[10];
    const float* s2c_off_b  = (const float*)d_in[11];
    const float* s2c_attw_w = (const float*)d_in[12];
    const float* s2c_attw_b = (const float*)d_in[13];
    const float* s2c_vp_w   = (const float*)d_in[14];
    const float* s2c_vp_b   = (const float*)d_in[15];
    const float* s2c_op_w   = (const float*)d_in[16];
    const float* s2c_op_b   = (const float*)d_in[17];
    const float* ln1_g = (const float*)d_in[18];
    const float* ln1_b = (const float*)d_in[19];
    const float* ln2_g = (const float*)d_in[20];
    const float* ln2_b = (const float*)d_in[21];
    const float* lnf_g = (const float*)d_in[22];
    const float* lnf_b = (const float*)d_in[23];
    const float* ffn1_w = (const float*)d_in[24];
    const float* ffn1_b = (const float*)d_in[25];
    const float* ffn2_w = (const float*)d_in[26];
    const float* ffn2_b = (const float*)d_in[27];
    const float* g1_w  = (const float*)d_in[28];
    const float* bn_g  = (const float*)d_in[29];
    const float* bn_b  = (const float*)d_in[30];
    const float* g2_w  = (const float*)d_in[31];
    const float* g2_b  = (const float*)d_in[32];

    float* ws = (float*)d_ws;
    size_t woff = 0;
    auto alloc = [&](size_t nfl) { float* p = ws + woff; woff += nfl; return p; };

    float* val     = alloc((size_t)Mtot * CC);       //  33.5 MB
    float* samp    = alloc((size_t)Mtot * CC);       //  33.5 MB
    float* cam_att = alloc((size_t)Mtot * CC);       //  33.5 MB
    float* sat_att = alloc((size_t)Mtot * CC);       //  33.5 MB
    float* offb    = alloc((size_t)Mtot * 64);       //   8.4 MB
    float* attwb   = alloc((size_t)Mtot * 32);       //   4.2 MB
    float* hbuf    = alloc((size_t)Mtot * 128);      //  16.8 MB
    float* mid     = alloc((size_t)Mtot * FFNN);     //  67.1 MB
    float* w2      = alloc((size_t)4608 * 128);      //   2.4 MB
    float* g2t     = alloc((size_t)128 * 256);       //   0.1 MB
    float* fused   = samp;   // samp dead after op-projection
    float* tbuf    = val;    // val dead after both attentions

    dim3 blk(256);

    repack_conv_w<<<(4608 * 128 + 255) / 256, blk, 0, stream>>>(g1_w, w2);
    repack_g2<<<(128 * 256 + 255) / 256, blk, 0, stream>>>(g2_w, g2t);

    // ---------- c2s deformable attention (q=cam, kv=sat) ----------
    gemm_k<1, EPI_NONE><<<dim3(4, 512), blk, 0, stream>>>(
        sat_bev, c2s_vp_w, c2s_vp_b, val, Mtot, 256, 256, nullptr, nullptr, nullptr, nullptr);
    gemm_k<1, EPI_NONE><<<dim3(1, 512), blk, 0, stream>>>(
        cam_bev, c2s_off_w, c2s_off_b, offb, Mtot, 256, 64, nullptr, nullptr, nullptr, nullptr);
    gemm_k<1, EPI_NONE><<<dim3(1, 512), blk, 0, stream>>>(
        cam_bev, c2s_attw_w, c2s_attw_b, attwb, Mtot, 256, 32, nullptr, nullptr, nullptr, nullptr);
    sample_k<<<(Mtot * 256) / 256, blk, 0, stream>>>(val, offb, attwb, samp);
    gemm_k<0, EPI_NONE><<<dim3(4, 512), blk, 0, stream>>>(
        samp, c2s_op_w, c2s_op_b, cam_att, Mtot, 256, 256, nullptr, nullptr, nullptr, nullptr);
    ln_res_bev_k<<<Mtot, blk, 0, stream>>>(cam_att, cam_bev, ln1_g, ln1_b);

    // ---------- s2c deformable attention (q=sat, kv=cam) ----------
    gemm_k<1, EPI_NONE><<<dim3(4, 512), blk, 0, stream>>>(
        cam_bev, s2c_vp_w, s2c_vp_b, val, Mtot, 256, 256, nullptr, nullptr, nullptr, nullptr);
    gemm_k<1, EPI_NONE><<<dim3(1, 512), blk, 0, stream>>>(
        sat_bev, s2c_off_w, s2c_off_b, offb, Mtot, 256, 64, nullptr, nullptr, nullptr, nullptr);
    gemm_k<1, EPI_NONE><<<dim3(1, 512), blk, 0, stream>>>(
        sat_bev, s2c_attw_w, s2c_attw_b, attwb, Mtot, 256, 32, nullptr, nullptr, nullptr, nullptr);
    sample_k<<<(Mtot * 256) / 256, blk, 0, stream>>>(val, offb, attwb, samp);
    gemm_k<0, EPI_NONE><<<dim3(4, 512), blk, 0, stream>>>(
        samp, s2c_op_w, s2c_op_b, sat_att, Mtot, 256, 256, nullptr, nullptr, nullptr, nullptr);
    ln_res_bev_k<<<Mtot, blk, 0, stream>>>(sat_att, sat_bev, ln2_g, ln2_b);

    // ---------- gating conv (implicit GEMM, K = 9*512) + BN + ReLU ----------
    gemm_k<2, EPI_BNRELU><<<dim3(2, 512), blk, 0, stream>>>(
        nullptr, w2, nullptr, hbuf, Mtot, 9 * 512, 128, cam_att, sat_att, bn_g, bn_b);

    // ---------- 1x1 conv + sigmoid + gated fusion ----------
    gemm_k<0, EPI_SIGGATE><<<dim3(4, 512), blk, 0, stream>>>(
        hbuf, g2t, g2_b, fused, Mtot, 128, 256, nullptr, nullptr, cam_att, sat_att);

    // ---------- FFN ----------
    gemm_k<0, EPI_RELU><<<dim3(8, 512), blk, 0, stream>>>(
        fused, ffn1_w, ffn1_b, mid, Mtot, 256, 512, nullptr, nullptr, nullptr, nullptr);
    gemm_k<0, EPI_ADDRES><<<dim3(4, 512), blk, 0, stream>>>(
        mid, ffn2_w, ffn2_b, tbuf, Mtot, 512, 256, nullptr, nullptr, fused, nullptr);

    // ---------- final LN + residual, transpose back to (B,C,H,W) ----------
    ln_final_k<<<Mtot, blk, 0, stream>>>(tbuf, cam_bev, lnf_g, lnf_b, (float*)d_out);
}

// Round 2
// 647.899 us; speedup vs baseline: 2.6857x; 2.6857x over previous
//
#include <hip/hip_runtime.h>
#include <hip/hip_bf16.h>
#include <cstddef>

#define BBn  2
#define CCn  256
#define HHn  128
#define WWn  128
#define NNn  (HHn*WWn)        // 16384
#define MTOT (BBn*NNn)        // 32768
#define PADW 130

typedef unsigned short u16;
typedef __attribute__((ext_vector_type(8))) short bf8v;
typedef __attribute__((ext_vector_type(4))) float f4v;

typedef __attribute__((address_space(1))) const void gvoid_t;
typedef __attribute__((address_space(3))) void svoid_t;
#define ASYNC16(g, l) __builtin_amdgcn_global_load_lds((gvoid_t*)(g), (svoid_t*)(l), 16, 0, 0)

__device__ __forceinline__ u16 f2bf(float f) {
    __hip_bfloat16 h = __float2bfloat16(f);
    return *reinterpret_cast<u16*>(&h);
}

// ---------------------------------------------------------------------------
// bf16 MFMA GEMM: out[M,Nc] = A[M,K](bf16) @ Wt[Nc,K](bf16, pre-transposed)
// tile BM x 128, BK=32, 4 waves (2x2), wave = (BM/2) x 64 via 16x16x32 MFMA
// ALOAD: 0 = row-major bf16 A ; 1 = padded conv image (B,130,130,512) bf16
// EPI:   0 bf16-out(+bias)         1 f32-out(+bias)
//        2 off/attw split          3 BN+ReLU -> bf16
//        4 sigmoid-gate -> f32+bf16  5 ReLU -> bf16   6 +bias+residual -> f32
// ---------------------------------------------------------------------------
template<int BM, int ALOAD, int EPI>
__global__ __launch_bounds__(256)
void mgemm(const u16* __restrict__ A, const u16* __restrict__ Wt,
           const float* __restrict__ bias, int M, int K, int Nc,
           float* __restrict__ out, float* __restrict__ out2,
           u16* __restrict__ obf, const u16* __restrict__ img,
           const float* __restrict__ e0, const float* __restrict__ e1)
{
    constexpr int MI = BM / 32;
    __shared__ __align__(16) u16 As[BM * 32];
    __shared__ __align__(16) u16 Bs[128 * 32];

    const int tid  = threadIdx.x;
    const int lane = tid & 63;
    const int w    = tid >> 6;
    const int wr   = w >> 1, wc = w & 1;
    const int m0   = blockIdx.y * BM;
    const int n0   = blockIdx.x * 128;

    // staging lane coordinates: chunk c = w*64+lane (16B each)
    const int c1    = w * 64 + lane;
    const int rowA1 = c1 >> 2;          // 0..63
    const int partA = c1 & 3;           // 16B quarter of a 64B row
    const int rowA2 = rowA1 + 64;

    const u16* gA1 = nullptr; const u16* gA2 = nullptr;
    long cb1 = 0, cb2 = 0;
    if constexpr (ALOAD == 0) {
        gA1 = A + (size_t)(m0 + rowA1) * K + partA * 8;
        if constexpr (BM == 128) gA2 = A + (size_t)(m0 + rowA2) * K + partA * 8;
    } else {
        int m1 = m0 + rowA1; int b1 = m1 >> 14; int sp1 = m1 & (NNn - 1);
        cb1 = ((long)b1 * PADW + (sp1 >> 7)) * PADW + (sp1 & 127);
        if constexpr (BM == 128) {
            int m2 = m0 + rowA2; int b2 = m2 >> 14; int sp2 = m2 & (NNn - 1);
            cb2 = ((long)b2 * PADW + (sp2 >> 7)) * PADW + (sp2 & 127);
        }
    }
    const u16* gB1 = Wt + (size_t)(n0 + rowA1) * K + partA * 8;
    const u16* gB2 = Wt + (size_t)(n0 + rowA2) * K + partA * 8;

    f4v acc[MI][4] = {};

    const int lr = lane & 15;
    const int kb = (lane >> 4) * 8;

    for (int k0 = 0; k0 < K; k0 += 32) {
        if constexpr (ALOAD == 0) {
            ASYNC16(gA1 + k0, (u16*)As + w * 512);
            if constexpr (BM == 128) ASYNC16(gA2 + k0, (u16*)As + 2048 + w * 512);
        } else {
            int tap = k0 >> 9;
            int ci0 = k0 & 511;
            int dy = tap / 3, dx = tap - dy * 3;
            const u16* p1 = img + (size_t)(cb1 + dy * PADW + dx) * 512 + ci0 + partA * 8;
            ASYNC16(p1, (u16*)As + w * 512);
            if constexpr (BM == 128) {
                const u16* p2 = img + (size_t)(cb2 + dy * PADW + dx) * 512 + ci0 + partA * 8;
                ASYNC16(p2, (u16*)As + 2048 + w * 512);
            }
        }
        ASYNC16(gB1 + k0, (u16*)Bs + w * 512);
        ASYNC16(gB2 + k0, (u16*)Bs + 2048 + w * 512);
        __syncthreads();

        bf8v af[MI], bv[4];
        #pragma unroll
        for (int i = 0; i < MI; ++i)
            af[i] = *(const bf8v*)&As[(wr * (BM / 2) + i * 16 + lr) * 32 + kb];
        #pragma unroll
        for (int j = 0; j < 4; ++j)
            bv[j] = *(const bf8v*)&Bs[(wc * 64 + j * 16 + lr) * 32 + kb];
        #pragma unroll
        for (int i = 0; i < MI; ++i)
            #pragma unroll
            for (int j = 0; j < 4; ++j)
                acc[i][j] = __builtin_amdgcn_mfma_f32_16x16x32_bf16(af[i], bv[j], acc[i][j], 0, 0, 0);
        __syncthreads();
    }

    // ---- epilogue: D lane map: n = lane&15 (+j*16), m = (lane>>4)*4+r (+i*16)
    const int lq = lane >> 4;
    const float bnscale = rsqrtf(1.0f + 1e-5f);
    float bj[4], s0[4], s1[4]; int ncol[4];
    #pragma unroll
    for (int j = 0; j < 4; ++j) {
        int n = n0 + wc * 64 + j * 16 + lr;
        ncol[j] = n;
        if constexpr (EPI == 0 || EPI == 1 || EPI == 4 || EPI == 5 || EPI == 6)
            bj[j] = bias ? bias[n] : 0.f;
        if constexpr (EPI == 3) { s0[j] = e0[n] * bnscale; s1[j] = e1[n]; }
    }
    #pragma unroll
    for (int i = 0; i < MI; ++i) {
        #pragma unroll
        for (int r = 0; r < 4; ++r) {
            int m = m0 + wr * (BM / 2) + i * 16 + lq * 4 + r;
            #pragma unroll
            for (int j = 0; j < 4; ++j) {
                int n = ncol[j];
                float v = acc[i][j][r];
                size_t oi = (size_t)m * Nc + n;
                if constexpr (EPI == 0) {
                    obf[oi] = f2bf(v + bj[j]);
                } else if constexpr (EPI == 1) {
                    out[oi] = v + bj[j];
                } else if constexpr (EPI == 2) {
                    if (n < 64)      out [(size_t)m * 64 + n]        = v + e0[n];
                    else if (n < 96) out2[(size_t)m * 32 + (n - 64)] = v + e1[n - 64];
                } else if constexpr (EPI == 3) {
                    obf[oi] = f2bf(fmaxf(v * s0[j] + s1[j], 0.f));
                } else if constexpr (EPI == 4) {
                    float vv = v + bj[j];
                    float g = 1.f / (1.f + __expf(-vv));
                    float f = g * e0[oi] + (1.f - g) * e1[oi];
                    out[oi] = f; obf[oi] = f2bf(f);
                } else if constexpr (EPI == 5) {
                    obf[oi] = f2bf(fmaxf(v + bj[j], 0.f));
                } else if constexpr (EPI == 6) {
                    out[oi] = v + bj[j] + e0[oi];
                }
            }
        }
    }
}

// ---------------------------------------------------------------------------
// bev (B,C,N) f32 -> q (B*N, C) bf16, tiled transpose
// ---------------------------------------------------------------------------
__global__ __launch_bounds__(256)
void tcvt_k(const float* __restrict__ bev, u16* __restrict__ q)
{
    __shared__ float t[64][65];
    int c0 = blockIdx.x * 64, sp0 = blockIdx.y * 64, b = blockIdx.z;
    #pragma unroll
    for (int it = 0; it < 16; ++it) {
        int idx = it * 256 + threadIdx.x;
        int cl = idx >> 6, sl = idx & 63;
        t[cl][sl] = bev[((size_t)(b * CCn + c0 + cl)) * NNn + sp0 + sl];
    }
    __syncthreads();
    #pragma unroll
    for (int it = 0; it < 16; ++it) {
        int idx = it * 256 + threadIdx.x;
        int sl = idx >> 6, cl = idx & 63;
        q[((size_t)(b * NNn + sp0 + sl)) * CCn + c0 + cl] = f2bf(t[cl][sl]);
    }
}

// ---------------------------------------------------------------------------
// deformable sampling, softmax over NP=4 fused; val bf16 channel-last
// thread: d-pair = (t&15)*2, h = (t>>4)&7, row = t>>7
// ---------------------------------------------------------------------------
__global__ __launch_bounds__(256)
void sample_k(const u16* __restrict__ val, const float* __restrict__ off,
              const float* __restrict__ lg, u16* __restrict__ outp)
{
    int t = blockIdx.x * 256 + threadIdx.x;
    int d2 = (t & 15) * 2;
    int h  = (t >> 4) & 7;
    int rn = t >> 7;
    int n = rn & (NNn - 1), b = rn >> 14;
    int yp = n >> 7, xp = n & 127;

    const float* ofp = off + (size_t)rn * 64 + h * 8;
    const float* lgp = lg  + (size_t)rn * 32 + h * 4;

    float l0 = lgp[0], l1 = lgp[1], l2 = lgp[2], l3 = lgp[3];
    float mx = fmaxf(fmaxf(l0, l1), fmaxf(l2, l3));
    float e0 = __expf(l0 - mx), e1 = __expf(l1 - mx), e2 = __expf(l2 - mx), e3 = __expf(l3 - mx);
    float inv = 1.f / (e0 + e1 + e2 + e3);
    float aw[4] = { e0 * inv, e1 * inv, e2 * inv, e3 * inv };

    const u16* vb = val + (size_t)b * NNn * CCn + h * 32 + d2;
    float a0 = 0.f, a1 = 0.f;
    #pragma unroll
    for (int p = 0; p < 4; ++p) {
        float xs = (float)xp + ofp[p * 2 + 0];
        float ys = (float)yp + ofp[p * 2 + 1];
        float x0f = floorf(xs), y0f = floorf(ys);
        float lx = xs - x0f, ly = ys - y0f;
        int x0 = (int)x0f, y0 = (int)y0f;
        float s0 = 0.f, s1 = 0.f;
        #pragma unroll
        for (int cy = 0; cy < 2; ++cy) {
            #pragma unroll
            for (int cx = 0; cx < 2; ++cx) {
                int xi = x0 + cx, yi = y0 + cy;
                float wgt = (cx ? lx : 1.f - lx) * (cy ? ly : 1.f - ly);
                if (xi >= 0 && xi < WWn && yi >= 0 && yi < HHn) {
                    const __hip_bfloat162 vv = *reinterpret_cast<const __hip_bfloat162*>(
                        vb + (size_t)(yi * WWn + xi) * CCn);
                    s0 += wgt * __bfloat162float(vv.x);
                    s1 += wgt * __bfloat162float(vv.y);
                }
            }
        }
        a0 += aw[p] * s0;
        a1 += aw[p] * s1;
    }
    __hip_bfloat162 o;
    o.x = __float2bfloat16(a0);
    o.y = __float2bfloat16(a1);
    *reinterpret_cast<__hip_bfloat162*>(outp + (size_t)rn * CCn + h * 32 + d2) = o;
}

// ---------------------------------------------------------------------------
// LayerNorm kernels
// ---------------------------------------------------------------------------
__device__ __forceinline__ void blk_reduce2(float& s, float& s2, float* sA, float* sB)
{
    #pragma unroll
    for (int o = 1; o < 64; o <<= 1) {
        s  += __shfl_xor(s,  o, 64);
        s2 += __shfl_xor(s2, o, 64);
    }
    int wid = threadIdx.x >> 6;
    if ((threadIdx.x & 63) == 0) { sA[wid] = s; sB[wid] = s2; }
    __syncthreads();
    s  = sA[0] + sA[1] + sA[2] + sA[3];
    s2 = sB[0] + sB[1] + sB[2] + sB[3];
}

// x = LN(x + bevT), also writes bf16 copy into padded image (channel choff)
__global__ __launch_bounds__(256)
void ln_res_bev_k(float* __restrict__ x, const float* __restrict__ bev,
                  const float* __restrict__ g, const float* __restrict__ bb,
                  u16* __restrict__ pad, int choff)
{
    __shared__ float sA[4], sB[4];
    int row = blockIdx.x;
    int c = threadIdx.x;
    int b = row >> 14, sp = row & (NNn - 1);
    float v = x[(size_t)row * CCn + c] + bev[((size_t)b * CCn + c) * NNn + sp];
    float s = v, s2 = v * v;
    blk_reduce2(s, s2, sA, sB);
    float mean = s * (1.f / CCn);
    float var  = s2 * (1.f / CCn) - mean * mean;
    float r = rsqrtf(var + 1e-5f);
    float o = (v - mean) * r * g[c] + bb[c];
    x[(size_t)row * CCn + c] = o;
    int y = sp >> 7, xx = sp & 127;
    pad[(((size_t)b * PADW + y + 1) * PADW + (xx + 1)) * 512 + choff + c] = f2bf(o);
}

// out(B,C,N) = LN(t) * g + b + cam_bev
__global__ __launch_bounds__(256)
void ln_final_k(const float* __restrict__ t, const float* __restrict__ cam,
                const float* __restrict__ g, const float* __restrict__ bb,
                float* __restrict__ out)
{
    __shared__ float sA[4], sB[4];
    int row = blockIdx.x;
    int c = threadIdx.x;
    int b = row >> 14, sp = row & (NNn - 1);
    float v = t[(size_t)row * CCn + c];
    float s = v, s2 = v * v;
    blk_reduce2(s, s2, sA, sB);
    float mean = s * (1.f / CCn);
    float var  = s2 * (1.f / CCn) - mean * mean;
    float r = rsqrtf(var + 1e-5f);
    size_t oi = ((size_t)b * CCn + c) * NNn + sp;
    out[oi] = (v - mean) * r * g[c] + bb[c] + cam[oi];
}

// ---------------------------------------------------------------------------
// weight repacks (f32 -> bf16, transposed to [N][K])
// ---------------------------------------------------------------------------
__global__ void repack_T_bf(const float* __restrict__ w, u16* __restrict__ o, int K, int N)
{
    int i = blockIdx.x * 256 + threadIdx.x;
    if (i >= N * K) return;
    int n = i / K, k = i - n * K;
    o[i] = f2bf(w[(size_t)k * N + n]);
}
__global__ void repack_oa_k(const float* __restrict__ offw, const float* __restrict__ attww,
                            u16* __restrict__ o)
{
    int i = blockIdx.x * 256 + threadIdx.x;   // 128*256
    if (i >= 128 * 256) return;
    int n = i >> 8, k = i & 255;
    float v = 0.f;
    if (n < 64) v = offw[(size_t)k * 64 + n];
    else if (n < 96) v = attww[(size_t)k * 32 + (n - 64)];
    o[i] = f2bf(v);
}
__global__ void repack_conv_k(const float* __restrict__ g1, u16* __restrict__ o)
{
    int i = blockIdx.x * 256 + threadIdx.x;   // 128*4608
    if (i >= 128 * 4608) return;
    int co = i / 4608, k = i - co * 4608;
    int tap = k >> 9, ci = k & 511;
    o[i] = f2bf(g1[((size_t)co * 512 + ci) * 9 + tap]);
}
__global__ void cast_bf_k(const float* __restrict__ w, u16* __restrict__ o, int n)
{
    int i = blockIdx.x * 256 + threadIdx.x;
    if (i < n) o[i] = f2bf(w[i]);
}

// ---------------------------------------------------------------------------
extern "C" void kernel_launch(void* const* d_in, const int* in_sizes, int n_in,
                              void* d_out, int out_size, void* d_ws, size_t ws_size,
                              hipStream_t stream)
{
    const float* cam_bev   = (const float*)d_in[0];
    const float* sat_bev   = (const float*)d_in[1];
    const float* c2s_off_w  = (const float*)d_in[2];
    const float* c2s_off_b  = (const float*)d_in[3];
    const float* c2s_attw_w = (const float*)d_in[4];
    const float* c2s_attw_b = (const float*)d_in[5];
    const float* c2s_vp_w   = (const float*)d_in[6];
    const float* c2s_vp_b   = (const float*)d_in[7];
    const float* c2s_op_w   = (const float*)d_in[8];
    const float* c2s_op_b   = (const float*)d_in[9];
    const float* s2c_off_w  = (const float*)d_in[10];
    const float* s2c_off_b  = (const float*)d_in[11];
    const float* s2c_attw_w = (const float*)d_in[12];
    const float* s2c_attw_b = (const float*)d_in[13];
    const float* s2c_vp_w   = (const float*)d_in[14];
    const float* s2c_vp_b   = (const float*)d_in[15];
    const float* s2c_op_w   = (const float*)d_in[16];
    const float* s2c_op_b   = (const float*)d_in[17];
    const float* ln1_g = (const float*)d_in[18];
    const float* ln1_b = (const float*)d_in[19];
    const float* ln2_g = (const float*)d_in[20];
    const float* ln2_b = (const float*)d_in[21];
    const float* lnf_g = (const float*)d_in[22];
    const float* lnf_b = (const float*)d_in[23];
    const float* ffn1_w = (const float*)d_in[24];
    const float* ffn1_b = (const float*)d_in[25];
    const float* ffn2_w = (const float*)d_in[26];
    const float* ffn2_b = (const float*)d_in[27];
    const float* g1_w  = (const float*)d_in[28];
    const float* bn_g  = (const float*)d_in[29];
    const float* bn_b  = (const float*)d_in[30];
    const float* g2_w  = (const float*)d_in[31];
    const float* g2_b  = (const float*)d_in[32];

    char* base = (char*)d_ws;
    size_t off = 0;
    auto alloc = [&](size_t bytes) -> void* {
        void* p = base + off;
        off += (bytes + 255) & ~(size_t)255;
        return p;
    };

    u16*   qcam   = (u16*)  alloc((size_t)MTOT * CCn * 2);      // 16.78MB
    u16*   qsat   = (u16*)  alloc((size_t)MTOT * CCn * 2);
    u16*   valb   = (u16*)  alloc((size_t)MTOT * CCn * 2);
    u16*   sampb  = (u16*)  alloc((size_t)MTOT * CCn * 2);
    float* offb   = (float*)alloc((size_t)MTOT * 64 * 4);
    float* attwb  = (float*)alloc((size_t)MTOT * 32 * 4);
    float* cam_att= (float*)alloc((size_t)MTOT * CCn * 4);      // 33.55MB
    float* sat_att= (float*)alloc((size_t)MTOT * CCn * 4);
    size_t padBytes = (size_t)BBn * PADW * PADW * 512 * 2;      // 34.6MB
    u16*   pad    = (u16*)  alloc(padBytes);
    u16*   hbuf   = (u16*)  alloc((size_t)MTOT * 128 * 2);
    float* fusedf = (float*)alloc((size_t)MTOT * CCn * 4);
    u16*   wvp1   = (u16*)  alloc(256 * 256 * 2);
    u16*   wop1   = (u16*)  alloc(256 * 256 * 2);
    u16*   wvp2   = (u16*)  alloc(256 * 256 * 2);
    u16*   wop2   = (u16*)  alloc(256 * 256 * 2);
    u16*   woa1   = (u16*)  alloc(128 * 256 * 2);
    u16*   woa2   = (u16*)  alloc(128 * 256 * 2);
    u16*   wf1    = (u16*)  alloc(512 * 256 * 2);
    u16*   wf2    = (u16*)  alloc(256 * 512 * 2);
    u16*   wcv    = (u16*)  alloc((size_t)128 * 4608 * 2);
    u16*   wg2    = (u16*)  alloc(256 * 128 * 2);
    // aliases (temporally disjoint)
    u16*   midb     = (u16*)cam_att;   // ffn1 out; cam_att dead after gate epi
    u16*   fused_bf = valb;            // val dead after 2nd sampling
    float* tbuf     = (float*)qcam;    // spans qcam+qsat (contiguous 33.55MB)

    dim3 blk(256);

    hipMemsetAsync(pad, 0, padBytes, stream);

    tcvt_k<<<dim3(4, 256, 2), blk, 0, stream>>>(cam_bev, qcam);
    tcvt_k<<<dim3(4, 256, 2), blk, 0, stream>>>(sat_bev, qsat);

    repack_T_bf<<<256, blk, 0, stream>>>(c2s_vp_w, wvp1, 256, 256);
    repack_T_bf<<<256, blk, 0, stream>>>(c2s_op_w, wop1, 256, 256);
    repack_T_bf<<<256, blk, 0, stream>>>(s2c_vp_w, wvp2, 256, 256);
    repack_T_bf<<<256, blk, 0, stream>>>(s2c_op_w, wop2, 256, 256);
    repack_T_bf<<<512, blk, 0, stream>>>(ffn1_w, wf1, 256, 512);
    repack_T_bf<<<512, blk, 0, stream>>>(ffn2_w, wf2, 512, 256);
    repack_oa_k<<<128, blk, 0, stream>>>(c2s_off_w, c2s_attw_w, woa1);
    repack_oa_k<<<128, blk, 0, stream>>>(s2c_off_w, s2c_attw_w, woa2);
    repack_conv_k<<<2304, blk, 0, stream>>>(g1_w, wcv);
    cast_bf_k<<<128, blk, 0, stream>>>(g2_w, wg2, 256 * 128);

    // ---------- c2s: q = cam, kv = sat ----------
    mgemm<128, 0, 0><<<dim3(2, 256), blk, 0, stream>>>(
        qsat, wvp1, c2s_vp_b, MTOT, 256, 256, nullptr, nullptr, valb, nullptr, nullptr, nullptr);
    mgemm<128, 0, 2><<<dim3(1, 256), blk, 0, stream>>>(
        qcam, woa1, nullptr, MTOT, 256, 128, offb, attwb, nullptr, nullptr, c2s_off_b, c2s_attw_b);
    sample_k<<<16384, blk, 0, stream>>>(valb, offb, attwb, sampb);
    mgemm<128, 0, 1><<<dim3(2, 256), blk, 0, stream>>>(
        sampb, wop1, c2s_op_b, MTOT, 256, 256, cam_att, nullptr, nullptr, nullptr, nullptr, nullptr);
    ln_res_bev_k<<<MTOT, blk, 0, stream>>>(cam_att, cam_bev, ln1_g, ln1_b, pad, 0);

    // ---------- s2c: q = sat, kv = cam ----------
    mgemm<128, 0, 0><<<dim3(2, 256), blk, 0, stream>>>(
        qcam, wvp2, s2c_vp_b, MTOT, 256, 256, nullptr, nullptr, valb, nullptr, nullptr, nullptr);
    mgemm<128, 0, 2><<<dim3(1, 256), blk, 0, stream>>>(
        qsat, woa2, nullptr, MTOT, 256, 128, offb, attwb, nullptr, nullptr, s2c_off_b, s2c_attw_b);
    sample_k<<<16384, blk, 0, stream>>>(valb, offb, attwb, sampb);
    mgemm<128, 0, 1><<<dim3(2, 256), blk, 0, stream>>>(
        sampb, wop2, s2c_op_b, MTOT, 256, 256, sat_att, nullptr, nullptr, nullptr, nullptr, nullptr);
    ln_res_bev_k<<<MTOT, blk, 0, stream>>>(sat_att, sat_bev, ln2_g, ln2_b, pad, 256);

    // ---------- gating conv (implicit GEMM over padded image) + BN + ReLU ----
    mgemm<64, 1, 3><<<dim3(1, 512), blk, 0, stream>>>(
        nullptr, wcv, nullptr, MTOT, 9 * 512, 128, nullptr, nullptr, hbuf, pad, bn_g, bn_b);

    // ---------- 1x1 conv + sigmoid + gated fusion (f32 + bf16 out) ----------
    mgemm<128, 0, 4><<<dim3(2, 256), blk, 0, stream>>>(
        hbuf, wg2, g2_b, MTOT, 128, 256, fusedf, nullptr, fused_bf, nullptr, cam_att, sat_att);

    // ---------- FFN ----------
    mgemm<128, 0, 5><<<dim3(4, 256), blk, 0, stream>>>(
        fused_bf, wf1, ffn1_b, MTOT, 256, 512, nullptr, nullptr, midb, nullptr, nullptr, nullptr);
    mgemm<128, 0, 6><<<dim3(2, 256), blk, 0, stream>>>(
        midb, wf2, ffn2_b, MTOT, 512, 256, tbuf, nullptr, nullptr, nullptr, fusedf, nullptr);

    // ---------- final LN + residual back to (B,C,H,W) ----------
    ln_final_k<<<MTOT, blk, 0, stream>>>(tbuf, cam_bev, lnf_g, lnf_b, (float*)d_out);
}

// Round 3
// 376.258 us; speedup vs baseline: 4.6247x; 1.7220x over previous
//
#include <hip/hip_runtime.h>
#include <hip/hip_bf16.h>
#include <cstddef>

#define BBn  2
#define CCn  256
#define HHn  128
#define WWn  128
#define NNn  (HHn*WWn)        // 16384
#define MTOT (BBn*NNn)        // 32768
#define PADW 130

typedef unsigned short u16;
typedef __attribute__((ext_vector_type(8))) short bf8v;
typedef __attribute__((ext_vector_type(4))) float f4v;

typedef __attribute__((address_space(1))) const void gvoid_t;
typedef __attribute__((address_space(3))) void svoid_t;
#define ASYNC16(g, l) __builtin_amdgcn_global_load_lds((gvoid_t*)(g), (svoid_t*)(l), 16, 0, 0)

__device__ __forceinline__ u16 f2bf(float f) {
    __hip_bfloat16 h = __float2bfloat16(f);
    return *reinterpret_cast<u16*>(&h);
}
__device__ __forceinline__ float bf2f(u16 h) {
    return __uint_as_float(((unsigned)h) << 16);
}

// ---------------------------------------------------------------------------
// bf16 MFMA GEMM, tile BM x BN, BK=32, 4 waves arranged WRxWC (WR=4/WC).
// A[M,K] bf16 row-major (ALOAD 0) or padded conv image (ALOAD 1).
// Wt[Nc,K] bf16 pre-transposed.
// EPI: 0 bf16+bias | 2 off/attw split | 3 BN+ReLU->bf16 | 4 sigmoid-gate
//      5 ReLU->bf16 | 7 resid-init + rowLN -> pad bf16 | 8 resid-init + rowLN -> f32
// ---------------------------------------------------------------------------
template<int BM, int BN, int WC, int ALOAD, int EPI>
__global__ __launch_bounds__(256)
void mgemm(const u16* __restrict__ A, const u16* __restrict__ Wt,
           const float* __restrict__ bias, int K, int Nc,
           float* __restrict__ outf, float* __restrict__ outf2,
           u16* __restrict__ outb, const u16* __restrict__ img,
           const void* __restrict__ resid,
           const float* __restrict__ p0, const float* __restrict__ p1,
           int choff)
{
    constexpr int WR = 4 / WC;
    constexpr int MROWS = BM / WR;       // rows per wave
    constexpr int MI = MROWS / 16;
    constexpr int AT = BM / 64;          // A staging chunks per thread
    constexpr int BT = BN / 64;

    __shared__ __align__(16) u16 As[BM * 32];
    __shared__ __align__(16) u16 Bs[BN * 32];
    __shared__ float red[4][64][2];      // LN cross-wave partials (EPI 7/8)

    const int tid  = threadIdx.x;
    const int lane = tid & 63;
    const int w    = tid >> 6;
    const int wr   = w / WC, wc = w % WC;
    int by = blockIdx.y;
    if constexpr (ALOAD == 1) by = ((by & 7) << 6) | (by >> 3);   // XCD swizzle (512=8*64)
    const int m0 = by * BM;
    const int n0 = blockIdx.x * BN;
    const int lr = lane & 15, lq = lane >> 4;
    const int kb = lq * 8;

    // staging source pointers
    const u16* gA[AT]; long cbA[AT]; int paA[AT];
    #pragma unroll
    for (int t = 0; t < AT; ++t) {
        int c = t * 256 + tid; int row = c >> 2; int part = c & 3;
        if constexpr (ALOAD == 0) {
            gA[t] = A + (size_t)(m0 + row) * K + part * 8;
        } else {
            int m = m0 + row; int b = m >> 14; int sp = m & (NNn - 1);
            cbA[t] = ((long)b * PADW + (sp >> 7)) * PADW + (sp & 127);
            paA[t] = part;
        }
    }
    const u16* gB[BT];
    #pragma unroll
    for (int t = 0; t < BT; ++t) {
        int c = t * 256 + tid; int row = c >> 2; int part = c & 3;
        gB[t] = Wt + (size_t)(n0 + row) * K + part * 8;
    }

    // accumulator (residual+bias init for LN epilogues)
    f4v acc[MI][4];
    if constexpr (EPI == 7 || EPI == 8) {
        #pragma unroll
        for (int j = 0; j < 4; ++j) {
            int n = wc * 64 + j * 16 + lr;
            float bj = bias[n];
            #pragma unroll
            for (int i = 0; i < MI; ++i)
                #pragma unroll
                for (int r = 0; r < 4; ++r) {
                    int m = m0 + i * 16 + lq * 4 + r;     // WR==1
                    float rv;
                    if constexpr (EPI == 7) rv = bf2f(((const u16*)resid)[(size_t)m * 256 + n]);
                    else                    rv = ((const float*)resid)[(size_t)m * 256 + n];
                    acc[i][j][r] = rv + bj;
                }
        }
    } else {
        #pragma unroll
        for (int i = 0; i < MI; ++i)
            #pragma unroll
            for (int j = 0; j < 4; ++j)
                acc[i][j] = (f4v){0.f, 0.f, 0.f, 0.f};
    }

    for (int k0 = 0; k0 < K; k0 += 32) {
        #pragma unroll
        for (int t = 0; t < AT; ++t) {
            if constexpr (ALOAD == 0) {
                ASYNC16(gA[t] + k0, (u16*)As + (t * 256 + tid) * 8);
            } else {
                int tap = k0 >> 9;
                int ci0 = k0 & 511;
                int dy = tap / 3, dx = tap - dy * 3;
                const u16* p = img + (size_t)(cbA[t] + dy * PADW + dx) * 512 + ci0 + paA[t] * 8;
                ASYNC16(p, (u16*)As + (t * 256 + tid) * 8);
            }
        }
        #pragma unroll
        for (int t = 0; t < BT; ++t)
            ASYNC16(gB[t] + k0, (u16*)Bs + (t * 256 + tid) * 8);
        __syncthreads();

        bf8v af[MI], bv[4];
        #pragma unroll
        for (int i = 0; i < MI; ++i)
            af[i] = *(const bf8v*)&As[(wr * MROWS + i * 16 + lr) * 32 + kb];
        #pragma unroll
        for (int j = 0; j < 4; ++j)
            bv[j] = *(const bf8v*)&Bs[(wc * 64 + j * 16 + lr) * 32 + kb];
        #pragma unroll
        for (int i = 0; i < MI; ++i)
            #pragma unroll
            for (int j = 0; j < 4; ++j)
                acc[i][j] = __builtin_amdgcn_mfma_f32_16x16x32_bf16(af[i], bv[j], acc[i][j], 0, 0, 0);
        __syncthreads();
    }

    // -------------------- epilogue --------------------
    if constexpr (EPI == 7 || EPI == 8) {
        float g4[4], b4[4];
        #pragma unroll
        for (int j = 0; j < 4; ++j) {
            int n = wc * 64 + j * 16 + lr;
            g4[j] = p0[n]; b4[j] = p1[n];
        }
        #pragma unroll
        for (int i = 0; i < MI; ++i)
            #pragma unroll
            for (int r = 0; r < 4; ++r) {
                float p = 0.f, p2 = 0.f;
                #pragma unroll
                for (int j = 0; j < 4; ++j) { float v = acc[i][j][r]; p += v; p2 += v * v; }
                p += __shfl_xor(p, 1, 16);  p2 += __shfl_xor(p2, 1, 16);
                p += __shfl_xor(p, 2, 16);  p2 += __shfl_xor(p2, 2, 16);
                p += __shfl_xor(p, 4, 16);  p2 += __shfl_xor(p2, 4, 16);
                p += __shfl_xor(p, 8, 16);  p2 += __shfl_xor(p2, 8, 16);
                if (lr == 0) {
                    int row = i * 16 + lq * 4 + r;
                    red[w][row][0] = p; red[w][row][1] = p2;
                }
            }
        __syncthreads();
        #pragma unroll
        for (int i = 0; i < MI; ++i)
            #pragma unroll
            for (int r = 0; r < 4; ++r) {
                int row = i * 16 + lq * 4 + r;
                float s  = red[0][row][0] + red[1][row][0] + red[2][row][0] + red[3][row][0];
                float s2 = red[0][row][1] + red[1][row][1] + red[2][row][1] + red[3][row][1];
                float mean = s * (1.f / 256.f);
                float var  = s2 * (1.f / 256.f) - mean * mean;
                float rstd = rsqrtf(var + 1e-5f);
                int m = m0 + row;
                if constexpr (EPI == 7) {
                    int b = m >> 14, sp = m & (NNn - 1);
                    size_t pb = (((size_t)b * PADW + (sp >> 7) + 1) * PADW + (sp & 127) + 1) * 512 + choff;
                    #pragma unroll
                    for (int j = 0; j < 4; ++j) {
                        int n = wc * 64 + j * 16 + lr;
                        outb[pb + n] = f2bf((acc[i][j][r] - mean) * rstd * g4[j] + b4[j]);
                    }
                } else {
                    #pragma unroll
                    for (int j = 0; j < 4; ++j) {
                        int n = wc * 64 + j * 16 + lr;
                        outf[(size_t)m * 256 + n] = (acc[i][j][r] - mean) * rstd * g4[j] + b4[j];
                    }
                }
            }
        return;
    }

    const float bnscale = rsqrtf(1.0f + 1e-5f);
    float bj[4], s0[4], s1[4]; int ncol[4];
    #pragma unroll
    for (int j = 0; j < 4; ++j) {
        int n = n0 + wc * 64 + j * 16 + lr;
        ncol[j] = n;
        if constexpr (EPI == 0 || EPI == 4 || EPI == 5) bj[j] = bias[n];
        if constexpr (EPI == 3) { s0[j] = p0[n] * bnscale; s1[j] = p1[n]; }
    }
    #pragma unroll
    for (int i = 0; i < MI; ++i) {
        #pragma unroll
        for (int r = 0; r < 4; ++r) {
            int m = m0 + wr * MROWS + i * 16 + lq * 4 + r;
            size_t pb = 0;
            if constexpr (EPI == 4) {
                int b = m >> 14, sp = m & (NNn - 1);
                pb = (((size_t)b * PADW + (sp >> 7) + 1) * PADW + (sp & 127) + 1) * 512;
            }
            #pragma unroll
            for (int j = 0; j < 4; ++j) {
                int n = ncol[j];
                float v = acc[i][j][r];
                size_t oi = (size_t)m * Nc + n;
                if constexpr (EPI == 0) {
                    outb[oi] = f2bf(v + bj[j]);
                } else if constexpr (EPI == 2) {
                    if (n < 64)      outf [(size_t)m * 64 + n]        = v + p0[n];
                    else if (n < 96) outf2[(size_t)m * 32 + (n - 64)] = v + p1[n - 64];
                } else if constexpr (EPI == 3) {
                    outb[oi] = f2bf(fmaxf(v * s0[j] + s1[j], 0.f));
                } else if constexpr (EPI == 4) {
                    float vv = v + bj[j];
                    float g = 1.f / (1.f + __expf(-vv));
                    float f = g * bf2f(img[pb + n]) + (1.f - g) * bf2f(img[pb + 256 + n]);
                    outf[oi] = f; outb[oi] = f2bf(f);
                } else if constexpr (EPI == 5) {
                    outb[oi] = f2bf(fmaxf(v + bj[j], 0.f));
                }
            }
        }
    }
}

// ---------------------------------------------------------------------------
// bev (B,C,N) f32 -> (B*N, C) bf16 ; z: 0-1 cam batches, 2-3 sat batches
// ---------------------------------------------------------------------------
__global__ __launch_bounds__(256)
void tcvt_k(const float* __restrict__ cam, const float* __restrict__ sat,
            u16* __restrict__ qcam, u16* __restrict__ qsat)
{
    __shared__ float t[64][65];
    int z = blockIdx.z;
    const float* src = (z < 2) ? cam : sat;
    u16* dst = (z < 2) ? qcam : qsat;
    int b = z & 1;
    int c0 = blockIdx.x * 64, sp0 = blockIdx.y * 64;
    #pragma unroll
    for (int it = 0; it < 16; ++it) {
        int idx = it * 256 + threadIdx.x;
        int cl = idx >> 6, sl = idx & 63;
        t[cl][sl] = src[((size_t)(b * CCn + c0 + cl)) * NNn + sp0 + sl];
    }
    __syncthreads();
    #pragma unroll
    for (int it = 0; it < 16; ++it) {
        int idx = it * 256 + threadIdx.x;
        int sl = idx >> 6, cl = idx & 63;
        dst[((size_t)(b * NNn + sp0 + sl)) * CCn + c0 + cl] = f2bf(t[cl][sl]);
    }
}

// (B,N,C) f32 -> d_out (B,C,N) f32 + cam_bev
__global__ __launch_bounds__(256)
void taddT_k(const float* __restrict__ t, const float* __restrict__ cam,
             float* __restrict__ out)
{
    __shared__ float s[64][65];
    int c0 = blockIdx.x * 64, sp0 = blockIdx.y * 64, b = blockIdx.z;
    #pragma unroll
    for (int it = 0; it < 16; ++it) {
        int idx = it * 256 + threadIdx.x;
        int sl = idx >> 6, cl = idx & 63;
        s[sl][cl] = t[(size_t)(b * NNn + sp0 + sl) * CCn + c0 + cl];
    }
    __syncthreads();
    #pragma unroll
    for (int it = 0; it < 16; ++it) {
        int idx = it * 256 + threadIdx.x;
        int cl = idx >> 6, sl = idx & 63;
        size_t oi = ((size_t)(b * CCn + c0 + cl)) * NNn + sp0 + sl;
        out[oi] = s[sl][cl] + cam[oi];
    }
}

// ---------------------------------------------------------------------------
// deformable sampling, softmax over NP=4 fused; 4 channels / thread
// ---------------------------------------------------------------------------
__global__ __launch_bounds__(256)
void sample_k(const u16* __restrict__ val, const float* __restrict__ off,
              const float* __restrict__ lg, u16* __restrict__ outp)
{
    int t = blockIdx.x * 256 + threadIdx.x;    // MTOT*64 threads
    int d4 = (t & 7) * 4;
    int h  = (t >> 3) & 7;
    int rn = t >> 6;
    int n = rn & (NNn - 1), b = rn >> 14;
    int yp = n >> 7, xp = n & 127;

    const float* ofp = off + (size_t)rn * 64 + h * 8;
    const float* lgp = lg  + (size_t)rn * 32 + h * 4;

    float l0 = lgp[0], l1 = lgp[1], l2 = lgp[2], l3 = lgp[3];
    float mx = fmaxf(fmaxf(l0, l1), fmaxf(l2, l3));
    float e0 = __expf(l0 - mx), e1 = __expf(l1 - mx), e2 = __expf(l2 - mx), e3 = __expf(l3 - mx);
    float inv = 1.f / (e0 + e1 + e2 + e3);
    float aw[4] = { e0 * inv, e1 * inv, e2 * inv, e3 * inv };

    const u16* vb = val + (size_t)b * NNn * CCn + h * 32 + d4;
    float a[4] = {0.f, 0.f, 0.f, 0.f};
    #pragma unroll
    for (int p = 0; p < 4; ++p) {
        float xs = (float)xp + ofp[p * 2 + 0];
        float ys = (float)yp + ofp[p * 2 + 1];
        float x0f = floorf(xs), y0f = floorf(ys);
        float lx = xs - x0f, ly = ys - y0f;
        int x0 = (int)x0f, y0 = (int)y0f;
        #pragma unroll
        for (int cy = 0; cy < 2; ++cy) {
            #pragma unroll
            for (int cx = 0; cx < 2; ++cx) {
                int xi = x0 + cx, yi = y0 + cy;
                float wgt = aw[p] * (cx ? lx : 1.f - lx) * (cy ? ly : 1.f - ly);
                if (xi >= 0 && xi < WWn && yi >= 0 && yi < HHn) {
                    ushort4 vv = *(const ushort4*)(vb + (size_t)(yi * WWn + xi) * CCn);
                    a[0] += wgt * bf2f(vv.x);
                    a[1] += wgt * bf2f(vv.y);
                    a[2] += wgt * bf2f(vv.z);
                    a[3] += wgt * bf2f(vv.w);
                }
            }
        }
    }
    ushort4 o;
    o.x = f2bf(a[0]); o.y = f2bf(a[1]); o.z = f2bf(a[2]); o.w = f2bf(a[3]);
    *(ushort4*)(outp + (size_t)rn * CCn + h * 32 + d4) = o;
}

// ---------------------------------------------------------------------------
// all weight repacks in one kernel (f32 -> bf16, transposed to [N][K])
// layout in wbase (u16 elems):
//   0        wvp1   65536    | 65536   wop1 | 131072 wvp2 | 196608 wop2
//   262144   wf1   131072    | 393216  wf2 131072
//   524288   woa1   32768    | 557056  woa2  32768
//   589824   wcv   589824    | 1179648 wg2   32768      total 1212416
// ---------------------------------------------------------------------------
__global__ __launch_bounds__(256)
void repack_all(const float* __restrict__ vp1, const float* __restrict__ op1,
                const float* __restrict__ vp2, const float* __restrict__ op2,
                const float* __restrict__ f1w, const float* __restrict__ f2w,
                const float* __restrict__ of1, const float* __restrict__ aw1,
                const float* __restrict__ of2, const float* __restrict__ aw2,
                const float* __restrict__ g1,  const float* __restrict__ g2,
                u16* __restrict__ wb)
{
    int i = blockIdx.x * 256 + threadIdx.x;
    if (i >= 1212416) return;
    float v;
    if (i < 262144) {
        const float* src[4] = { vp1, op1, vp2, op2 };
        int q = i >> 16, j = i & 65535;
        int n = j >> 8, k = j & 255;
        v = src[q][(size_t)k * 256 + n];
    } else if (i < 393216) {
        int j = i - 262144; int n = j >> 8, k = j & 255;      // [512][256]
        v = f1w[(size_t)k * 512 + n];
    } else if (i < 524288) {
        int j = i - 393216; int n = j >> 9, k = j & 511;      // [256][512]
        v = f2w[(size_t)k * 256 + n];
    } else if (i < 589824) {
        int jj = i - 524288; int hh = jj >> 15; int j = jj & 32767;
        int n = j >> 8, k = j & 255;                          // [128][256]
        const float* ofw = hh ? of2 : of1;
        const float* aww = hh ? aw2 : aw1;
        if (n < 64)      v = ofw[(size_t)k * 64 + n];
        else if (n < 96) v = aww[(size_t)k * 32 + (n - 64)];
        else             v = 0.f;
    } else if (i < 1179648) {
        int j = i - 589824; int co = j / 4608, k = j - co * 4608;
        int tap = k >> 9, ci = k & 511;
        v = g1[((size_t)co * 512 + ci) * 9 + tap];
    } else {
        int j = i - 1179648; int n = j >> 7, k = j & 127;     // [256][128]
        v = g2[(size_t)n * 128 + k];
    }
    wb[i] = f2bf(v);
}

// ---------------------------------------------------------------------------
extern "C" void kernel_launch(void* const* d_in, const int* in_sizes, int n_in,
                              void* d_out, int out_size, void* d_ws, size_t ws_size,
                              hipStream_t stream)
{
    const float* cam_bev   = (const float*)d_in[0];
    const float* sat_bev   = (const float*)d_in[1];
    const float* c2s_off_w  = (const float*)d_in[2];
    const float* c2s_off_b  = (const float*)d_in[3];
    const float* c2s_attw_w = (const float*)d_in[4];
    const float* c2s_attw_b = (const float*)d_in[5];
    const float* c2s_vp_w   = (const float*)d_in[6];
    const float* c2s_vp_b   = (const float*)d_in[7];
    const float* c2s_op_w   = (const float*)d_in[8];
    const float* c2s_op_b   = (const float*)d_in[9];
    const float* s2c_off_w  = (const float*)d_in[10];
    const float* s2c_off_b  = (const float*)d_in[11];
    const float* s2c_attw_w = (const float*)d_in[12];
    const float* s2c_attw_b = (const float*)d_in[13];
    const float* s2c_vp_w   = (const float*)d_in[14];
    const float* s2c_vp_b   = (const float*)d_in[15];
    const float* s2c_op_w   = (const float*)d_in[16];
    const float* s2c_op_b   = (const float*)d_in[17];
    const float* ln1_g = (const float*)d_in[18];
    const float* ln1_b = (const float*)d_in[19];
    const float* ln2_g = (const float*)d_in[20];
    const float* ln2_b = (const float*)d_in[21];
    const float* lnf_g = (const float*)d_in[22];
    const float* lnf_b = (const float*)d_in[23];
    const float* ffn1_w = (const float*)d_in[24];
    const float* ffn1_b = (const float*)d_in[25];
    const float* ffn2_w = (const float*)d_in[26];
    const float* ffn2_b = (const float*)d_in[27];
    const float* g1_w  = (const float*)d_in[28];
    const float* bn_g  = (const float*)d_in[29];
    const float* bn_b  = (const float*)d_in[30];
    const float* g2_w  = (const float*)d_in[31];
    const float* g2_b  = (const float*)d_in[32];

    char* base = (char*)d_ws;
    size_t off = 0;
    auto alloc = [&](size_t bytes) -> void* {
        void* p = base + off;
        off += (bytes + 255) & ~(size_t)255;
        return p;
    };

    u16*   qcam   = (u16*)  alloc((size_t)MTOT * CCn * 2);      // 16.78MB
    u16*   qsat   = (u16*)  alloc((size_t)MTOT * CCn * 2);
    u16*   valb   = (u16*)  alloc((size_t)MTOT * CCn * 2);
    u16*   sampb  = (u16*)  alloc((size_t)MTOT * CCn * 2);
    float* offb   = (float*)alloc((size_t)MTOT * 64 * 4);
    float* attwb  = (float*)alloc((size_t)MTOT * 32 * 4);
    size_t padBytes = (size_t)BBn * PADW * PADW * 512 * 2;      // 34.6MB
    u16*   pad    = (u16*)  alloc(padBytes);
    u16*   hbuf   = (u16*)  alloc((size_t)MTOT * 128 * 2);
    float* fusedf = (float*)alloc((size_t)MTOT * CCn * 4);
    u16*   midb   = (u16*)  alloc((size_t)MTOT * 512 * 2);
    u16*   wbase  = (u16*)  alloc((size_t)1212416 * 2);
    // weight slices
    u16* wvp1 = wbase;
    u16* wop1 = wbase + 65536;
    u16* wvp2 = wbase + 131072;
    u16* wop2 = wbase + 196608;
    u16* wf1  = wbase + 262144;
    u16* wf2  = wbase + 393216;
    u16* woa1 = wbase + 524288;
    u16* woa2 = wbase + 557056;
    u16* wcv  = wbase + 589824;
    u16* wg2  = wbase + 1179648;
    // aliases (temporally disjoint)
    u16*   fused_bf = valb;             // valb dead after 2nd sampling
    float* tbuf     = (float*)qcam;     // qcam+qsat contiguous 33.55MB, dead before ffn2

    dim3 blk(256);

    hipMemsetAsync(pad, 0, padBytes, stream);
    tcvt_k<<<dim3(4, 256, 4), blk, 0, stream>>>(cam_bev, sat_bev, qcam, qsat);
    repack_all<<<4736, blk, 0, stream>>>(c2s_vp_w, c2s_op_w, s2c_vp_w, s2c_op_w,
                                         ffn1_w, ffn2_w, c2s_off_w, c2s_attw_w,
                                         s2c_off_w, s2c_attw_w, g1_w, g2_w, wbase);

    // ---------- c2s: q = cam, kv = sat ----------
    mgemm<128, 128, 2, 0, 0><<<dim3(2, 256), blk, 0, stream>>>(
        qsat, wvp1, c2s_vp_b, 256, 256, nullptr, nullptr, valb, nullptr, nullptr, nullptr, nullptr, 0);
    mgemm<128, 128, 2, 0, 2><<<dim3(1, 256), blk, 0, stream>>>(
        qcam, woa1, nullptr, 256, 128, offb, attwb, nullptr, nullptr, nullptr, c2s_off_b, c2s_attw_b, 0);
    sample_k<<<8192, blk, 0, stream>>>(valb, offb, attwb, sampb);
    mgemm<64, 256, 4, 0, 7><<<dim3(1, 512), blk, 0, stream>>>(
        sampb, wop1, c2s_op_b, 256, 256, nullptr, nullptr, pad, nullptr, qcam, ln1_g, ln1_b, 0);

    // ---------- s2c: q = sat, kv = cam ----------
    mgemm<128, 128, 2, 0, 0><<<dim3(2, 256), blk, 0, stream>>>(
        qcam, wvp2, s2c_vp_b, 256, 256, nullptr, nullptr, valb, nullptr, nullptr, nullptr, nullptr, 0);
    mgemm<128, 128, 2, 0, 2><<<dim3(1, 256), blk, 0, stream>>>(
        qsat, woa2, nullptr, 256, 128, offb, attwb, nullptr, nullptr, nullptr, s2c_off_b, s2c_attw_b, 0);
    sample_k<<<8192, blk, 0, stream>>>(valb, offb, attwb, sampb);
    mgemm<64, 256, 4, 0, 7><<<dim3(1, 512), blk, 0, stream>>>(
        sampb, wop2, s2c_op_b, 256, 256, nullptr, nullptr, pad, nullptr, qsat, ln2_g, ln2_b, 256);

    // ---------- gating conv (implicit GEMM, XCD-swizzled) + BN + ReLU ----------
    mgemm<64, 128, 2, 1, 3><<<dim3(1, 512), blk, 0, stream>>>(
        nullptr, wcv, nullptr, 4608, 128, nullptr, nullptr, hbuf, pad, nullptr, bn_g, bn_b, 0);

    // ---------- 1x1 conv + sigmoid + gated fusion (maps read from pad) ----------
    mgemm<128, 128, 2, 0, 4><<<dim3(2, 256), blk, 0, stream>>>(
        hbuf, wg2, g2_b, 128, 256, fusedf, nullptr, fused_bf, pad, nullptr, nullptr, nullptr, 0);

    // ---------- FFN ----------
    mgemm<128, 128, 2, 0, 5><<<dim3(4, 256), blk, 0, stream>>>(
        fused_bf, wf1, ffn1_b, 256, 512, nullptr, nullptr, midb, nullptr, nullptr, nullptr, nullptr, 0);
    mgemm<64, 256, 4, 0, 8><<<dim3(1, 512), blk, 0, stream>>>(
        midb, wf2, ffn2_b, 512, 256, tbuf, nullptr, nullptr, nullptr, fusedf, lnf_g, lnf_b, 0);

    // ---------- transpose back to (B,C,H,W) + cam_bev residual ----------
    taddT_k<<<dim3(4, 256, 2), blk, 0, stream>>>(tbuf, cam_bev, (float*)d_out);
}

// Round 4
// 349.510 us; speedup vs baseline: 4.9786x; 1.0765x over previous
//
#include <hip/hip_runtime.h>
#include <hip/hip_bf16.h>
#include <cstddef>

#define BBn  2
#define CCn  256
#define HHn  128
#define WWn  128
#define NNn  (HHn*WWn)        // 16384
#define MTOT (BBn*NNn)        // 32768
#define PADW 130

typedef unsigned short u16;
typedef __attribute__((ext_vector_type(8))) short bf8v;
typedef __attribute__((ext_vector_type(4))) float f4v;

typedef __attribute__((address_space(1))) const void gvoid_t;
typedef __attribute__((address_space(3))) void svoid_t;
#define ASYNC16(g, l) __builtin_amdgcn_global_load_lds((gvoid_t*)(g), (svoid_t*)(l), 16, 0, 0)

__device__ __forceinline__ u16 f2bf(float f) {
    __hip_bfloat16 h = __float2bfloat16(f);
    return *reinterpret_cast<u16*>(&h);
}
__device__ __forceinline__ float bf2f(u16 h) {
    return __uint_as_float(((unsigned)h) << 16);
}

// z-offsets (elements) applied when blockIdx.z == 1
struct ZOff {
    long a, w, bia, f1, f2, b1, r, p;
    int ch, kb;
};

// ---------------------------------------------------------------------------
// bf16 MFMA GEMM, tile BM x BN, BK=32, 4 waves arranged WRxWC (WR=4/WC).
// A[M,K] bf16 row-major (ALOAD 0) or padded conv image (ALOAD 1).
// Wt[Nc,ldw] bf16 pre-transposed.  K = loop length; k window = [z*kb, z*kb+K)
// EPI: 0 bf16+bias | 1 raw f32 (split-K partial) | 2 off/attw split
//      4 sigmoid-gate | 5 ReLU->bf16
//      7 resid-init + rowLN -> pad bf16 | 8 resid-init + rowLN -> f32
// ---------------------------------------------------------------------------
template<int BM, int BN, int WC, int ALOAD, int EPI>
__global__ __launch_bounds__(256)
void mgemm(const u16* __restrict__ A, const u16* __restrict__ Wt,
           const float* __restrict__ bias, int K, int ldw, int Nc,
           float* __restrict__ outf, float* __restrict__ outf2,
           u16* __restrict__ outb, const u16* __restrict__ img,
           const void* __restrict__ resid,
           const float* __restrict__ p0, const float* __restrict__ p1,
           int choff, ZOff zo)
{
    constexpr int WR = 4 / WC;
    constexpr int MROWS = BM / WR;       // rows per wave
    constexpr int MI = MROWS / 16;
    constexpr int AT = BM / 64;          // A staging chunks per thread
    constexpr int BT = BN / 64;

    __shared__ __align__(16) u16 As[BM * 32];
    __shared__ __align__(16) u16 Bs[BN * 32];
    __shared__ float red[4][64][2];      // LN cross-wave partials (EPI 7/8)

    const int z = blockIdx.z;
    if (z) {
        A += zo.a; Wt += zo.w;
        if (bias)  bias  += zo.bia;
        if (outf)  outf  += zo.f1;
        if (outf2) outf2 += zo.f2;
        if (outb)  outb  += zo.b1;
        if (p0)    p0    += zo.p;
        if (p1)    p1    += zo.p;
        choff += zo.ch;
    }
    const int kbeg = z * zo.kb;

    const int tid  = threadIdx.x;
    const int lane = tid & 63;
    const int w    = tid >> 6;
    const int wr   = w / WC, wc = w % WC;
    int by = blockIdx.y;
    if constexpr (ALOAD == 1) by = ((by & 7) << 5) | (by >> 3);   // XCD swizzle (256=8*32)
    const int m0 = by * BM;
    const int n0 = blockIdx.x * BN;
    const int lr = lane & 15, lq = lane >> 4;
    const int kb = lq * 8;

    // staging source pointers
    const u16* gA[AT]; long cbA[AT]; int paA[AT];
    #pragma unroll
    for (int t = 0; t < AT; ++t) {
        int c = t * 256 + tid; int row = c >> 2; int part = c & 3;
        if constexpr (ALOAD == 0) {
            gA[t] = A + (size_t)(m0 + row) * K + part * 8;
        } else {
            int m = m0 + row; int b = m >> 14; int sp = m & (NNn - 1);
            cbA[t] = ((long)b * PADW + (sp >> 7)) * PADW + (sp & 127);
            paA[t] = part;
        }
    }
    const u16* gB[BT];
    #pragma unroll
    for (int t = 0; t < BT; ++t) {
        int c = t * 256 + tid; int row = c >> 2; int part = c & 3;
        gB[t] = Wt + (size_t)(n0 + row) * ldw + part * 8;
    }

    // accumulator (residual+bias init for LN epilogues; WR==1 there)
    f4v acc[MI][4];
    if constexpr (EPI == 7 || EPI == 8) {
        const u16*   r16 = (const u16*)resid   + (z ? zo.r : 0);
        const float* r32 = (const float*)resid + (z ? zo.r : 0);
        #pragma unroll
        for (int j = 0; j < 4; ++j) {
            int n = wc * 64 + j * 16 + lr;
            float bj = bias[n];
            #pragma unroll
            for (int i = 0; i < MI; ++i)
                #pragma unroll
                for (int r = 0; r < 4; ++r) {
                    int m = m0 + i * 16 + lq * 4 + r;
                    float rv;
                    if constexpr (EPI == 7) rv = bf2f(r16[(size_t)m * 256 + n]);
                    else                    rv = r32[(size_t)m * 256 + n];
                    acc[i][j][r] = rv + bj;
                }
        }
    } else {
        #pragma unroll
        for (int i = 0; i < MI; ++i)
            #pragma unroll
            for (int j = 0; j < 4; ++j)
                acc[i][j] = (f4v){0.f, 0.f, 0.f, 0.f};
    }

    for (int k0 = kbeg; k0 < kbeg + K; k0 += 32) {
        #pragma unroll
        for (int t = 0; t < AT; ++t) {
            if constexpr (ALOAD == 0) {
                ASYNC16(gA[t] + k0, (u16*)As + (t * 256 + tid) * 8);
            } else {
                int tap = k0 >> 9;
                int ci0 = k0 & 511;
                int dy = tap / 3, dx = tap - dy * 3;
                const u16* p = img + (size_t)(cbA[t] + dy * PADW + dx) * 512 + ci0 + paA[t] * 8;
                ASYNC16(p, (u16*)As + (t * 256 + tid) * 8);
            }
        }
        #pragma unroll
        for (int t = 0; t < BT; ++t)
            ASYNC16(gB[t] + k0, (u16*)Bs + (t * 256 + tid) * 8);
        __syncthreads();

        bf8v af[MI], bv[4];
        #pragma unroll
        for (int i = 0; i < MI; ++i)
            af[i] = *(const bf8v*)&As[(wr * MROWS + i * 16 + lr) * 32 + kb];
        #pragma unroll
        for (int j = 0; j < 4; ++j)
            bv[j] = *(const bf8v*)&Bs[(wc * 64 + j * 16 + lr) * 32 + kb];
        #pragma unroll
        for (int i = 0; i < MI; ++i)
            #pragma unroll
            for (int j = 0; j < 4; ++j)
                acc[i][j] = __builtin_amdgcn_mfma_f32_16x16x32_bf16(af[i], bv[j], acc[i][j], 0, 0, 0);
        __syncthreads();
    }

    // -------------------- epilogue --------------------
    if constexpr (EPI == 7 || EPI == 8) {
        float g4[4], b4[4];
        #pragma unroll
        for (int j = 0; j < 4; ++j) {
            int n = wc * 64 + j * 16 + lr;
            g4[j] = p0[n]; b4[j] = p1[n];
        }
        #pragma unroll
        for (int i = 0; i < MI; ++i)
            #pragma unroll
            for (int r = 0; r < 4; ++r) {
                float p = 0.f, p2 = 0.f;
                #pragma unroll
                for (int j = 0; j < 4; ++j) { float v = acc[i][j][r]; p += v; p2 += v * v; }
                p += __shfl_xor(p, 1, 16);  p2 += __shfl_xor(p2, 1, 16);
                p += __shfl_xor(p, 2, 16);  p2 += __shfl_xor(p2, 2, 16);
                p += __shfl_xor(p, 4, 16);  p2 += __shfl_xor(p2, 4, 16);
                p += __shfl_xor(p, 8, 16);  p2 += __shfl_xor(p2, 8, 16);
                if (lr == 0) {
                    int row = i * 16 + lq * 4 + r;
                    red[w][row][0] = p; red[w][row][1] = p2;
                }
            }
        __syncthreads();
        #pragma unroll
        for (int i = 0; i < MI; ++i)
            #pragma unroll
            for (int r = 0; r < 4; ++r) {
                int row = i * 16 + lq * 4 + r;
                float s  = red[0][row][0] + red[1][row][0] + red[2][row][0] + red[3][row][0];
                float s2 = red[0][row][1] + red[1][row][1] + red[2][row][1] + red[3][row][1];
                float mean = s * (1.f / 256.f);
                float var  = s2 * (1.f / 256.f) - mean * mean;
                float rstd = rsqrtf(var + 1e-5f);
                int m = m0 + row;
                if constexpr (EPI == 7) {
                    int b = m >> 14, sp = m & (NNn - 1);
                    size_t pb = (((size_t)b * PADW + (sp >> 7) + 1) * PADW + (sp & 127) + 1) * 512 + choff;
                    #pragma unroll
                    for (int j = 0; j < 4; ++j) {
                        int n = wc * 64 + j * 16 + lr;
                        outb[pb + n] = f2bf((acc[i][j][r] - mean) * rstd * g4[j] + b4[j]);
                    }
                } else {
                    #pragma unroll
                    for (int j = 0; j < 4; ++j) {
                        int n = wc * 64 + j * 16 + lr;
                        outf[(size_t)m * 256 + n] = (acc[i][j][r] - mean) * rstd * g4[j] + b4[j];
                    }
                }
            }
        return;
    }

    float bj[4]; int ncol[4];
    #pragma unroll
    for (int j = 0; j < 4; ++j) {
        int n = n0 + wc * 64 + j * 16 + lr;
        ncol[j] = n;
        if constexpr (EPI == 0 || EPI == 4 || EPI == 5) bj[j] = bias[n];
    }
    #pragma unroll
    for (int i = 0; i < MI; ++i) {
        #pragma unroll
        for (int r = 0; r < 4; ++r) {
            int m = m0 + wr * MROWS + i * 16 + lq * 4 + r;
            size_t pb = 0;
            if constexpr (EPI == 4) {
                int b = m >> 14, sp = m & (NNn - 1);
                pb = (((size_t)b * PADW + (sp >> 7) + 1) * PADW + (sp & 127) + 1) * 512;
            }
            #pragma unroll
            for (int j = 0; j < 4; ++j) {
                int n = ncol[j];
                float v = acc[i][j][r];
                size_t oi = (size_t)m * Nc + n;
                if constexpr (EPI == 0) {
                    outb[oi] = f2bf(v + bj[j]);
                } else if constexpr (EPI == 1) {
                    outf[oi] = v;
                } else if constexpr (EPI == 2) {
                    if (n < 64)      outf [(size_t)m * 64 + n]        = v + p0[n];
                    else if (n < 96) outf2[(size_t)m * 32 + (n - 64)] = v + p1[n - 64];
                } else if constexpr (EPI == 4) {
                    float vv = v + bj[j];
                    float g = 1.f / (1.f + __expf(-vv));
                    float f = g * bf2f(img[pb + n]) + (1.f - g) * bf2f(img[pb + 256 + n]);
                    outf[oi] = f; outb[oi] = f2bf(f);
                } else if constexpr (EPI == 5) {
                    outb[oi] = f2bf(fmaxf(v + bj[j], 0.f));
                }
            }
        }
    }
}

// ---------------------------------------------------------------------------
// split-K combine + BN + ReLU -> bf16
// ---------------------------------------------------------------------------
__global__ __launch_bounds__(256)
void combine_k(const float* __restrict__ part, const float* __restrict__ bng,
               const float* __restrict__ bnb, u16* __restrict__ hb)
{
    const float bnscale = rsqrtf(1.0f + 1e-5f);
    int i = (blockIdx.x * 256 + threadIdx.x) * 4;   // over MTOT*128
    int n = i & 127;
    float4 a = *(const float4*)&part[i];
    float4 b = *(const float4*)&part[(size_t)MTOT * 128 + i];
    ushort4 o;
    o.x = f2bf(fmaxf((a.x + b.x) * bnscale * bng[n + 0] + bnb[n + 0], 0.f));
    o.y = f2bf(fmaxf((a.y + b.y) * bnscale * bng[n + 1] + bnb[n + 1], 0.f));
    o.z = f2bf(fmaxf((a.z + b.z) * bnscale * bng[n + 2] + bnb[n + 2], 0.f));
    o.w = f2bf(fmaxf((a.w + b.w) * bnscale * bng[n + 3] + bnb[n + 3], 0.f));
    *(ushort4*)&hb[i] = o;
}

// ---------------------------------------------------------------------------
// bev (B,C,N) f32 -> (B*N, C) bf16 ; z: 0-1 cam batches, 2-3 sat batches
// ---------------------------------------------------------------------------
__global__ __launch_bounds__(256)
void tcvt_k(const float* __restrict__ cam, const float* __restrict__ sat,
            u16* __restrict__ qcam, u16* __restrict__ qsat)
{
    __shared__ float t[64][65];
    int z = blockIdx.z;
    const float* src = (z < 2) ? cam : sat;
    u16* dst = (z < 2) ? qcam : qsat;
    int b = z & 1;
    int c0 = blockIdx.x * 64, sp0 = blockIdx.y * 64;
    #pragma unroll
    for (int it = 0; it < 16; ++it) {
        int idx = it * 256 + threadIdx.x;
        int cl = idx >> 6, sl = idx & 63;
        t[cl][sl] = src[((size_t)(b * CCn + c0 + cl)) * NNn + sp0 + sl];
    }
    __syncthreads();
    #pragma unroll
    for (int it = 0; it < 16; ++it) {
        int idx = it * 256 + threadIdx.x;
        int sl = idx >> 6, cl = idx & 63;
        dst[((size_t)(b * NNn + sp0 + sl)) * CCn + c0 + cl] = f2bf(t[cl][sl]);
    }
}

// (B,N,C) f32 -> d_out (B,C,N) f32 + cam_bev
__global__ __launch_bounds__(256)
void taddT_k(const float* __restrict__ t, const float* __restrict__ cam,
             float* __restrict__ out)
{
    __shared__ float s[64][65];
    int c0 = blockIdx.x * 64, sp0 = blockIdx.y * 64, b = blockIdx.z;
    #pragma unroll
    for (int it = 0; it < 16; ++it) {
        int idx = it * 256 + threadIdx.x;
        int sl = idx >> 6, cl = idx & 63;
        s[sl][cl] = t[(size_t)(b * NNn + sp0 + sl) * CCn + c0 + cl];
    }
    __syncthreads();
    #pragma unroll
    for (int it = 0; it < 16; ++it) {
        int idx = it * 256 + threadIdx.x;
        int cl = idx >> 6, sl = idx & 63;
        size_t oi = ((size_t)(b * CCn + c0 + cl)) * NNn + sp0 + sl;
        out[oi] = s[sl][cl] + cam[oi];
    }
}

// ---------------------------------------------------------------------------
// deformable sampling, softmax over NP=4 fused; 4 channels / thread
// z = blockIdx.z selects c2s / s2c stream (fixed strides)
// ---------------------------------------------------------------------------
__global__ __launch_bounds__(256)
void sample_k(const u16* __restrict__ val, const float* __restrict__ off,
              const float* __restrict__ lg, u16* __restrict__ outp)
{
    int z = blockIdx.z;
    val  += (size_t)z * MTOT * CCn;
    off  += (size_t)z * MTOT * 64;
    lg   += (size_t)z * MTOT * 32;
    outp += (size_t)z * MTOT * CCn;

    int t = blockIdx.x * 256 + threadIdx.x;    // MTOT*64 threads
    int d4 = (t & 7) * 4;
    int h  = (t >> 3) & 7;
    int rn = t >> 6;
    int n = rn & (NNn - 1), b = rn >> 14;
    int yp = n >> 7, xp = n & 127;

    const float* ofp = off + (size_t)rn * 64 + h * 8;
    const float* lgp = lg  + (size_t)rn * 32 + h * 4;

    float l0 = lgp[0], l1 = lgp[1], l2 = lgp[2], l3 = lgp[3];
    float mx = fmaxf(fmaxf(l0, l1), fmaxf(l2, l3));
    float e0 = __expf(l0 - mx), e1 = __expf(l1 - mx), e2 = __expf(l2 - mx), e3 = __expf(l3 - mx);
    float inv = 1.f / (e0 + e1 + e2 + e3);
    float aw[4] = { e0 * inv, e1 * inv, e2 * inv, e3 * inv };

    const u16* vb = val + (size_t)b * NNn * CCn + h * 32 + d4;
    float a[4] = {0.f, 0.f, 0.f, 0.f};
    #pragma unroll
    for (int p = 0; p < 4; ++p) {
        float xs = (float)xp + ofp[p * 2 + 0];
        float ys = (float)yp + ofp[p * 2 + 1];
        float x0f = floorf(xs), y0f = floorf(ys);
        float lx = xs - x0f, ly = ys - y0f;
        int x0 = (int)x0f, y0 = (int)y0f;
        #pragma unroll
        for (int cy = 0; cy < 2; ++cy) {
            #pragma unroll
            for (int cx = 0; cx < 2; ++cx) {
                int xi = x0 + cx, yi = y0 + cy;
                float wgt = aw[p] * (cx ? lx : 1.f - lx) * (cy ? ly : 1.f - ly);
                if (xi >= 0 && xi < WWn && yi >= 0 && yi < HHn) {
                    ushort4 vv = *(const ushort4*)(vb + (size_t)(yi * WWn + xi) * CCn);
                    a[0] += wgt * bf2f(vv.x);
                    a[1] += wgt * bf2f(vv.y);
                    a[2] += wgt * bf2f(vv.z);
                    a[3] += wgt * bf2f(vv.w);
                }
            }
        }
    }
    ushort4 o;
    o.x = f2bf(a[0]); o.y = f2bf(a[1]); o.z = f2bf(a[2]); o.w = f2bf(a[3]);
    *(ushort4*)(outp + (size_t)rn * CCn + h * 32 + d4) = o;
}

// ---------------------------------------------------------------------------
// all weight repacks + bias/LN packing in one kernel
// wbase layout (u16 elems):
//   0      wvp1 | 65536  wvp2 | 131072 wop1 | 196608 wop2
//   262144 wf1 131072   | 393216 wf2 131072
//   524288 woa1 32768   | 557056 woa2 32768
//   589824 wcv 589824   | 1179648 wg2 32768     total 1212416
// biasbuf layout (f32): 0 vp_b c2s | 256 vp_b s2c | 512 op_b c2s | 768 op_b s2c
//   1024 off_b c2s(64) | 1088 attw_b c2s(32) | 1120 off_b s2c | 1184 attw_b s2c
//   1216 ln1_g | 1472 ln1_b | 1728 ln2_g | 1984 ln2_b        total 2240
// ---------------------------------------------------------------------------
__global__ __launch_bounds__(256)
void repack_all(const float* __restrict__ vp1, const float* __restrict__ op1,
                const float* __restrict__ vp2, const float* __restrict__ op2,
                const float* __restrict__ f1w, const float* __restrict__ f2w,
                const float* __restrict__ of1, const float* __restrict__ aw1,
                const float* __restrict__ of2, const float* __restrict__ aw2,
                const float* __restrict__ g1,  const float* __restrict__ g2,
                const float* __restrict__ vpb1, const float* __restrict__ vpb2,
                const float* __restrict__ opb1, const float* __restrict__ opb2,
                const float* __restrict__ ofb1, const float* __restrict__ awb1,
                const float* __restrict__ ofb2, const float* __restrict__ awb2,
                const float* __restrict__ l1g, const float* __restrict__ l1b,
                const float* __restrict__ l2g, const float* __restrict__ l2b,
                u16* __restrict__ wb, float* __restrict__ bb)
{
    int i = blockIdx.x * 256 + threadIdx.x;
    if (i >= 1212416 + 2240) return;
    if (i >= 1212416) {
        int j = i - 1212416;
        float v;
        if      (j < 256)  v = vpb1[j];
        else if (j < 512)  v = vpb2[j - 256];
        else if (j < 768)  v = opb1[j - 512];
        else if (j < 1024) v = opb2[j - 768];
        else if (j < 1088) v = ofb1[j - 1024];
        else if (j < 1120) v = awb1[j - 1088];
        else if (j < 1184) v = ofb2[j - 1120];
        else if (j < 1216) v = awb2[j - 1184];
        else if (j < 1472) v = l1g[j - 1216];
        else if (j < 1728) v = l1b[j - 1472];
        else if (j < 1984) v = l2g[j - 1728];
        else               v = l2b[j - 1984];
        bb[j] = v;
        return;
    }
    float v;
    if (i < 262144) {
        const float* src[4] = { vp1, vp2, op1, op2 };
        int q = i >> 16, j = i & 65535;
        int n = j >> 8, k = j & 255;
        v = src[q][(size_t)k * 256 + n];
    } else if (i < 393216) {
        int j = i - 262144; int n = j >> 8, k = j & 255;      // [512][256]
        v = f1w[(size_t)k * 512 + n];
    } else if (i < 524288) {
        int j = i - 393216; int n = j >> 9, k = j & 511;      // [256][512]
        v = f2w[(size_t)k * 256 + n];
    } else if (i < 589824) {
        int jj = i - 524288; int hh = jj >> 15; int j = jj & 32767;
        int n = j >> 8, k = j & 255;                          // [128][256]
        const float* ofw = hh ? of2 : of1;
        const float* aww = hh ? aw2 : aw1;
        if (n < 64)      v = ofw[(size_t)k * 64 + n];
        else if (n < 96) v = aww[(size_t)k * 32 + (n - 64)];
        else             v = 0.f;
    } else if (i < 1179648) {
        int j = i - 589824; int co = j / 4608, k = j - co * 4608;
        int tap = k >> 9, ci = k & 511;
        v = g1[((size_t)co * 512 + ci) * 9 + tap];
    } else {
        int j = i - 1179648; int n = j >> 7, k = j & 127;     // [256][128]
        v = g2[(size_t)n * 128 + k];
    }
    wb[i] = f2bf(v);
}

// ---------------------------------------------------------------------------
extern "C" void kernel_launch(void* const* d_in, const int* in_sizes, int n_in,
                              void* d_out, int out_size, void* d_ws, size_t ws_size,
                              hipStream_t stream)
{
    const float* cam_bev   = (const float*)d_in[0];
    const float* sat_bev   = (const float*)d_in[1];
    const float* c2s_off_w  = (const float*)d_in[2];
    const float* c2s_off_b  = (const float*)d_in[3];
    const float* c2s_attw_w = (const float*)d_in[4];
    const float* c2s_attw_b = (const float*)d_in[5];
    const float* c2s_vp_w   = (const float*)d_in[6];
    const float* c2s_vp_b   = (const float*)d_in[7];
    const float* c2s_op_w   = (const float*)d_in[8];
    const float* c2s_op_b   = (const float*)d_in[9];
    const float* s2c_off_w  = (const float*)d_in[10];
    const float* s2c_off_b  = (const float*)d_in[11];
    const float* s2c_attw_w = (const float*)d_in[12];
    const float* s2c_attw_b = (const float*)d_in[13];
    const float* s2c_vp_w   = (const float*)d_in[14];
    const float* s2c_vp_b   = (const float*)d_in[15];
    const float* s2c_op_w   = (const float*)d_in[16];
    const float* s2c_op_b   = (const float*)d_in[17];
    const float* ln1_g = (const float*)d_in[18];
    const float* ln1_b = (const float*)d_in[19];
    const float* ln2_g = (const float*)d_in[20];
    const float* ln2_b = (const float*)d_in[21];
    const float* lnf_g = (const float*)d_in[22];
    const float* lnf_b = (const float*)d_in[23];
    const float* ffn1_w = (const float*)d_in[24];
    const float* ffn1_b = (const float*)d_in[25];
    const float* ffn2_w = (const float*)d_in[26];
    const float* ffn2_b = (const float*)d_in[27];
    const float* g1_w  = (const float*)d_in[28];
    const float* bn_g  = (const float*)d_in[29];
    const float* bn_b  = (const float*)d_in[30];
    const float* g2_w  = (const float*)d_in[31];
    const float* g2_b  = (const float*)d_in[32];

    char* base = (char*)d_ws;
    size_t off = 0;
    auto alloc = [&](size_t bytes) -> void* {
        void* p = base + off;
        off += (bytes + 255) & ~(size_t)255;
        return p;
    };

    u16*   qcam   = (u16*)  alloc((size_t)MTOT * CCn * 2 * 2);   // qcam|qsat contiguous
    u16*   qsat   = qcam + (size_t)MTOT * CCn;
    u16*   valb   = (u16*)  alloc((size_t)MTOT * CCn * 2 * 2);   // pair
    u16*   sampb  = (u16*)  alloc((size_t)MTOT * CCn * 2 * 2);   // pair
    float* offb   = (float*)alloc((size_t)MTOT * 64 * 4 * 2);    // pair
    float* attwb  = (float*)alloc((size_t)MTOT * 32 * 4 * 2);    // pair
    size_t padBytes = (size_t)BBn * PADW * PADW * 512 * 2;       // 34.6MB
    u16*   pad    = (u16*)  alloc(padBytes);
    u16*   hbuf   = (u16*)  alloc((size_t)MTOT * 128 * 2);
    float* fusedf = (float*)alloc((size_t)MTOT * CCn * 4);
    u16*   wbase  = (u16*)  alloc((size_t)1212416 * 2);
    float* biasbf = (float*)alloc((size_t)2240 * 4);
    // weight slices
    u16* wvp = wbase;                 // pair, stride 65536
    u16* wop = wbase + 131072;        // pair, stride 65536
    u16* wf1 = wbase + 262144;
    u16* wf2 = wbase + 393216;
    u16* woa = wbase + 524288;        // pair, stride 32768
    u16* wcv = wbase + 589824;
    u16* wg2 = wbase + 1179648;
    // aliases (temporally disjoint)
    u16*   fused_bf = valb;              // valb dead after sampling
    float* convpart = (float*)sampb;     // sampb dead after op_both (2x MTOT*128 f32)
    float* tbuf     = (float*)sampb;     // dead after combine
    u16*   midb     = qcam;              // qcam/qsat dead after op_both (MTOT*512 bf16)

    dim3 blk(256);
    ZOff zz{0, 0, 0, 0, 0, 0, 0, 0, 0, 0};

    hipMemsetAsync(pad, 0, padBytes, stream);
    tcvt_k<<<dim3(4, 256, 4), blk, 0, stream>>>(cam_bev, sat_bev, qcam, qsat);
    repack_all<<<4746, blk, 0, stream>>>(c2s_vp_w, c2s_op_w, s2c_vp_w, s2c_op_w,
                                         ffn1_w, ffn2_w, c2s_off_w, c2s_attw_w,
                                         s2c_off_w, s2c_attw_w, g1_w, g2_w,
                                         c2s_vp_b, s2c_vp_b, c2s_op_b, s2c_op_b,
                                         c2s_off_b, c2s_attw_b, s2c_off_b, s2c_attw_b,
                                         ln1_g, ln1_b, ln2_g, ln2_b,
                                         wbase, biasbf);

    // ---------- value projections (z=0: kv=sat, z=1: kv=cam) ----------
    {
        ZOff zo{ -(long)MTOT * CCn, 65536, 256, 0, 0, (long)MTOT * CCn, 0, 0, 0, 0 };
        mgemm<128, 128, 2, 0, 0><<<dim3(2, 256, 2), blk, 0, stream>>>(
            qsat, wvp, biasbf, 256, 256, 256,
            nullptr, nullptr, valb, nullptr, nullptr, nullptr, nullptr, 0, zo);
    }
    // ---------- offset+attw projections (z=0: q=cam, z=1: q=sat) ----------
    {
        ZOff zo{ (long)MTOT * CCn, 32768, 0, (long)MTOT * 64, (long)MTOT * 32, 0, 0, 96, 0, 0 };
        mgemm<128, 128, 2, 0, 2><<<dim3(1, 256, 2), blk, 0, stream>>>(
            qcam, woa, nullptr, 256, 256, 128,
            offb, attwb, nullptr, nullptr, nullptr, biasbf + 1024, biasbf + 1088, 0, zo);
    }
    // ---------- deformable sampling (both streams) ----------
    sample_k<<<dim3(8192, 1, 2), blk, 0, stream>>>(valb, offb, attwb, sampb);
    // ---------- output projections + residual + LN -> pad image ----------
    {
        ZOff zo{ (long)MTOT * CCn, 65536, 256, 0, 0, 0, (long)MTOT * CCn, 512, 256, 0 };
        mgemm<64, 256, 4, 0, 7><<<dim3(1, 512, 2), blk, 0, stream>>>(
            sampb, wop, biasbf + 512, 256, 256, 256,
            nullptr, nullptr, pad, nullptr, qcam, biasbf + 1216, biasbf + 1472, 0, zo);
    }
    // ---------- gating conv: implicit GEMM, split-K=2, f32 partials ----------
    {
        ZOff zo{ 0, 0, 0, (long)MTOT * 128, 0, 0, 0, 0, 0, 2304 };
        mgemm<128, 128, 2, 1, 1><<<dim3(1, 256, 2), blk, 0, stream>>>(
            nullptr, wcv, nullptr, 2304, 4608, 128,
            convpart, nullptr, nullptr, pad, nullptr, nullptr, nullptr, 0, zo);
    }
    combine_k<<<4096, blk, 0, stream>>>(convpart, bn_g, bn_b, hbuf);

    // ---------- 1x1 conv + sigmoid + gated fusion ----------
    mgemm<128, 128, 2, 0, 4><<<dim3(2, 256, 1), blk, 0, stream>>>(
        hbuf, wg2, g2_b, 128, 128, 256,
        fusedf, nullptr, fused_bf, pad, nullptr, nullptr, nullptr, 0, zz);

    // ---------- FFN ----------
    mgemm<128, 128, 2, 0, 5><<<dim3(4, 256, 1), blk, 0, stream>>>(
        fused_bf, wf1, ffn1_b, 256, 256, 512,
        nullptr, nullptr, midb, nullptr, nullptr, nullptr, nullptr, 0, zz);
    mgemm<64, 256, 4, 0, 8><<<dim3(1, 512, 1), blk, 0, stream>>>(
        midb, wf2, ffn2_b, 512, 512, 256,
        tbuf, nullptr, nullptr, nullptr, fusedf, lnf_g, lnf_b, 0, zz);

    // ---------- transpose back to (B,C,H,W) + cam_bev residual ----------
    taddT_k<<<dim3(4, 256, 2), blk, 0, stream>>>(tbuf, cam_bev, (float*)d_out);
}

// Round 7
// 344.821 us; speedup vs baseline: 5.0463x; 1.0136x over previous
//
#include <hip/hip_runtime.h>
#include <hip/hip_bf16.h>
#include <cstddef>

#define BBn  2
#define CCn  256
#define HHn  128
#define WWn  128
#define NNn  (HHn*WWn)        // 16384
#define MTOT (BBn*NNn)        // 32768
#define PADW 130

typedef unsigned short u16;
typedef __attribute__((ext_vector_type(8))) short bf8v;
typedef __attribute__((ext_vector_type(4))) float f4v;

typedef __attribute__((address_space(1))) const void gvoid_t;
typedef __attribute__((address_space(3))) void svoid_t;
#define ASYNC16(g, l) __builtin_amdgcn_global_load_lds((gvoid_t*)(g), (svoid_t*)(l), 16, 0, 0)

__device__ __forceinline__ u16 f2bf(float f) {
    __hip_bfloat16 h = __float2bfloat16(f);
    return *reinterpret_cast<u16*>(&h);
}
__device__ __forceinline__ float bf2f(u16 h) {
    return __uint_as_float(((unsigned)h) << 16);
}

// z-offsets (elements), applied scaled by blockIdx.z
struct ZOff {
    long a, w, bia, f1, f2, b1, r, p;
    int ch;
};

// ---------------------------------------------------------------------------
// bf16 MFMA GEMM, tile BM x BN, BK=32, 4 waves arranged WRxWC (WR=4/WC).
// ALOAD 0: A[M,KK] bf16 row-major (stride KK).
// ALOAD 1: padded conv image (B,130,130,512) bf16; KK = taps per z (x512 K).
// Wt[Nc,ldw] bf16 pre-transposed.
// EPI: 0 bf16+bias | 1 raw f32 (split-K partial) | 2 off/attw split
//      4 sigmoid-gate | 5 ReLU->bf16
//      7 resid-init + rowLN -> pad bf16 | 9 resid-init + rowLN -> (B,C,N) + cam
// ---------------------------------------------------------------------------
template<int BM, int BN, int WC, int ALOAD, int EPI, int KK>
__global__ __launch_bounds__(256)
void mgemm(const u16* __restrict__ A, const u16* __restrict__ Wt,
           const float* __restrict__ bias, int ldw, int Nc,
           float* __restrict__ outf, float* __restrict__ outf2,
           u16* __restrict__ outb, const u16* __restrict__ img,
           const void* __restrict__ resid,
           const float* __restrict__ p0, const float* __restrict__ p1,
           int choff, ZOff zo)
{
    constexpr int WR = 4 / WC;
    constexpr int MROWS = BM / WR;       // rows per wave
    constexpr int MI = MROWS / 16;
    constexpr int AT = BM / 64;          // A staging chunks per thread
    constexpr int BT = BN / 64;

    __shared__ __align__(16) u16 As[BM * 32];
    __shared__ __align__(16) u16 Bs[BN * 32];
    __shared__ float red[4][64][2];      // LN cross-wave partials (EPI 7/9)

    const int z = blockIdx.z;
    if (z) {
        A += (long)z * zo.a; Wt += (long)z * zo.w;
        if (bias)  bias  += (long)z * zo.bia;
        if (outf)  outf  += (long)z * zo.f1;
        if (outf2) outf2 += (long)z * zo.f2;
        if (outb)  outb  += (long)z * zo.b1;
        if (p0)    p0    += (long)z * zo.p;
        if (p1)    p1    += (long)z * zo.p;
        choff += z * zo.ch;
    }

    const int tid  = threadIdx.x;
    const int lane = tid & 63;
    const int w    = tid >> 6;
    const int wr   = w / WC, wc = w % WC;
    int by = blockIdx.y;
    if constexpr (ALOAD == 1) by = ((by & 7) << 5) | (by >> 3);   // XCD swizzle (256=8*32)
    const int m0 = by * BM;
    const int n0 = blockIdx.x * BN;
    const int lr = lane & 15, lq = lane >> 4;
    const int kb = lq * 8;

    // staging source pointers
    const u16* gA[AT]; long cbA[AT]; int paA[AT];
    #pragma unroll
    for (int t = 0; t < AT; ++t) {
        int c = t * 256 + tid; int row = c >> 2; int part = c & 3;
        if constexpr (ALOAD == 0) {
            gA[t] = A + (size_t)(m0 + row) * KK + part * 8;
        } else {
            int m = m0 + row; int b = m >> 14; int sp = m & (NNn - 1);
            cbA[t] = ((long)b * PADW + (sp >> 7)) * PADW + (sp & 127);
            paA[t] = part;
        }
    }
    const u16* gB[BT];
    #pragma unroll
    for (int t = 0; t < BT; ++t) {
        int c = t * 256 + tid; int row = c >> 2; int part = c & 3;
        gB[t] = Wt + (size_t)(n0 + row) * ldw + part * 8;
    }

    // accumulator (residual+bias init for LN epilogues; WR==1 there)
    f4v acc[MI][4];
    if constexpr (EPI == 7 || EPI == 9) {
        const u16*   r16 = (const u16*)resid   + (EPI == 7 ? (long)z * zo.r : 0);
        const float* r32 = (const float*)resid;
        #pragma unroll
        for (int j = 0; j < 4; ++j) {
            int n = wc * 64 + j * 16 + lr;
            float bj = bias[n];
            #pragma unroll
            for (int i = 0; i < MI; ++i)
                #pragma unroll
                for (int r = 0; r < 4; ++r) {
                    int m = m0 + i * 16 + lq * 4 + r;
                    float rv;
                    if constexpr (EPI == 7) rv = bf2f(r16[(size_t)m * 256 + n]);
                    else                    rv = r32[(size_t)m * 256 + n];
                    acc[i][j][r] = rv + bj;
                }
        }
    } else {
        #pragma unroll
        for (int i = 0; i < MI; ++i)
            #pragma unroll
            for (int j = 0; j < 4; ++j)
                acc[i][j] = (f4v){0.f, 0.f, 0.f, 0.f};
    }

    auto kstep = [&](auto stageA, const u16* gBt[BT], int koff) {
        #pragma unroll
        for (int t = 0; t < AT; ++t) stageA(t);
        #pragma unroll
        for (int t = 0; t < BT; ++t)
            ASYNC16(gBt[t] + koff, (u16*)Bs + (t * 256 + tid) * 8);
        __syncthreads();
        bf8v af[MI], bv[4];
        #pragma unroll
        for (int i = 0; i < MI; ++i)
            af[i] = *(const bf8v*)&As[(wr * MROWS + i * 16 + lr) * 32 + kb];
        #pragma unroll
        for (int j = 0; j < 4; ++j)
            bv[j] = *(const bf8v*)&Bs[(wc * 64 + j * 16 + lr) * 32 + kb];
        #pragma unroll
        for (int i = 0; i < MI; ++i)
            #pragma unroll
            for (int j = 0; j < 4; ++j)
                acc[i][j] = __builtin_amdgcn_mfma_f32_16x16x32_bf16(af[i], bv[j], acc[i][j], 0, 0, 0);
        __syncthreads();
    };

    if constexpr (ALOAD == 0) {
        for (int k0 = 0; k0 < KK; k0 += 32) {
            kstep([&](int t) {
                ASYNC16(gA[t] + k0, (u16*)As + (t * 256 + tid) * 8);
            }, gB, k0);
        }
    } else {
        const int tap0 = z * KK;
        #pragma unroll
        for (int tt = 0; tt < KK; ++tt) {
            int tap = tap0 + tt;
            int dy = tap / 3, dx = tap - dy * 3;
            const u16* bpA[AT]; const u16* gBt[BT];
            #pragma unroll
            for (int t = 0; t < AT; ++t)
                bpA[t] = img + (size_t)(cbA[t] + dy * PADW + dx) * 512 + paA[t] * 8;
            #pragma unroll
            for (int t = 0; t < BT; ++t)
                gBt[t] = gB[t] + tap * 512;
            #pragma unroll 2
            for (int ci = 0; ci < 512; ci += 32) {
                kstep([&](int t) {
                    ASYNC16(bpA[t] + ci, (u16*)As + (t * 256 + tid) * 8);
                }, gBt, ci);
            }
        }
    }

    // -------------------- epilogue --------------------
    if constexpr (EPI == 7 || EPI == 9) {
        float g4[4], b4[4];
        #pragma unroll
        for (int j = 0; j < 4; ++j) {
            int n = wc * 64 + j * 16 + lr;
            g4[j] = p0[n]; b4[j] = p1[n];
        }
        #pragma unroll
        for (int i = 0; i < MI; ++i)
            #pragma unroll
            for (int r = 0; r < 4; ++r) {
                float p = 0.f, p2 = 0.f;
                #pragma unroll
                for (int j = 0; j < 4; ++j) { float v = acc[i][j][r]; p += v; p2 += v * v; }
                p += __shfl_xor(p, 1, 16);  p2 += __shfl_xor(p2, 1, 16);
                p += __shfl_xor(p, 2, 16);  p2 += __shfl_xor(p2, 2, 16);
                p += __shfl_xor(p, 4, 16);  p2 += __shfl_xor(p2, 4, 16);
                p += __shfl_xor(p, 8, 16);  p2 += __shfl_xor(p2, 8, 16);
                if (lr == 0) {
                    int row = i * 16 + lq * 4 + r;
                    red[w][row][0] = p; red[w][row][1] = p2;
                }
            }
        __syncthreads();
        #pragma unroll
        for (int i = 0; i < MI; ++i) {
            float mean4[4], rstd4[4];
            #pragma unroll
            for (int r = 0; r < 4; ++r) {
                int row = i * 16 + lq * 4 + r;
                float s  = red[0][row][0] + red[1][row][0] + red[2][row][0] + red[3][row][0];
                float s2 = red[0][row][1] + red[1][row][1] + red[2][row][1] + red[3][row][1];
                float mean = s * (1.f / 256.f);
                float var  = s2 * (1.f / 256.f) - mean * mean;
                mean4[r] = mean;
                rstd4[r] = rsqrtf(var + 1e-5f);
            }
            if constexpr (EPI == 7) {
                #pragma unroll
                for (int r = 0; r < 4; ++r) {
                    int m = m0 + i * 16 + lq * 4 + r;
                    int b = m >> 14, sp = m & (NNn - 1);
                    size_t pb = (((size_t)b * PADW + (sp >> 7) + 1) * PADW + (sp & 127) + 1) * 512 + choff;
                    #pragma unroll
                    for (int j = 0; j < 4; ++j) {
                        int n = wc * 64 + j * 16 + lr;
                        outb[pb + n] = f2bf((acc[i][j][r] - mean4[r]) * rstd4[r] * g4[j] + b4[j]);
                    }
                }
            } else {
                // transposed write to (B,C,N) + cam residual (outf2 = cam_bev)
                int mb = m0 + i * 16 + lq * 4;
                int b = mb >> 14, sp = mb & (NNn - 1);
                #pragma unroll
                for (int j = 0; j < 4; ++j) {
                    int n = wc * 64 + j * 16 + lr;
                    size_t oi = ((size_t)b * 256 + n) * NNn + sp;
                    float4 cv = *(const float4*)&outf2[oi];
                    float4 o;
                    o.x = (acc[i][j][0] - mean4[0]) * rstd4[0] * g4[j] + b4[j] + cv.x;
                    o.y = (acc[i][j][1] - mean4[1]) * rstd4[1] * g4[j] + b4[j] + cv.y;
                    o.z = (acc[i][j][2] - mean4[2]) * rstd4[2] * g4[j] + b4[j] + cv.z;
                    o.w = (acc[i][j][3] - mean4[3]) * rstd4[3] * g4[j] + b4[j] + cv.w;
                    *(float4*)&outf[oi] = o;
                }
            }
        }
        return;
    }

    float bj[4]; int ncol[4];
    #pragma unroll
    for (int j = 0; j < 4; ++j) {
        int n = n0 + wc * 64 + j * 16 + lr;
        ncol[j] = n;
        if constexpr (EPI == 0 || EPI == 4 || EPI == 5) bj[j] = bias[n];
    }
    #pragma unroll
    for (int i = 0; i < MI; ++i) {
        #pragma unroll
        for (int r = 0; r < 4; ++r) {
            int m = m0 + wr * MROWS + i * 16 + lq * 4 + r;
            size_t pb = 0;
            if constexpr (EPI == 4) {
                int b = m >> 14, sp = m & (NNn - 1);
                pb = (((size_t)b * PADW + (sp >> 7) + 1) * PADW + (sp & 127) + 1) * 512;
            }
            #pragma unroll
            for (int j = 0; j < 4; ++j) {
                int n = ncol[j];
                float v = acc[i][j][r];
                size_t oi = (size_t)m * Nc + n;
                if constexpr (EPI == 0) {
                    outb[oi] = f2bf(v + bj[j]);
                } else if constexpr (EPI == 1) {
                    outf[oi] = v;
                } else if constexpr (EPI == 2) {
                    if (n < 64)      outf [(size_t)m * 64 + n]        = v + p0[n];
                    else if (n < 96) outf2[(size_t)m * 32 + (n - 64)] = v + p1[n - 64];
                } else if constexpr (EPI == 4) {
                    float vv = v + bj[j];
                    float g = 1.f / (1.f + __expf(-vv));
                    float f = g * bf2f(img[pb + n]) + (1.f - g) * bf2f(img[pb + 256 + n]);
                    outf[oi] = f; outb[oi] = f2bf(f);
                } else if constexpr (EPI == 5) {
                    outb[oi] = f2bf(fmaxf(v + bj[j], 0.f));
                }
            }
        }
    }
}

// ---------------------------------------------------------------------------
// split-K combine (3 partials) + BN + ReLU -> bf16
// ---------------------------------------------------------------------------
__global__ __launch_bounds__(256)
void combine_k(const float* __restrict__ part, const float* __restrict__ bng,
               const float* __restrict__ bnb, u16* __restrict__ hb)
{
    const float bnscale = rsqrtf(1.0f + 1e-5f);
    int i = (blockIdx.x * 256 + threadIdx.x) * 4;   // over MTOT*128
    int n = i & 127;
    float4 a = *(const float4*)&part[i];
    float4 b = *(const float4*)&part[(size_t)MTOT * 128 + i];
    float4 c = *(const float4*)&part[(size_t)MTOT * 256 + i];
    ushort4 o;
    o.x = f2bf(fmaxf((a.x + b.x + c.x) * bnscale * bng[n + 0] + bnb[n + 0], 0.f));
    o.y = f2bf(fmaxf((a.y + b.y + c.y) * bnscale * bng[n + 1] + bnb[n + 1], 0.f));
    o.z = f2bf(fmaxf((a.z + b.z + c.z) * bnscale * bng[n + 2] + bnb[n + 2], 0.f));
    o.w = f2bf(fmaxf((a.w + b.w + c.w) * bnscale * bng[n + 3] + bnb[n + 3], 0.f));
    *(ushort4*)&hb[i] = o;
}

// ---------------------------------------------------------------------------
// bev (B,C,N) f32 -> (B*N, C) bf16 ; z: 0-1 cam batches, 2-3 sat batches
// ---------------------------------------------------------------------------
__global__ __launch_bounds__(256)
void tcvt_k(const float* __restrict__ cam, const float* __restrict__ sat,
            u16* __restrict__ qcam, u16* __restrict__ qsat)
{
    __shared__ float t[64][65];
    int z = blockIdx.z;
    const float* src = (z < 2) ? cam : sat;
    u16* dst = (z < 2) ? qcam : qsat;
    int b = z & 1;
    int c0 = blockIdx.x * 64, sp0 = blockIdx.y * 64;
    #pragma unroll
    for (int it = 0; it < 16; ++it) {
        int idx = it * 256 + threadIdx.x;
        int cl = idx >> 6, sl = idx & 63;
        t[cl][sl] = src[((size_t)(b * CCn + c0 + cl)) * NNn + sp0 + sl];
    }
    __syncthreads();
    #pragma unroll
    for (int it = 0; it < 16; ++it) {
        int idx = it * 256 + threadIdx.x;
        int sl = idx >> 6, cl = idx & 63;
        dst[((size_t)(b * NNn + sp0 + sl)) * CCn + c0 + cl] = f2bf(t[cl][sl]);
    }
}

// ---------------------------------------------------------------------------
// deformable sampling, softmax over NP=4 fused; 4 channels / thread
// z = blockIdx.z selects c2s / s2c stream (fixed strides)
// ---------------------------------------------------------------------------
__global__ __launch_bounds__(256)
void sample_k(const u16* __restrict__ val, const float* __restrict__ off,
              const float* __restrict__ lg, u16* __restrict__ outp)
{
    int z = blockIdx.z;
    val  += (size_t)z * MTOT * CCn;
    off  += (size_t)z * MTOT * 64;
    lg   += (size_t)z * MTOT * 32;
    outp += (size_t)z * MTOT * CCn;

    int t = blockIdx.x * 256 + threadIdx.x;    // MTOT*64 threads
    int d4 = (t & 7) * 4;
    int h  = (t >> 3) & 7;
    int rn = t >> 6;
    int n = rn & (NNn - 1), b = rn >> 14;
    int yp = n >> 7, xp = n & 127;

    const float* ofp = off + (size_t)rn * 64 + h * 8;
    const float* lgp = lg  + (size_t)rn * 32 + h * 4;

    float l0 = lgp[0], l1 = lgp[1], l2 = lgp[2], l3 = lgp[3];
    float mx = fmaxf(fmaxf(l0, l1), fmaxf(l2, l3));
    float e0 = __expf(l0 - mx), e1 = __expf(l1 - mx), e2 = __expf(l2 - mx), e3 = __expf(l3 - mx);
    float inv = 1.f / (e0 + e1 + e2 + e3);
    float aw[4] = { e0 * inv, e1 * inv, e2 * inv, e3 * inv };

    const u16* vb = val + (size_t)b * NNn * CCn + h * 32 + d4;
    float a[4] = {0.f, 0.f, 0.f, 0.f};
    #pragma unroll
    for (int p = 0; p < 4; ++p) {
        float xs = (float)xp + ofp[p * 2 + 0];
        float ys = (float)yp + ofp[p * 2 + 1];
        float x0f = floorf(xs), y0f = floorf(ys);
        float lx = xs - x0f, ly = ys - y0f;
        int x0 = (int)x0f, y0 = (int)y0f;
        #pragma unroll
        for (int cy = 0; cy < 2; ++cy) {
            #pragma unroll
            for (int cx = 0; cx < 2; ++cx) {
                int xi = x0 + cx, yi = y0 + cy;
                float wgt = aw[p] * (cx ? lx : 1.f - lx) * (cy ? ly : 1.f - ly);
                if (xi >= 0 && xi < WWn && yi >= 0 && yi < HHn) {
                    ushort4 vv = *(const ushort4*)(vb + (size_t)(yi * WWn + xi) * CCn);
                    a[0] += wgt * bf2f(vv.x);
                    a[1] += wgt * bf2f(vv.y);
                    a[2] += wgt * bf2f(vv.z);
                    a[3] += wgt * bf2f(vv.w);
                }
            }
        }
    }
    ushort4 o;
    o.x = f2bf(a[0]); o.y = f2bf(a[1]); o.z = f2bf(a[2]); o.w = f2bf(a[3]);
    *(ushort4*)(outp + (size_t)rn * CCn + h * 32 + d4) = o;
}

// ---------------------------------------------------------------------------
// all weight repacks + bias/LN packing in one kernel (layouts in comments of r3)
// ---------------------------------------------------------------------------
__global__ __launch_bounds__(256)
void repack_all(const float* __restrict__ vp1, const float* __restrict__ op1,
                const float* __restrict__ vp2, const float* __restrict__ op2,
                const float* __restrict__ f1w, const float* __restrict__ f2w,
                const float* __restrict__ of1, const float* __restrict__ aw1,
                const float* __restrict__ of2, const float* __restrict__ aw2,
                const float* __restrict__ g1,  const float* __restrict__ g2,
                const float* __restrict__ vpb1, const float* __restrict__ vpb2,
                const float* __restrict__ opb1, const float* __restrict__ opb2,
                const float* __restrict__ ofb1, const float* __restrict__ awb1,
                const float* __restrict__ ofb2, const float* __restrict__ awb2,
                const float* __restrict__ l1g, const float* __restrict__ l1b,
                const float* __restrict__ l2g, const float* __restrict__ l2b,
                u16* __restrict__ wb, float* __restrict__ bb)
{
    int i = blockIdx.x * 256 + threadIdx.x;
    if (i >= 1212416 + 2240) return;
    if (i >= 1212416) {
        int j = i - 1212416;
        float v;
        if      (j < 256)  v = vpb1[j];
        else if (j < 512)  v = vpb2[j - 256];
        else if (j < 768)  v = opb1[j - 512];
        else if (j < 1024) v = opb2[j - 768];
        else if (j < 1088) v = ofb1[j - 1024];
        else if (j < 1120) v = awb1[j - 1088];
        else if (j < 1184) v = ofb2[j - 1120];
        else if (j < 1216) v = awb2[j - 1184];
        else if (j < 1472) v = l1g[j - 1216];
        else if (j < 1728) v = l1b[j - 1472];
        else if (j < 1984) v = l2g[j - 1728];
        else               v = l2b[j - 1984];
        bb[j] = v;
        return;
    }
    float v;
    if (i < 262144) {
        const float* src[4] = { vp1, vp2, op1, op2 };
        int q = i >> 16, j = i & 65535;
        int n = j >> 8, k = j & 255;
        v = src[q][(size_t)k * 256 + n];
    } else if (i < 393216) {
        int j = i - 262144; int n = j >> 8, k = j & 255;      // [512][256]
        v = f1w[(size_t)k * 512 + n];
    } else if (i < 524288) {
        int j = i - 393216; int n = j >> 9, k = j & 511;      // [256][512]
        v = f2w[(size_t)k * 256 + n];
    } else if (i < 589824) {
        int jj = i - 524288; int hh = jj >> 15; int j = jj & 32767;
        int n = j >> 8, k = j & 255;                          // [128][256]
        const float* ofw = hh ? of2 : of1;
        const float* aww = hh ? aw2 : aw1;
        if (n < 64)      v = ofw[(size_t)k * 64 + n];
        else if (n < 96) v = aww[(size_t)k * 32 + (n - 64)];
        else             v = 0.f;
    } else if (i < 1179648) {
        int j = i - 589824; int co = j / 4608, k = j - co * 4608;
        int tap = k >> 9, ci = k & 511;
        v = g1[((size_t)co * 512 + ci) * 9 + tap];
    } else {
        int j = i - 1179648; int n = j >> 7, k = j & 127;     // [256][128]
        v = g2[(size_t)n * 128 + k];
    }
    wb[i] = f2bf(v);
}

// ---------------------------------------------------------------------------
extern "C" void kernel_launch(void* const* d_in, const int* in_sizes, int n_in,
                              void* d_out, int out_size, void* d_ws, size_t ws_size,
                              hipStream_t stream)
{
    const float* cam_bev   = (const float*)d_in[0];
    const float* sat_bev   = (const float*)d_in[1];
    const float* c2s_off_w  = (const float*)d_in[2];
    const float* c2s_off_b  = (const float*)d_in[3];
    const float* c2s_attw_w = (const float*)d_in[4];
    const float* c2s_attw_b = (const float*)d_in[5];
    const float* c2s_vp_w   = (const float*)d_in[6];
    const float* c2s_vp_b   = (const float*)d_in[7];
    const float* c2s_op_w   = (const float*)d_in[8];
    const float* c2s_op_b   = (const float*)d_in[9];
    const float* s2c_off_w  = (const float*)d_in[10];
    const float* s2c_off_b  = (const float*)d_in[11];
    const float* s2c_attw_w = (const float*)d_in[12];
    const float* s2c_attw_b = (const float*)d_in[13];
    const float* s2c_vp_w   = (const float*)d_in[14];
    const float* s2c_vp_b   = (const float*)d_in[15];
    const float* s2c_op_w   = (const float*)d_in[16];
    const float* s2c_op_b   = (const float*)d_in[17];
    const float* ln1_g = (const float*)d_in[18];
    const float* ln1_b = (const float*)d_in[19];
    const float* ln2_g = (const float*)d_in[20];
    const float* ln2_b = (const float*)d_in[21];
    const float* lnf_g = (const float*)d_in[22];
    const float* lnf_b = (const float*)d_in[23];
    const float* ffn1_w = (const float*)d_in[24];
    const float* ffn1_b = (const float*)d_in[25];
    const float* ffn2_w = (const float*)d_in[26];
    const float* ffn2_b = (const float*)d_in[27];
    const float* g1_w  = (const float*)d_in[28];
    const float* bn_g  = (const float*)d_in[29];
    const float* bn_b  = (const float*)d_in[30];
    const float* g2_w  = (const float*)d_in[31];
    const float* g2_b  = (const float*)d_in[32];

    char* base = (char*)d_ws;
    size_t off = 0;
    auto alloc = [&](size_t bytes) -> void* {
        void* p = base + off;
        off += (bytes + 255) & ~(size_t)255;
        return p;
    };

    u16*   qcam   = (u16*)  alloc((size_t)MTOT * CCn * 2 * 2);   // qcam|qsat contiguous
    u16*   qsat   = qcam + (size_t)MTOT * CCn;
    u16*   valb   = (u16*)  alloc((size_t)MTOT * CCn * 2 * 2);   // pair
    u16*   sampb  = (u16*)  alloc((size_t)MTOT * CCn * 2 * 2);   // pair (33.55MB)
    float* offb   = (float*)alloc((size_t)MTOT * 64 * 4 * 2);    // pair (16.78MB)
    float* attwb  = (float*)alloc((size_t)MTOT * 32 * 4 * 2);    // pair
    size_t padBytes = (size_t)BBn * PADW * PADW * 512 * 2;       // 34.6MB
    u16*   pad    = (u16*)  alloc(padBytes);
    u16*   hbuf   = (u16*)  alloc((size_t)MTOT * 128 * 2);
    float* fusedf = (float*)alloc((size_t)MTOT * CCn * 4);
    u16*   wbase  = (u16*)  alloc((size_t)1212416 * 2);
    float* biasbf = (float*)alloc((size_t)2240 * 4);
    // weight slices
    u16* wvp = wbase;                 // pair, stride 65536
    u16* wop = wbase + 131072;        // pair, stride 65536
    u16* wf1 = wbase + 262144;
    u16* wf2 = wbase + 393216;
    u16* woa = wbase + 524288;        // pair, stride 32768
    u16* wcv = wbase + 589824;
    u16* wg2 = wbase + 1179648;
    // aliases (temporally disjoint)
    u16*   fused_bf = valb;              // valb dead after sampling
    float* convpart = (float*)sampb;     // sampb+offb dead after op-pair: 3x MTOT*128 f32 = 50.3MB
    u16*   midb     = qcam;              // qcam/qsat dead after op-pair (MTOT*512 bf16)

    dim3 blk(256);
    ZOff zz{0, 0, 0, 0, 0, 0, 0, 0, 0};

    hipMemsetAsync(pad, 0, padBytes, stream);
    tcvt_k<<<dim3(4, 256, 4), blk, 0, stream>>>(cam_bev, sat_bev, qcam, qsat);
    repack_all<<<4746, blk, 0, stream>>>(c2s_vp_w, c2s_op_w, s2c_vp_w, s2c_op_w,
                                         ffn1_w, ffn2_w, c2s_off_w, c2s_attw_w,
                                         s2c_off_w, s2c_attw_w, g1_w, g2_w,
                                         c2s_vp_b, s2c_vp_b, c2s_op_b, s2c_op_b,
                                         c2s_off_b, c2s_attw_b, s2c_off_b, s2c_attw_b,
                                         ln1_g, ln1_b, ln2_g, ln2_b,
                                         wbase, biasbf);

    // ---------- value projections (z=0: kv=sat, z=1: kv=cam) ----------
    {
        ZOff zo{ -(long)MTOT * CCn, 65536, 256, 0, 0, (long)MTOT * CCn, 0, 0, 0 };
        mgemm<128, 128, 2, 0, 0, 256><<<dim3(2, 256, 2), blk, 0, stream>>>(
            qsat, wvp, biasbf, 256, 256,
            nullptr, nullptr, valb, nullptr, nullptr, nullptr, nullptr, 0, zo);
    }
    // ---------- offset+attw projections (z=0: q=cam, z=1: q=sat) ----------
    {
        ZOff zo{ (long)MTOT * CCn, 32768, 0, (long)MTOT * 64, (long)MTOT * 32, 0, 0, 96, 0 };
        mgemm<128, 128, 2, 0, 2, 256><<<dim3(1, 256, 2), blk, 0, stream>>>(
            qcam, woa, nullptr, 256, 128,
            offb, attwb, nullptr, nullptr, nullptr, biasbf + 1024, biasbf + 1088, 0, zo);
    }
    // ---------- deformable sampling (both streams) ----------
    sample_k<<<dim3(8192, 1, 2), blk, 0, stream>>>(valb, offb, attwb, sampb);
    // ---------- output projections + residual + LN -> pad image ----------
    {
        ZOff zo{ (long)MTOT * CCn, 65536, 256, 0, 0, 0, (long)MTOT * CCn, 512, 256 };
        mgemm<64, 256, 4, 0, 7, 256><<<dim3(1, 512, 2), blk, 0, stream>>>(
            sampb, wop, biasbf + 512, 256, 256,
            nullptr, nullptr, pad, nullptr, qcam, biasbf + 1216, biasbf + 1472, 0, zo);
    }
    // ---------- gating conv: implicit GEMM, split-K=3 (3 taps/z), f32 partials ---
    {
        ZOff zo{ 0, 0, 0, (long)MTOT * 128, 0, 0, 0, 0, 0 };
        mgemm<128, 128, 2, 1, 1, 3><<<dim3(1, 256, 3), blk, 0, stream>>>(
            nullptr, wcv, nullptr, 4608, 128,
            convpart, nullptr, nullptr, pad, nullptr, nullptr, nullptr, 0, zo);
    }
    combine_k<<<4096, blk, 0, stream>>>(convpart, bn_g, bn_b, hbuf);

    // ---------- 1x1 conv + sigmoid + gated fusion ----------
    mgemm<128, 128, 2, 0, 4, 128><<<dim3(2, 256, 1), blk, 0, stream>>>(
        hbuf, wg2, g2_b, 128, 256,
        fusedf, nullptr, fused_bf, pad, nullptr, nullptr, nullptr, 0, zz);

    // ---------- FFN ----------
    mgemm<128, 128, 2, 0, 5, 256><<<dim3(4, 256, 1), blk, 0, stream>>>(
        fused_bf, wf1, ffn1_b, 256, 512,
        nullptr, nullptr, midb, nullptr, nullptr, nullptr, nullptr, 0, zz);
    // ffn2 + final LN + transpose to (B,C,N) + cam residual (EPI 9)
    mgemm<64, 256, 4, 0, 9, 512><<<dim3(1, 512, 1), blk, 0, stream>>>(
        midb, wf2, ffn2_b, 512, 256,
        (float*)d_out, (float*)cam_bev, nullptr, nullptr, fusedf, lnf_g, lnf_b, 0, zz);
}

// Round 8
// 327.481 us; speedup vs baseline: 5.3135x; 1.0530x over previous
//
#include <hip/hip_runtime.h>
#include <hip/hip_bf16.h>
#include <cstddef>

#define BBn  2
#define CCn  256
#define HHn  128
#define WWn  128
#define NNn  (HHn*WWn)        // 16384
#define MTOT (BBn*NNn)        // 32768
#define PADW 130

typedef unsigned short u16;
typedef __attribute__((ext_vector_type(8))) short bf8v;
typedef __attribute__((ext_vector_type(4))) float f4v;

typedef __attribute__((address_space(1))) const void gvoid_t;
typedef __attribute__((address_space(3))) void svoid_t;
#define ASYNC16(g, l) __builtin_amdgcn_global_load_lds((gvoid_t*)(g), (svoid_t*)(l), 16, 0, 0)

__device__ __forceinline__ u16 f2bf(float f) {
    __hip_bfloat16 h = __float2bfloat16(f);
    return *reinterpret_cast<u16*>(&h);
}
__device__ __forceinline__ float bf2f(u16 h) {
    return __uint_as_float(((unsigned)h) << 16);
}

// z-offsets (elements), applied scaled by blockIdx.z
struct ZOff {
    long a, w, bia, f1, f2, b1, r, p;
    int ch;
};

// ---------------------------------------------------------------------------
// bf16 MFMA GEMM, tile BM x BN, BK=32, 4 waves arranged WRxWC (WR=4/WC).
// ALOAD 0: A[M,KK] bf16 row-major (stride KK).
// Wt[Nc,ldw] bf16 pre-transposed.
// EPI: 0 bf16+bias | 2 off/attw split | 4 sigmoid-gate (bf16 out)
//      5 ReLU->bf16
//      7 resid(bf16)-init + rowLN -> pad bf16 | 9 resid(bf16)-init + rowLN -> (B,C,N) + cam
// ---------------------------------------------------------------------------
template<int BM, int BN, int WC, int EPI, int KK>
__global__ __launch_bounds__(256)
void mgemm(const u16* __restrict__ A, const u16* __restrict__ Wt,
           const float* __restrict__ bias, int ldw, int Nc,
           float* __restrict__ outf, float* __restrict__ outf2,
           u16* __restrict__ outb, const u16* __restrict__ img,
           const void* __restrict__ resid,
           const float* __restrict__ p0, const float* __restrict__ p1,
           int choff, ZOff zo)
{
    constexpr int WR = 4 / WC;
    constexpr int MROWS = BM / WR;       // rows per wave
    constexpr int MI = MROWS / 16;
    constexpr int AT = BM / 64;          // A staging chunks per thread
    constexpr int BT = BN / 64;

    __shared__ __align__(16) u16 As[BM * 32];
    __shared__ __align__(16) u16 Bs[BN * 32];
    __shared__ float red[4][64][2];      // LN cross-wave partials (EPI 7/9)

    const int z = blockIdx.z;
    if (z) {
        A += (long)z * zo.a; Wt += (long)z * zo.w;
        if (bias)  bias  += (long)z * zo.bia;
        if (outf)  outf  += (long)z * zo.f1;
        if (outf2) outf2 += (long)z * zo.f2;
        if (outb)  outb  += (long)z * zo.b1;
        if (p0)    p0    += (long)z * zo.p;
        if (p1)    p1    += (long)z * zo.p;
        choff += z * zo.ch;
    }

    const int tid  = threadIdx.x;
    const int lane = tid & 63;
    const int w    = tid >> 6;
    const int wr   = w / WC, wc = w % WC;
    const int by = blockIdx.y;
    const int m0 = by * BM;
    const int n0 = blockIdx.x * BN;
    const int lr = lane & 15, lq = lane >> 4;
    const int kb = lq * 8;

    // staging source pointers
    const u16* gA[AT];
    #pragma unroll
    for (int t = 0; t < AT; ++t) {
        int c = t * 256 + tid; int row = c >> 2; int part = c & 3;
        gA[t] = A + (size_t)(m0 + row) * KK + part * 8;
    }
    const u16* gB[BT];
    #pragma unroll
    for (int t = 0; t < BT; ++t) {
        int c = t * 256 + tid; int row = c >> 2; int part = c & 3;
        gB[t] = Wt + (size_t)(n0 + row) * ldw + part * 8;
    }

    // accumulator (residual+bias init for LN epilogues; WR==1 there)
    f4v acc[MI][4];
    if constexpr (EPI == 7 || EPI == 9) {
        const u16* r16 = (const u16*)resid + (EPI == 7 ? (long)z * zo.r : 0);
        #pragma unroll
        for (int j = 0; j < 4; ++j) {
            int n = wc * 64 + j * 16 + lr;
            float bj = bias[n];
            #pragma unroll
            for (int i = 0; i < MI; ++i)
                #pragma unroll
                for (int r = 0; r < 4; ++r) {
                    int m = m0 + i * 16 + lq * 4 + r;
                    acc[i][j][r] = bf2f(r16[(size_t)m * 256 + n]) + bj;
                }
        }
    } else {
        #pragma unroll
        for (int i = 0; i < MI; ++i)
            #pragma unroll
            for (int j = 0; j < 4; ++j)
                acc[i][j] = (f4v){0.f, 0.f, 0.f, 0.f};
    }

    for (int k0 = 0; k0 < KK; k0 += 32) {
        #pragma unroll
        for (int t = 0; t < AT; ++t)
            ASYNC16(gA[t] + k0, (u16*)As + (t * 256 + tid) * 8);
        #pragma unroll
        for (int t = 0; t < BT; ++t)
            ASYNC16(gB[t] + k0, (u16*)Bs + (t * 256 + tid) * 8);
        __syncthreads();

        bf8v af[MI], bv[4];
        #pragma unroll
        for (int i = 0; i < MI; ++i)
            af[i] = *(const bf8v*)&As[(wr * MROWS + i * 16 + lr) * 32 + kb];
        #pragma unroll
        for (int j = 0; j < 4; ++j)
            bv[j] = *(const bf8v*)&Bs[(wc * 64 + j * 16 + lr) * 32 + kb];
        #pragma unroll
        for (int i = 0; i < MI; ++i)
            #pragma unroll
            for (int j = 0; j < 4; ++j)
                acc[i][j] = __builtin_amdgcn_mfma_f32_16x16x32_bf16(af[i], bv[j], acc[i][j], 0, 0, 0);
        __syncthreads();
    }

    // -------------------- epilogue --------------------
    if constexpr (EPI == 7 || EPI == 9) {
        float g4[4], b4[4];
        #pragma unroll
        for (int j = 0; j < 4; ++j) {
            int n = wc * 64 + j * 16 + lr;
            g4[j] = p0[n]; b4[j] = p1[n];
        }
        #pragma unroll
        for (int i = 0; i < MI; ++i)
            #pragma unroll
            for (int r = 0; r < 4; ++r) {
                float p = 0.f, p2 = 0.f;
                #pragma unroll
                for (int j = 0; j < 4; ++j) { float v = acc[i][j][r]; p += v; p2 += v * v; }
                p += __shfl_xor(p, 1, 16);  p2 += __shfl_xor(p2, 1, 16);
                p += __shfl_xor(p, 2, 16);  p2 += __shfl_xor(p2, 2, 16);
                p += __shfl_xor(p, 4, 16);  p2 += __shfl_xor(p2, 4, 16);
                p += __shfl_xor(p, 8, 16);  p2 += __shfl_xor(p2, 8, 16);
                if (lr == 0) {
                    int row = i * 16 + lq * 4 + r;
                    red[w][row][0] = p; red[w][row][1] = p2;
                }
            }
        __syncthreads();
        #pragma unroll
        for (int i = 0; i < MI; ++i) {
            float mean4[4], rstd4[4];
            #pragma unroll
            for (int r = 0; r < 4; ++r) {
                int row = i * 16 + lq * 4 + r;
                float s  = red[0][row][0] + red[1][row][0] + red[2][row][0] + red[3][row][0];
                float s2 = red[0][row][1] + red[1][row][1] + red[2][row][1] + red[3][row][1];
                float mean = s * (1.f / 256.f);
                float var  = s2 * (1.f / 256.f) - mean * mean;
                mean4[r] = mean;
                rstd4[r] = rsqrtf(var + 1e-5f);
            }
            if constexpr (EPI == 7) {
                #pragma unroll
                for (int r = 0; r < 4; ++r) {
                    int m = m0 + i * 16 + lq * 4 + r;
                    int b = m >> 14, sp = m & (NNn - 1);
                    size_t pb = (((size_t)b * PADW + (sp >> 7) + 1) * PADW + (sp & 127) + 1) * 512 + choff;
                    #pragma unroll
                    for (int j = 0; j < 4; ++j) {
                        int n = wc * 64 + j * 16 + lr;
                        outb[pb + n] = f2bf((acc[i][j][r] - mean4[r]) * rstd4[r] * g4[j] + b4[j]);
                    }
                }
            } else {
                // transposed write to (B,C,N) + cam residual (outf2 = cam_bev)
                int mb = m0 + i * 16 + lq * 4;
                int b = mb >> 14, sp = mb & (NNn - 1);
                #pragma unroll
                for (int j = 0; j < 4; ++j) {
                    int n = wc * 64 + j * 16 + lr;
                    size_t oi = ((size_t)b * 256 + n) * NNn + sp;
                    float4 cv = *(const float4*)&outf2[oi];
                    float4 o;
                    o.x = (acc[i][j][0] - mean4[0]) * rstd4[0] * g4[j] + b4[j] + cv.x;
                    o.y = (acc[i][j][1] - mean4[1]) * rstd4[1] * g4[j] + b4[j] + cv.y;
                    o.z = (acc[i][j][2] - mean4[2]) * rstd4[2] * g4[j] + b4[j] + cv.z;
                    o.w = (acc[i][j][3] - mean4[3]) * rstd4[3] * g4[j] + b4[j] + cv.w;
                    *(float4*)&outf[oi] = o;
                }
            }
        }
        return;
    }

    float bj[4]; int ncol[4];
    #pragma unroll
    for (int j = 0; j < 4; ++j) {
        int n = n0 + wc * 64 + j * 16 + lr;
        ncol[j] = n;
        if constexpr (EPI == 0 || EPI == 4 || EPI == 5) bj[j] = bias[n];
    }
    #pragma unroll
    for (int i = 0; i < MI; ++i) {
        #pragma unroll
        for (int r = 0; r < 4; ++r) {
            int m = m0 + wr * MROWS + i * 16 + lq * 4 + r;
            size_t pb = 0;
            if constexpr (EPI == 4) {
                int b = m >> 14, sp = m & (NNn - 1);
                pb = (((size_t)b * PADW + (sp >> 7) + 1) * PADW + (sp & 127) + 1) * 512;
            }
            #pragma unroll
            for (int j = 0; j < 4; ++j) {
                int n = ncol[j];
                float v = acc[i][j][r];
                size_t oi = (size_t)m * Nc + n;
                if constexpr (EPI == 0) {
                    outb[oi] = f2bf(v + bj[j]);
                } else if constexpr (EPI == 2) {
                    if (n < 64)      outf [(size_t)m * 64 + n]        = v + p0[n];
                    else if (n < 96) outf2[(size_t)m * 32 + (n - 64)] = v + p1[n - 64];
                } else if constexpr (EPI == 4) {
                    float vv = v + bj[j];
                    float g = 1.f / (1.f + __expf(-vv));
                    float f = g * bf2f(img[pb + n]) + (1.f - g) * bf2f(img[pb + 256 + n]);
                    outb[oi] = f2bf(f);
                } else if constexpr (EPI == 5) {
                    outb[oi] = f2bf(fmaxf(v + bj[j], 0.f));
                }
            }
        }
    }
}

// ---------------------------------------------------------------------------
// dedicated conv kernel: 128x128 tile, BK=64 (32 MFMA per barrier-pair),
// both-sides XOR swizzle (source chunk ^= row&7; fragment read same XOR).
// grid (1, 256, 3): z = tap-triple, f32 partial out.
// ---------------------------------------------------------------------------
template<int TAPS>
__global__ __launch_bounds__(256)
void conv_k(const u16* __restrict__ img, const u16* __restrict__ Wt,
            float* __restrict__ outp)
{
    __shared__ __align__(16) u16 As[128 * 64];
    __shared__ __align__(16) u16 Bs[128 * 64];

    const int z = blockIdx.z;
    outp += (size_t)z * MTOT * 128;
    const int tid = threadIdx.x;
    const int lane = tid & 63;
    const int w = tid >> 6;
    const int wr = w >> 1, wc = w & 1;
    int by = blockIdx.y;
    by = ((by & 7) << 5) | (by >> 3);       // XCD swizzle (256 = 8*32)
    const int m0 = by * 128;
    const int lr = lane & 15, lq = lane >> 4;

    // staging: 4 chunks/thread for A and B; chunk c -> row=c>>3, part=c&7
    // source k-chunk pre-swizzled: pg = part ^ (row&7); LDS dest linear.
    long cbA[4]; int pgA[4]; const u16* wB[4]; int ldsOff[4];
    #pragma unroll
    for (int t = 0; t < 4; ++t) {
        int c = t * 256 + tid;
        int row = c >> 3, part = c & 7;
        int pg = part ^ (row & 7);
        ldsOff[t] = c * 8;
        int m = m0 + row; int b = m >> 14; int sp = m & (NNn - 1);
        cbA[t] = ((long)b * PADW + (sp >> 7)) * PADW + (sp & 127);
        pgA[t] = pg;
        wB[t] = Wt + (size_t)row * 4608 + pg * 8;
    }

    f4v acc[4][4];
    #pragma unroll
    for (int i = 0; i < 4; ++i)
        #pragma unroll
        for (int j = 0; j < 4; ++j)
            acc[i][j] = (f4v){0.f, 0.f, 0.f, 0.f};

    const int tap0 = z * TAPS;
    #pragma unroll
    for (int tt = 0; tt < TAPS; ++tt) {
        int tap = tap0 + tt;
        int dy = tap / 3, dx = tap - dy * 3;
        const u16* bpA[4]; const u16* bpB[4];
        #pragma unroll
        for (int t = 0; t < 4; ++t) {
            bpA[t] = img + (size_t)(cbA[t] + dy * PADW + dx) * 512 + pgA[t] * 8;
            bpB[t] = wB[t] + tap * 512;
        }
        #pragma unroll 2
        for (int ci = 0; ci < 512; ci += 64) {
            #pragma unroll
            for (int t = 0; t < 4; ++t)
                ASYNC16(bpA[t] + ci, (u16*)As + ldsOff[t]);
            #pragma unroll
            for (int t = 0; t < 4; ++t)
                ASYNC16(bpB[t] + ci, (u16*)Bs + ldsOff[t]);
            __syncthreads();
            #pragma unroll
            for (int kk = 0; kk < 2; ++kk) {
                bf8v af[4], bv[4];
                #pragma unroll
                for (int i = 0; i < 4; ++i) {
                    int row = wr * 64 + i * 16 + lr;
                    af[i] = *(const bf8v*)&As[(row * 8 + ((kk * 4 + lq) ^ (row & 7))) * 8];
                }
                #pragma unroll
                for (int j = 0; j < 4; ++j) {
                    int row = wc * 64 + j * 16 + lr;
                    bv[j] = *(const bf8v*)&Bs[(row * 8 + ((kk * 4 + lq) ^ (row & 7))) * 8];
                }
                #pragma unroll
                for (int i = 0; i < 4; ++i)
                    #pragma unroll
                    for (int j = 0; j < 4; ++j)
                        acc[i][j] = __builtin_amdgcn_mfma_f32_16x16x32_bf16(af[i], bv[j], acc[i][j], 0, 0, 0);
            }
            __syncthreads();
        }
    }

    #pragma unroll
    for (int i = 0; i < 4; ++i)
        #pragma unroll
        for (int r = 0; r < 4; ++r) {
            int m = m0 + wr * 64 + i * 16 + lq * 4 + r;
            #pragma unroll
            for (int j = 0; j < 4; ++j) {
                int n = wc * 64 + j * 16 + lr;
                outp[(size_t)m * 128 + n] = acc[i][j][r];
            }
        }
}

// ---------------------------------------------------------------------------
// split-K combine (3 partials) + BN + ReLU -> bf16
// ---------------------------------------------------------------------------
__global__ __launch_bounds__(256)
void combine_k(const float* __restrict__ part, const float* __restrict__ bng,
               const float* __restrict__ bnb, u16* __restrict__ hb)
{
    const float bnscale = rsqrtf(1.0f + 1e-5f);
    int i = (blockIdx.x * 256 + threadIdx.x) * 4;   // over MTOT*128
    int n = i & 127;
    float4 a = *(const float4*)&part[i];
    float4 b = *(const float4*)&part[(size_t)MTOT * 128 + i];
    float4 c = *(const float4*)&part[(size_t)MTOT * 256 + i];
    ushort4 o;
    o.x = f2bf(fmaxf((a.x + b.x + c.x) * bnscale * bng[n + 0] + bnb[n + 0], 0.f));
    o.y = f2bf(fmaxf((a.y + b.y + c.y) * bnscale * bng[n + 1] + bnb[n + 1], 0.f));
    o.z = f2bf(fmaxf((a.z + b.z + c.z) * bnscale * bng[n + 2] + bnb[n + 2], 0.f));
    o.w = f2bf(fmaxf((a.w + b.w + c.w) * bnscale * bng[n + 3] + bnb[n + 3], 0.f));
    *(ushort4*)&hb[i] = o;
}

// ---------------------------------------------------------------------------
// bev (B,C,N) f32 -> (B*N, C) bf16 ; z: 0-1 cam batches, 2-3 sat batches
// ---------------------------------------------------------------------------
__global__ __launch_bounds__(256)
void tcvt_k(const float* __restrict__ cam, const float* __restrict__ sat,
            u16* __restrict__ qcam, u16* __restrict__ qsat)
{
    __shared__ float t[64][65];
    int z = blockIdx.z;
    const float* src = (z < 2) ? cam : sat;
    u16* dst = (z < 2) ? qcam : qsat;
    int b = z & 1;
    int c0 = blockIdx.x * 64, sp0 = blockIdx.y * 64;
    #pragma unroll
    for (int it = 0; it < 16; ++it) {
        int idx = it * 256 + threadIdx.x;
        int cl = idx >> 6, sl = idx & 63;
        t[cl][sl] = src[((size_t)(b * CCn + c0 + cl)) * NNn + sp0 + sl];
    }
    __syncthreads();
    #pragma unroll
    for (int it = 0; it < 16; ++it) {
        int idx = it * 256 + threadIdx.x;
        int sl = idx >> 6, cl = idx & 63;
        dst[((size_t)(b * NNn + sp0 + sl)) * CCn + c0 + cl] = f2bf(t[cl][sl]);
    }
}

// ---------------------------------------------------------------------------
// deformable sampling, softmax over NP=4 fused; 4 channels / thread
// z = blockIdx.z selects c2s / s2c stream (fixed strides)
// ---------------------------------------------------------------------------
__global__ __launch_bounds__(256)
void sample_k(const u16* __restrict__ val, const float* __restrict__ off,
              const float* __restrict__ lg, u16* __restrict__ outp)
{
    int z = blockIdx.z;
    val  += (size_t)z * MTOT * CCn;
    off  += (size_t)z * MTOT * 64;
    lg   += (size_t)z * MTOT * 32;
    outp += (size_t)z * MTOT * CCn;

    int t = blockIdx.x * 256 + threadIdx.x;    // MTOT*64 threads
    int d4 = (t & 7) * 4;
    int h  = (t >> 3) & 7;
    int rn = t >> 6;
    int n = rn & (NNn - 1), b = rn >> 14;
    int yp = n >> 7, xp = n & 127;

    const float* ofp = off + (size_t)rn * 64 + h * 8;
    const float* lgp = lg  + (size_t)rn * 32 + h * 4;

    float l0 = lgp[0], l1 = lgp[1], l2 = lgp[2], l3 = lgp[3];
    float mx = fmaxf(fmaxf(l0, l1), fmaxf(l2, l3));
    float e0 = __expf(l0 - mx), e1 = __expf(l1 - mx), e2 = __expf(l2 - mx), e3 = __expf(l3 - mx);
    float inv = 1.f / (e0 + e1 + e2 + e3);
    float aw[4] = { e0 * inv, e1 * inv, e2 * inv, e3 * inv };

    const u16* vb = val + (size_t)b * NNn * CCn + h * 32 + d4;
    float a[4] = {0.f, 0.f, 0.f, 0.f};
    #pragma unroll
    for (int p = 0; p < 4; ++p) {
        float xs = (float)xp + ofp[p * 2 + 0];
        float ys = (float)yp + ofp[p * 2 + 1];
        float x0f = floorf(xs), y0f = floorf(ys);
        float lx = xs - x0f, ly = ys - y0f;
        int x0 = (int)x0f, y0 = (int)y0f;
        #pragma unroll
        for (int cy = 0; cy < 2; ++cy) {
            #pragma unroll
            for (int cx = 0; cx < 2; ++cx) {
                int xi = x0 + cx, yi = y0 + cy;
                float wgt = aw[p] * (cx ? lx : 1.f - lx) * (cy ? ly : 1.f - ly);
                if (xi >= 0 && xi < WWn && yi >= 0 && yi < HHn) {
                    ushort4 vv = *(const ushort4*)(vb + (size_t)(yi * WWn + xi) * CCn);
                    a[0] += wgt * bf2f(vv.x);
                    a[1] += wgt * bf2f(vv.y);
                    a[2] += wgt * bf2f(vv.z);
                    a[3] += wgt * bf2f(vv.w);
                }
            }
        }
    }
    ushort4 o;
    o.x = f2bf(a[0]); o.y = f2bf(a[1]); o.z = f2bf(a[2]); o.w = f2bf(a[3]);
    *(ushort4*)(outp + (size_t)rn * CCn + h * 32 + d4) = o;
}

// ---------------------------------------------------------------------------
// all weight repacks + bias/LN packing in one kernel (layouts in comments of r3)
// ---------------------------------------------------------------------------
__global__ __launch_bounds__(256)
void repack_all(const float* __restrict__ vp1, const float* __restrict__ op1,
                const float* __restrict__ vp2, const float* __restrict__ op2,
                const float* __restrict__ f1w, const float* __restrict__ f2w,
                const float* __restrict__ of1, const float* __restrict__ aw1,
                const float* __restrict__ of2, const float* __restrict__ aw2,
                const float* __restrict__ g1,  const float* __restrict__ g2,
                const float* __restrict__ vpb1, const float* __restrict__ vpb2,
                const float* __restrict__ opb1, const float* __restrict__ opb2,
                const float* __restrict__ ofb1, const float* __restrict__ awb1,
                const float* __restrict__ ofb2, const float* __restrict__ awb2,
                const float* __restrict__ l1g, const float* __restrict__ l1b,
                const float* __restrict__ l2g, const float* __restrict__ l2b,
                u16* __restrict__ wb, float* __restrict__ bb)
{
    int i = blockIdx.x * 256 + threadIdx.x;
    if (i >= 1212416 + 2240) return;
    if (i >= 1212416) {
        int j = i - 1212416;
        float v;
        if      (j < 256)  v = vpb1[j];
        else if (j < 512)  v = vpb2[j - 256];
        else if (j < 768)  v = opb1[j - 512];
        else if (j < 1024) v = opb2[j - 768];
        else if (j < 1088) v = ofb1[j - 1024];
        else if (j < 1120) v = awb1[j - 1088];
        else if (j < 1184) v = ofb2[j - 1120];
        else if (j < 1216) v = awb2[j - 1184];
        else if (j < 1472) v = l1g[j - 1216];
        else if (j < 1728) v = l1b[j - 1472];
        else if (j < 1984) v = l2g[j - 1728];
        else               v = l2b[j - 1984];
        bb[j] = v;
        return;
    }
    float v;
    if (i < 262144) {
        const float* src[4] = { vp1, vp2, op1, op2 };
        int q = i >> 16, j = i & 65535;
        int n = j >> 8, k = j & 255;
        v = src[q][(size_t)k * 256 + n];
    } else if (i < 393216) {
        int j = i - 262144; int n = j >> 8, k = j & 255;      // [512][256]
        v = f1w[(size_t)k * 512 + n];
    } else if (i < 524288) {
        int j = i - 393216; int n = j >> 9, k = j & 511;      // [256][512]
        v = f2w[(size_t)k * 256 + n];
    } else if (i < 589824) {
        int jj = i - 524288; int hh = jj >> 15; int j = jj & 32767;
        int n = j >> 8, k = j & 255;                          // [128][256]
        const float* ofw = hh ? of2 : of1;
        const float* aww = hh ? aw2 : aw1;
        if (n < 64)      v = ofw[(size_t)k * 64 + n];
        else if (n < 96) v = aww[(size_t)k * 32 + (n - 64)];
        else             v = 0.f;
    } else if (i < 1179648) {
        int j = i - 589824; int co = j / 4608, k = j - co * 4608;
        int tap = k >> 9, ci = k & 511;
        v = g1[((size_t)co * 512 + ci) * 9 + tap];
    } else {
        int j = i - 1179648; int n = j >> 7, k = j & 127;     // [256][128]
        v = g2[(size_t)n * 128 + k];
    }
    wb[i] = f2bf(v);
}

// ---------------------------------------------------------------------------
extern "C" void kernel_launch(void* const* d_in, const int* in_sizes, int n_in,
                              void* d_out, int out_size, void* d_ws, size_t ws_size,
                              hipStream_t stream)
{
    const float* cam_bev   = (const float*)d_in[0];
    const float* sat_bev   = (const float*)d_in[1];
    const float* c2s_off_w  = (const float*)d_in[2];
    const float* c2s_off_b  = (const float*)d_in[3];
    const float* c2s_attw_w = (const float*)d_in[4];
    const float* c2s_attw_b = (const float*)d_in[5];
    const float* c2s_vp_w   = (const float*)d_in[6];
    const float* c2s_vp_b   = (const float*)d_in[7];
    const float* c2s_op_w   = (const float*)d_in[8];
    const float* c2s_op_b   = (const float*)d_in[9];
    const float* s2c_off_w  = (const float*)d_in[10];
    const float* s2c_off_b  = (const float*)d_in[11];
    const float* s2c_attw_w = (const float*)d_in[12];
    const float* s2c_attw_b = (const float*)d_in[13];
    const float* s2c_vp_w   = (const float*)d_in[14];
    const float* s2c_vp_b   = (const float*)d_in[15];
    const float* s2c_op_w   = (const float*)d_in[16];
    const float* s2c_op_b   = (const float*)d_in[17];
    const float* ln1_g = (const float*)d_in[18];
    const float* ln1_b = (const float*)d_in[19];
    const float* ln2_g = (const float*)d_in[20];
    const float* ln2_b = (const float*)d_in[21];
    const float* lnf_g = (const float*)d_in[22];
    const float* lnf_b = (const float*)d_in[23];
    const float* ffn1_w = (const float*)d_in[24];
    const float* ffn1_b = (const float*)d_in[25];
    const float* ffn2_w = (const float*)d_in[26];
    const float* ffn2_b = (const float*)d_in[27];
    const float* g1_w  = (const float*)d_in[28];
    const float* bn_g  = (const float*)d_in[29];
    const float* bn_b  = (const float*)d_in[30];
    const float* g2_w  = (const float*)d_in[31];
    const float* g2_b  = (const float*)d_in[32];

    char* base = (char*)d_ws;
    size_t off = 0;
    auto alloc = [&](size_t bytes) -> void* {
        void* p = base + off;
        off += (bytes + 255) & ~(size_t)255;
        return p;
    };

    u16*   qcam   = (u16*)  alloc((size_t)MTOT * CCn * 2 * 2);   // qcam|qsat contiguous
    u16*   qsat   = qcam + (size_t)MTOT * CCn;
    u16*   valb   = (u16*)  alloc((size_t)MTOT * CCn * 2 * 2);   // pair
    u16*   sampb  = (u16*)  alloc((size_t)MTOT * CCn * 2 * 2);   // pair (33.55MB)
    float* offb   = (float*)alloc((size_t)MTOT * 64 * 4 * 2);    // pair (16.78MB)
    float* attwb  = (float*)alloc((size_t)MTOT * 32 * 4 * 2);    // pair
    size_t padBytes = (size_t)BBn * PADW * PADW * 512 * 2;       // 34.6MB
    u16*   pad    = (u16*)  alloc(padBytes);
    u16*   hbuf   = (u16*)  alloc((size_t)MTOT * 128 * 2);
    u16*   wbase  = (u16*)  alloc((size_t)1212416 * 2);
    float* biasbf = (float*)alloc((size_t)2240 * 4);
    // weight slices
    u16* wvp = wbase;                 // pair, stride 65536
    u16* wop = wbase + 131072;        // pair, stride 65536
    u16* wf1 = wbase + 262144;
    u16* wf2 = wbase + 393216;
    u16* woa = wbase + 524288;        // pair, stride 32768
    u16* wcv = wbase + 589824;
    u16* wg2 = wbase + 1179648;
    // aliases (temporally disjoint)
    u16*   fused_bf = valb;              // valb dead after sampling
    float* convpart = (float*)sampb;     // sampb+offb dead after op-pair: 3x MTOT*128 f32 = 50.3MB
    u16*   midb     = qcam;              // qcam/qsat dead after op-pair (MTOT*512 bf16)

    dim3 blk(256);
    ZOff zz{0, 0, 0, 0, 0, 0, 0, 0, 0};

    hipMemsetAsync(pad, 0, padBytes, stream);
    tcvt_k<<<dim3(4, 256, 4), blk, 0, stream>>>(cam_bev, sat_bev, qcam, qsat);
    repack_all<<<4746, blk, 0, stream>>>(c2s_vp_w, c2s_op_w, s2c_vp_w, s2c_op_w,
                                         ffn1_w, ffn2_w, c2s_off_w, c2s_attw_w,
                                         s2c_off_w, s2c_attw_w, g1_w, g2_w,
                                         c2s_vp_b, s2c_vp_b, c2s_op_b, s2c_op_b,
                                         c2s_off_b, c2s_attw_b, s2c_off_b, s2c_attw_b,
                                         ln1_g, ln1_b, ln2_g, ln2_b,
                                         wbase, biasbf);

    // ---------- value projections (z=0: kv=sat, z=1: kv=cam) ----------
    {
        ZOff zo{ -(long)MTOT * CCn, 65536, 256, 0, 0, (long)MTOT * CCn, 0, 0, 0 };
        mgemm<128, 128, 2, 0, 256><<<dim3(2, 256, 2), blk, 0, stream>>>(
            qsat, wvp, biasbf, 256, 256,
            nullptr, nullptr, valb, nullptr, nullptr, nullptr, nullptr, 0, zo);
    }
    // ---------- offset+attw projections (z=0: q=cam, z=1: q=sat) ----------
    {
        ZOff zo{ (long)MTOT * CCn, 32768, 0, (long)MTOT * 64, (long)MTOT * 32, 0, 0, 96, 0 };
        mgemm<128, 128, 2, 2, 256><<<dim3(1, 256, 2), blk, 0, stream>>>(
            qcam, woa, nullptr, 256, 128,
            offb, attwb, nullptr, nullptr, nullptr, biasbf + 1024, biasbf + 1088, 0, zo);
    }
    // ---------- deformable sampling (both streams) ----------
    sample_k<<<dim3(8192, 1, 2), blk, 0, stream>>>(valb, offb, attwb, sampb);
    // ---------- output projections + residual + LN -> pad image ----------
    {
        ZOff zo{ (long)MTOT * CCn, 65536, 256, 0, 0, 0, (long)MTOT * CCn, 512, 256 };
        mgemm<64, 256, 4, 7, 256><<<dim3(1, 512, 2), blk, 0, stream>>>(
            sampb, wop, biasbf + 512, 256, 256,
            nullptr, nullptr, pad, nullptr, qcam, biasbf + 1216, biasbf + 1472, 0, zo);
    }
    // ---------- gating conv: implicit GEMM, BK=64, split-K=3, f32 partials ----
    conv_k<3><<<dim3(1, 256, 3), blk, 0, stream>>>(pad, wcv, convpart);
    combine_k<<<4096, blk, 0, stream>>>(convpart, bn_g, bn_b, hbuf);

    // ---------- 1x1 conv + sigmoid + gated fusion (bf16 out only) ----------
    mgemm<128, 128, 2, 4, 128><<<dim3(2, 256, 1), blk, 0, stream>>>(
        hbuf, wg2, g2_b, 128, 256,
        nullptr, nullptr, fused_bf, pad, nullptr, nullptr, nullptr, 0, zz);

    // ---------- FFN ----------
    mgemm<128, 128, 2, 5, 256><<<dim3(4, 256, 1), blk, 0, stream>>>(
        fused_bf, wf1, ffn1_b, 256, 512,
        nullptr, nullptr, midb, nullptr, nullptr, nullptr, nullptr, 0, zz);
    // ffn2 + final LN + transpose to (B,C,N) + cam residual (EPI 9, bf16 resid)
    mgemm<64, 256, 4, 9, 512><<<dim3(1, 512, 1), blk, 0, stream>>>(
        midb, wf2, ffn2_b, 512, 256,
        (float*)d_out, (float*)cam_bev, nullptr, nullptr, fused_bf, lnf_g, lnf_b, 0, zz);
}

// Round 9
// 322.608 us; speedup vs baseline: 5.3938x; 1.0151x over previous
//
#include <hip/hip_runtime.h>
#include <hip/hip_bf16.h>
#include <cstddef>

#define BBn  2
#define CCn  256
#define HHn  128
#define WWn  128
#define NNn  (HHn*WWn)        // 16384
#define MTOT (BBn*NNn)        // 32768
#define PADW 130

typedef unsigned short u16;
typedef __attribute__((ext_vector_type(8))) short bf8v;
typedef __attribute__((ext_vector_type(8))) unsigned short u16x8;
typedef __attribute__((ext_vector_type(4))) float f4v;

typedef __attribute__((address_space(1))) const void gvoid_t;
typedef __attribute__((address_space(3))) void svoid_t;
#define ASYNC16(g, l) __builtin_amdgcn_global_load_lds((gvoid_t*)(g), (svoid_t*)(l), 16, 0, 0)

__device__ __forceinline__ u16 f2bf(float f) {
    __hip_bfloat16 h = __float2bfloat16(f);
    return *reinterpret_cast<u16*>(&h);
}
__device__ __forceinline__ float bf2f(u16 h) {
    return __uint_as_float(((unsigned)h) << 16);
}

// z-offsets (elements), applied scaled by blockIdx.z
struct ZOff {
    long a, w, bia, f1, f2, b1, r, p;
    int ch;
};

// ---------------------------------------------------------------------------
// bf16 MFMA GEMM, tile BM x BN, BK=32, 4 waves arranged WRxWC (WR=4/WC).
// A[M,KK] bf16 row-major (stride KK). Wt[Nc,ldw] bf16 pre-transposed.
// EPI: 0 bf16+bias | 2 off/attw split | 4 sigmoid-gate (bf16 out)
//      5 ReLU->bf16
//      7 resid(bf16)-init + rowLN -> pad bf16 | 9 resid(bf16)-init + rowLN -> (B,C,N) + cam
// ---------------------------------------------------------------------------
template<int BM, int BN, int WC, int EPI, int KK>
__global__ __launch_bounds__(256)
void mgemm(const u16* __restrict__ A, const u16* __restrict__ Wt,
           const float* __restrict__ bias, int ldw, int Nc,
           float* __restrict__ outf, float* __restrict__ outf2,
           u16* __restrict__ outb, const u16* __restrict__ img,
           const void* __restrict__ resid,
           const float* __restrict__ p0, const float* __restrict__ p1,
           int choff, ZOff zo)
{
    constexpr int WR = 4 / WC;
    constexpr int MROWS = BM / WR;       // rows per wave
    constexpr int MI = MROWS / 16;
    constexpr int AT = BM / 64;          // A staging chunks per thread
    constexpr int BT = BN / 64;

    __shared__ __align__(16) u16 As[BM * 32];
    __shared__ __align__(16) u16 Bs[BN * 32];
    __shared__ float red[4][64][2];      // LN cross-wave partials (EPI 7/9)

    const int z = blockIdx.z;
    if (z) {
        A += (long)z * zo.a; Wt += (long)z * zo.w;
        if (bias)  bias  += (long)z * zo.bia;
        if (outf)  outf  += (long)z * zo.f1;
        if (outf2) outf2 += (long)z * zo.f2;
        if (outb)  outb  += (long)z * zo.b1;
        if (p0)    p0    += (long)z * zo.p;
        if (p1)    p1    += (long)z * zo.p;
        choff += z * zo.ch;
    }

    const int tid  = threadIdx.x;
    const int lane = tid & 63;
    const int w    = tid >> 6;
    const int wr   = w / WC, wc = w % WC;
    const int by = blockIdx.y;
    const int m0 = by * BM;
    const int n0 = blockIdx.x * BN;
    const int lr = lane & 15, lq = lane >> 4;
    const int kb = lq * 8;

    // staging source pointers
    const u16* gA[AT];
    #pragma unroll
    for (int t = 0; t < AT; ++t) {
        int c = t * 256 + tid; int row = c >> 2; int part = c & 3;
        gA[t] = A + (size_t)(m0 + row) * KK + part * 8;
    }
    const u16* gB[BT];
    #pragma unroll
    for (int t = 0; t < BT; ++t) {
        int c = t * 256 + tid; int row = c >> 2; int part = c & 3;
        gB[t] = Wt + (size_t)(n0 + row) * ldw + part * 8;
    }

    // accumulator (residual+bias init for LN epilogues; WR==1 there)
    f4v acc[MI][4];
    if constexpr (EPI == 7 || EPI == 9) {
        const u16* r16 = (const u16*)resid + (EPI == 7 ? (long)z * zo.r : 0);
        #pragma unroll
        for (int j = 0; j < 4; ++j) {
            int n = wc * 64 + j * 16 + lr;
            float bj = bias[n];
            #pragma unroll
            for (int i = 0; i < MI; ++i)
                #pragma unroll
                for (int r = 0; r < 4; ++r) {
                    int m = m0 + i * 16 + lq * 4 + r;
                    acc[i][j][r] = bf2f(r16[(size_t)m * 256 + n]) + bj;
                }
        }
    } else {
        #pragma unroll
        for (int i = 0; i < MI; ++i)
            #pragma unroll
            for (int j = 0; j < 4; ++j)
                acc[i][j] = (f4v){0.f, 0.f, 0.f, 0.f};
    }

    for (int k0 = 0; k0 < KK; k0 += 32) {
        #pragma unroll
        for (int t = 0; t < AT; ++t)
            ASYNC16(gA[t] + k0, (u16*)As + (t * 256 + tid) * 8);
        #pragma unroll
        for (int t = 0; t < BT; ++t)
            ASYNC16(gB[t] + k0, (u16*)Bs + (t * 256 + tid) * 8);
        __syncthreads();

        bf8v af[MI], bv[4];
        #pragma unroll
        for (int i = 0; i < MI; ++i)
            af[i] = *(const bf8v*)&As[(wr * MROWS + i * 16 + lr) * 32 + kb];
        #pragma unroll
        for (int j = 0; j < 4; ++j)
            bv[j] = *(const bf8v*)&Bs[(wc * 64 + j * 16 + lr) * 32 + kb];
        #pragma unroll
        for (int i = 0; i < MI; ++i)
            #pragma unroll
            for (int j = 0; j < 4; ++j)
                acc[i][j] = __builtin_amdgcn_mfma_f32_16x16x32_bf16(af[i], bv[j], acc[i][j], 0, 0, 0);
        __syncthreads();
    }

    // -------------------- epilogue --------------------
    if constexpr (EPI == 7 || EPI == 9) {
        float g4[4], b4[4];
        #pragma unroll
        for (int j = 0; j < 4; ++j) {
            int n = wc * 64 + j * 16 + lr;
            g4[j] = p0[n]; b4[j] = p1[n];
        }
        #pragma unroll
        for (int i = 0; i < MI; ++i)
            #pragma unroll
            for (int r = 0; r < 4; ++r) {
                float p = 0.f, p2 = 0.f;
                #pragma unroll
                for (int j = 0; j < 4; ++j) { float v = acc[i][j][r]; p += v; p2 += v * v; }
                p += __shfl_xor(p, 1, 16);  p2 += __shfl_xor(p2, 1, 16);
                p += __shfl_xor(p, 2, 16);  p2 += __shfl_xor(p2, 2, 16);
                p += __shfl_xor(p, 4, 16);  p2 += __shfl_xor(p2, 4, 16);
                p += __shfl_xor(p, 8, 16);  p2 += __shfl_xor(p2, 8, 16);
                if (lr == 0) {
                    int row = i * 16 + lq * 4 + r;
                    red[w][row][0] = p; red[w][row][1] = p2;
                }
            }
        __syncthreads();
        #pragma unroll
        for (int i = 0; i < MI; ++i) {
            float mean4[4], rstd4[4];
            #pragma unroll
            for (int r = 0; r < 4; ++r) {
                int row = i * 16 + lq * 4 + r;
                float s  = red[0][row][0] + red[1][row][0] + red[2][row][0] + red[3][row][0];
                float s2 = red[0][row][1] + red[1][row][1] + red[2][row][1] + red[3][row][1];
                float mean = s * (1.f / 256.f);
                float var  = s2 * (1.f / 256.f) - mean * mean;
                mean4[r] = mean;
                rstd4[r] = rsqrtf(var + 1e-5f);
            }
            if constexpr (EPI == 7) {
                #pragma unroll
                for (int r = 0; r < 4; ++r) {
                    int m = m0 + i * 16 + lq * 4 + r;
                    int b = m >> 14, sp = m & (NNn - 1);
                    size_t pb = (((size_t)b * PADW + (sp >> 7) + 1) * PADW + (sp & 127) + 1) * 512 + choff;
                    #pragma unroll
                    for (int j = 0; j < 4; ++j) {
                        int n = wc * 64 + j * 16 + lr;
                        outb[pb + n] = f2bf((acc[i][j][r] - mean4[r]) * rstd4[r] * g4[j] + b4[j]);
                    }
                }
            } else {
                // transposed write to (B,C,N) + cam residual (outf2 = cam_bev)
                int mb = m0 + i * 16 + lq * 4;
                int b = mb >> 14, sp = mb & (NNn - 1);
                #pragma unroll
                for (int j = 0; j < 4; ++j) {
                    int n = wc * 64 + j * 16 + lr;
                    size_t oi = ((size_t)b * 256 + n) * NNn + sp;
                    float4 cv = *(const float4*)&outf2[oi];
                    float4 o;
                    o.x = (acc[i][j][0] - mean4[0]) * rstd4[0] * g4[j] + b4[j] + cv.x;
                    o.y = (acc[i][j][1] - mean4[1]) * rstd4[1] * g4[j] + b4[j] + cv.y;
                    o.z = (acc[i][j][2] - mean4[2]) * rstd4[2] * g4[j] + b4[j] + cv.z;
                    o.w = (acc[i][j][3] - mean4[3]) * rstd4[3] * g4[j] + b4[j] + cv.w;
                    *(float4*)&outf[oi] = o;
                }
            }
        }
        return;
    }

    float bj[4]; int ncol[4];
    #pragma unroll
    for (int j = 0; j < 4; ++j) {
        int n = n0 + wc * 64 + j * 16 + lr;
        ncol[j] = n;
        if constexpr (EPI == 0 || EPI == 4 || EPI == 5) bj[j] = bias[n];
    }
    #pragma unroll
    for (int i = 0; i < MI; ++i) {
        #pragma unroll
        for (int r = 0; r < 4; ++r) {
            int m = m0 + wr * MROWS + i * 16 + lq * 4 + r;
            size_t pb = 0;
            if constexpr (EPI == 4) {
                int b = m >> 14, sp = m & (NNn - 1);
                pb = (((size_t)b * PADW + (sp >> 7) + 1) * PADW + (sp & 127) + 1) * 512;
            }
            #pragma unroll
            for (int j = 0; j < 4; ++j) {
                int n = ncol[j];
                float v = acc[i][j][r];
                size_t oi = (size_t)m * Nc + n;
                if constexpr (EPI == 0) {
                    outb[oi] = f2bf(v + bj[j]);
                } else if constexpr (EPI == 2) {
                    if (n < 64)      outf [(size_t)m * 64 + n]        = v + p0[n];
                    else if (n < 96) outf2[(size_t)m * 32 + (n - 64)] = v + p1[n - 64];
                } else if constexpr (EPI == 4) {
                    float vv = v + bj[j];
                    float g = 1.f / (1.f + __expf(-vv));
                    float f = g * bf2f(img[pb + n]) + (1.f - g) * bf2f(img[pb + 256 + n]);
                    outb[oi] = f2bf(f);
                } else if constexpr (EPI == 5) {
                    outb[oi] = f2bf(fmaxf(v + bj[j], 0.f));
                }
            }
        }
    }
}

// ---------------------------------------------------------------------------
// dedicated conv kernel: 128x128 tile, BK=64 (32 MFMA per barrier-pair),
// both-sides XOR swizzle (source chunk ^= row&7; fragment read same XOR).
// grid (1, 256, 3): z = tap-triple, f32 partial out.
// ---------------------------------------------------------------------------
template<int TAPS>
__global__ __launch_bounds__(256)
void conv_k(const u16* __restrict__ img, const u16* __restrict__ Wt,
            float* __restrict__ outp)
{
    __shared__ __align__(16) u16 As[128 * 64];
    __shared__ __align__(16) u16 Bs[128 * 64];

    const int z = blockIdx.z;
    outp += (size_t)z * MTOT * 128;
    const int tid = threadIdx.x;
    const int lane = tid & 63;
    const int w = tid >> 6;
    const int wr = w >> 1, wc = w & 1;
    int by = blockIdx.y;
    by = ((by & 7) << 5) | (by >> 3);       // XCD swizzle (256 = 8*32)
    const int m0 = by * 128;
    const int lr = lane & 15, lq = lane >> 4;

    // staging: 4 chunks/thread for A and B; chunk c -> row=c>>3, part=c&7
    // source k-chunk pre-swizzled: pg = part ^ (row&7); LDS dest linear.
    long cbA[4]; int pgA[4]; const u16* wB[4]; int ldsOff[4];
    #pragma unroll
    for (int t = 0; t < 4; ++t) {
        int c = t * 256 + tid;
        int row = c >> 3, part = c & 7;
        int pg = part ^ (row & 7);
        ldsOff[t] = c * 8;
        int m = m0 + row; int b = m >> 14; int sp = m & (NNn - 1);
        cbA[t] = ((long)b * PADW + (sp >> 7)) * PADW + (sp & 127);
        pgA[t] = pg;
        wB[t] = Wt + (size_t)row * 4608 + pg * 8;
    }

    f4v acc[4][4];
    #pragma unroll
    for (int i = 0; i < 4; ++i)
        #pragma unroll
        for (int j = 0; j < 4; ++j)
            acc[i][j] = (f4v){0.f, 0.f, 0.f, 0.f};

    const int tap0 = z * TAPS;
    #pragma unroll
    for (int tt = 0; tt < TAPS; ++tt) {
        int tap = tap0 + tt;
        int dy = tap / 3, dx = tap - dy * 3;
        const u16* bpA[4]; const u16* bpB[4];
        #pragma unroll
        for (int t = 0; t < 4; ++t) {
            bpA[t] = img + (size_t)(cbA[t] + dy * PADW + dx) * 512 + pgA[t] * 8;
            bpB[t] = wB[t] + tap * 512;
        }
        #pragma unroll 2
        for (int ci = 0; ci < 512; ci += 64) {
            #pragma unroll
            for (int t = 0; t < 4; ++t)
                ASYNC16(bpA[t] + ci, (u16*)As + ldsOff[t]);
            #pragma unroll
            for (int t = 0; t < 4; ++t)
                ASYNC16(bpB[t] + ci, (u16*)Bs + ldsOff[t]);
            __syncthreads();
            #pragma unroll
            for (int kk = 0; kk < 2; ++kk) {
                bf8v af[4], bv[4];
                #pragma unroll
                for (int i = 0; i < 4; ++i) {
                    int row = wr * 64 + i * 16 + lr;
                    af[i] = *(const bf8v*)&As[(row * 8 + ((kk * 4 + lq) ^ (row & 7))) * 8];
                }
                #pragma unroll
                for (int j = 0; j < 4; ++j) {
                    int row = wc * 64 + j * 16 + lr;
                    bv[j] = *(const bf8v*)&Bs[(row * 8 + ((kk * 4 + lq) ^ (row & 7))) * 8];
                }
                #pragma unroll
                for (int i = 0; i < 4; ++i)
                    #pragma unroll
                    for (int j = 0; j < 4; ++j)
                        acc[i][j] = __builtin_amdgcn_mfma_f32_16x16x32_bf16(af[i], bv[j], acc[i][j], 0, 0, 0);
            }
            __syncthreads();
        }
    }

    #pragma unroll
    for (int i = 0; i < 4; ++i)
        #pragma unroll
        for (int r = 0; r < 4; ++r) {
            int m = m0 + wr * 64 + i * 16 + lq * 4 + r;
            #pragma unroll
            for (int j = 0; j < 4; ++j) {
                int n = wc * 64 + j * 16 + lr;
                outp[(size_t)m * 128 + n] = acc[i][j][r];
            }
        }
}

// ---------------------------------------------------------------------------
// split-K combine (3 partials) + BN + ReLU -> bf16
// ---------------------------------------------------------------------------
__global__ __launch_bounds__(256)
void combine_k(const float* __restrict__ part, const float* __restrict__ bng,
               const float* __restrict__ bnb, u16* __restrict__ hb)
{
    const float bnscale = rsqrtf(1.0f + 1e-5f);
    int i = (blockIdx.x * 256 + threadIdx.x) * 4;   // over MTOT*128
    int n = i & 127;
    float4 a = *(const float4*)&part[i];
    float4 b = *(const float4*)&part[(size_t)MTOT * 128 + i];
    float4 c = *(const float4*)&part[(size_t)MTOT * 256 + i];
    ushort4 o;
    o.x = f2bf(fmaxf((a.x + b.x + c.x) * bnscale * bng[n + 0] + bnb[n + 0], 0.f));
    o.y = f2bf(fmaxf((a.y + b.y + c.y) * bnscale * bng[n + 1] + bnb[n + 1], 0.f));
    o.z = f2bf(fmaxf((a.z + b.z + c.z) * bnscale * bng[n + 2] + bnb[n + 2], 0.f));
    o.w = f2bf(fmaxf((a.w + b.w + c.w) * bnscale * bng[n + 3] + bnb[n + 3], 0.f));
    *(ushort4*)&hb[i] = o;
}

// ---------------------------------------------------------------------------
// bev (B,C,N) f32 -> (B*N, C) bf16 ; z: 0-1 cam batches, 2-3 sat batches
// ---------------------------------------------------------------------------
__global__ __launch_bounds__(256)
void tcvt_k(const float* __restrict__ cam, const float* __restrict__ sat,
            u16* __restrict__ qcam, u16* __restrict__ qsat)
{
    __shared__ float t[64][65];
    int z = blockIdx.z;
    const float* src = (z < 2) ? cam : sat;
    u16* dst = (z < 2) ? qcam : qsat;
    int b = z & 1;
    int c0 = blockIdx.x * 64, sp0 = blockIdx.y * 64;
    #pragma unroll
    for (int it = 0; it < 16; ++it) {
        int idx = it * 256 + threadIdx.x;
        int cl = idx >> 6, sl = idx & 63;
        t[cl][sl] = src[((size_t)(b * CCn + c0 + cl)) * NNn + sp0 + sl];
    }
    __syncthreads();
    #pragma unroll
    for (int it = 0; it < 16; ++it) {
        int idx = it * 256 + threadIdx.x;
        int sl = idx >> 6, cl = idx & 63;
        dst[((size_t)(b * NNn + sp0 + sl)) * CCn + c0 + cl] = f2bf(t[cl][sl]);
    }
}

// ---------------------------------------------------------------------------
// deformable sampling: one thread per (row, head), all 32 channels.
// softmax over NP=4 fused; 4x ushort8 (64B) gathers per corner.
// z = blockIdx.z selects c2s / s2c stream.
// ---------------------------------------------------------------------------
__global__ __launch_bounds__(256)
void sample_k(const u16* __restrict__ val, const float* __restrict__ off,
              const float* __restrict__ lg, u16* __restrict__ outp)
{
    int z = blockIdx.z;
    val  += (size_t)z * MTOT * CCn;
    off  += (size_t)z * MTOT * 64;
    lg   += (size_t)z * MTOT * 32;
    outp += (size_t)z * MTOT * CCn;

    int t = blockIdx.x * 256 + threadIdx.x;    // MTOT*8 threads
    int h  = t & 7;
    int rn = t >> 3;
    int n = rn & (NNn - 1), b = rn >> 14;
    int yp = n >> 7, xp = n & 127;

    const float* ofp = off + (size_t)rn * 64 + h * 8;
    const float* lgp = lg  + (size_t)rn * 32 + h * 4;

    float4 of0 = *(const float4*)ofp;
    float4 of1 = *(const float4*)(ofp + 4);
    float4 lgv = *(const float4*)lgp;
    float ofx[4] = { of0.x, of0.z, of1.x, of1.z };
    float ofy[4] = { of0.y, of0.w, of1.y, of1.w };

    float mx = fmaxf(fmaxf(lgv.x, lgv.y), fmaxf(lgv.z, lgv.w));
    float e0 = __expf(lgv.x - mx), e1 = __expf(lgv.y - mx);
    float e2 = __expf(lgv.z - mx), e3 = __expf(lgv.w - mx);
    float inv = 1.f / (e0 + e1 + e2 + e3);
    float aw[4] = { e0 * inv, e1 * inv, e2 * inv, e3 * inv };

    const u16* vb = val + (size_t)b * NNn * CCn + h * 32;
    float acc[32];
    #pragma unroll
    for (int q = 0; q < 32; ++q) acc[q] = 0.f;

    #pragma unroll
    for (int p = 0; p < 4; ++p) {
        float xs = (float)xp + ofx[p];
        float ys = (float)yp + ofy[p];
        float x0f = floorf(xs), y0f = floorf(ys);
        float lx = xs - x0f, ly = ys - y0f;
        int x0 = (int)x0f, y0 = (int)y0f;
        #pragma unroll
        for (int c = 0; c < 4; ++c) {
            int xi = x0 + (c & 1), yi = y0 + (c >> 1);
            float wgt = aw[p] * ((c & 1) ? lx : 1.f - lx) * ((c >> 1) ? ly : 1.f - ly);
            if (xi >= 0 && xi < WWn && yi >= 0 && yi < HHn) {
                const u16* src = vb + (size_t)(yi * WWn + xi) * CCn;
                #pragma unroll
                for (int q = 0; q < 4; ++q) {
                    u16x8 v = *(const u16x8*)(src + q * 8);
                    #pragma unroll
                    for (int e = 0; e < 8; ++e)
                        acc[q * 8 + e] += wgt * bf2f(v[e]);
                }
            }
        }
    }

    u16* dst = outp + (size_t)rn * CCn + h * 32;
    #pragma unroll
    for (int q = 0; q < 4; ++q) {
        u16x8 o;
        #pragma unroll
        for (int e = 0; e < 8; ++e) o[e] = f2bf(acc[q * 8 + e]);
        *(u16x8*)(dst + q * 8) = o;
    }
}

// ---------------------------------------------------------------------------
// all weight repacks + bias/LN packing in one kernel (layouts in comments of r3)
// ---------------------------------------------------------------------------
__global__ __launch_bounds__(256)
void repack_all(const float* __restrict__ vp1, const float* __restrict__ op1,
                const float* __restrict__ vp2, const float* __restrict__ op2,
                const float* __restrict__ f1w, const float* __restrict__ f2w,
                const float* __restrict__ of1, const float* __restrict__ aw1,
                const float* __restrict__ of2, const float* __restrict__ aw2,
                const float* __restrict__ g1,  const float* __restrict__ g2,
                const float* __restrict__ vpb1, const float* __restrict__ vpb2,
                const float* __restrict__ opb1, const float* __restrict__ opb2,
                const float* __restrict__ ofb1, const float* __restrict__ awb1,
                const float* __restrict__ ofb2, const float* __restrict__ awb2,
                const float* __restrict__ l1g, const float* __restrict__ l1b,
                const float* __restrict__ l2g, const float* __restrict__ l2b,
                u16* __restrict__ wb, float* __restrict__ bb)
{
    int i = blockIdx.x * 256 + threadIdx.x;
    if (i >= 1212416 + 2240) return;
    if (i >= 1212416) {
        int j = i - 1212416;
        float v;
        if      (j < 256)  v = vpb1[j];
        else if (j < 512)  v = vpb2[j - 256];
        else if (j < 768)  v = opb1[j - 512];
        else if (j < 1024) v = opb2[j - 768];
        else if (j < 1088) v = ofb1[j - 1024];
        else if (j < 1120) v = awb1[j - 1088];
        else if (j < 1184) v = ofb2[j - 1120];
        else if (j < 1216) v = awb2[j - 1184];
        else if (j < 1472) v = l1g[j - 1216];
        else if (j < 1728) v = l1b[j - 1472];
        else if (j < 1984) v = l2g[j - 1728];
        else               v = l2b[j - 1984];
        bb[j] = v;
        return;
    }
    float v;
    if (i < 262144) {
        const float* src[4] = { vp1, vp2, op1, op2 };
        int q = i >> 16, j = i & 65535;
        int n = j >> 8, k = j & 255;
        v = src[q][(size_t)k * 256 + n];
    } else if (i < 393216) {
        int j = i - 262144; int n = j >> 8, k = j & 255;      // [512][256]
        v = f1w[(size_t)k * 512 + n];
    } else if (i < 524288) {
        int j = i - 393216; int n = j >> 9, k = j & 511;      // [256][512]
        v = f2w[(size_t)k * 256 + n];
    } else if (i < 589824) {
        int jj = i - 524288; int hh = jj >> 15; int j = jj & 32767;
        int n = j >> 8, k = j & 255;                          // [128][256]
        const float* ofw = hh ? of2 : of1;
        const float* aww = hh ? aw2 : aw1;
        if (n < 64)      v = ofw[(size_t)k * 64 + n];
        else if (n < 96) v = aww[(size_t)k * 32 + (n - 64)];
        else             v = 0.f;
    } else if (i < 1179648) {
        int j = i - 589824; int co = j / 4608, k = j - co * 4608;
        int tap = k >> 9, ci = k & 511;
        v = g1[((size_t)co * 512 + ci) * 9 + tap];
    } else {
        int j = i - 1179648; int n = j >> 7, k = j & 127;     // [256][128]
        v = g2[(size_t)n * 128 + k];
    }
    wb[i] = f2bf(v);
}

// ---------------------------------------------------------------------------
extern "C" void kernel_launch(void* const* d_in, const int* in_sizes, int n_in,
                              void* d_out, int out_size, void* d_ws, size_t ws_size,
                              hipStream_t stream)
{
    const float* cam_bev   = (const float*)d_in[0];
    const float* sat_bev   = (const float*)d_in[1];
    const float* c2s_off_w  = (const float*)d_in[2];
    const float* c2s_off_b  = (const float*)d_in[3];
    const float* c2s_attw_w = (const float*)d_in[4];
    const float* c2s_attw_b = (const float*)d_in[5];
    const float* c2s_vp_w   = (const float*)d_in[6];
    const float* c2s_vp_b   = (const float*)d_in[7];
    const float* c2s_op_w   = (const float*)d_in[8];
    const float* c2s_op_b   = (const float*)d_in[9];
    const float* s2c_off_w  = (const float*)d_in[10];
    const float* s2c_off_b  = (const float*)d_in[11];
    const float* s2c_attw_w = (const float*)d_in[12];
    const float* s2c_attw_b = (const float*)d_in[13];
    const float* s2c_vp_w   = (const float*)d_in[14];
    const float* s2c_vp_b   = (const float*)d_in[15];
    const float* s2c_op_w   = (const float*)d_in[16];
    const float* s2c_op_b   = (const float*)d_in[17];
    const float* ln1_g = (const float*)d_in[18];
    const float* ln1_b = (const float*)d_in[19];
    const float* ln2_g = (const float*)d_in[20];
    const float* ln2_b = (const float*)d_in[21];
    const float* lnf_g = (const float*)d_in[22];
    const float* lnf_b = (const float*)d_in[23];
    const float* ffn1_w = (const float*)d_in[24];
    const float* ffn1_b = (const float*)d_in[25];
    const float* ffn2_w = (const float*)d_in[26];
    const float* ffn2_b = (const float*)d_in[27];
    const float* g1_w  = (const float*)d_in[28];
    const float* bn_g  = (const float*)d_in[29];
    const float* bn_b  = (const float*)d_in[30];
    const float* g2_w  = (const float*)d_in[31];
    const float* g2_b  = (const float*)d_in[32];

    char* base = (char*)d_ws;
    size_t off = 0;
    auto alloc = [&](size_t bytes) -> void* {
        void* p = base + off;
        off += (bytes + 255) & ~(size_t)255;
        return p;
    };

    u16*   qcam   = (u16*)  alloc((size_t)MTOT * CCn * 2 * 2);   // qcam|qsat contiguous
    u16*   qsat   = qcam + (size_t)MTOT * CCn;
    u16*   valb   = (u16*)  alloc((size_t)MTOT * CCn * 2 * 2);   // pair
    u16*   sampb  = (u16*)  alloc((size_t)MTOT * CCn * 2 * 2);   // pair (33.55MB)
    float* offb   = (float*)alloc((size_t)MTOT * 64 * 4 * 2);    // pair (16.78MB)
    float* attwb  = (float*)alloc((size_t)MTOT * 32 * 4 * 2);    // pair
    size_t padBytes = (size_t)BBn * PADW * PADW * 512 * 2;       // 34.6MB
    u16*   pad    = (u16*)  alloc(padBytes);
    u16*   hbuf   = (u16*)  alloc((size_t)MTOT * 128 * 2);
    u16*   wbase  = (u16*)  alloc((size_t)1212416 * 2);
    float* biasbf = (float*)alloc((size_t)2240 * 4);
    // weight slices
    u16* wvp = wbase;                 // pair, stride 65536
    u16* wop = wbase + 131072;        // pair, stride 65536
    u16* wf1 = wbase + 262144;
    u16* wf2 = wbase + 393216;
    u16* woa = wbase + 524288;        // pair, stride 32768
    u16* wcv = wbase + 589824;
    u16* wg2 = wbase + 1179648;
    // aliases (temporally disjoint)
    u16*   fused_bf = valb;              // valb dead after sampling
    float* convpart = (float*)sampb;     // sampb+offb dead after op-pair: 3x MTOT*128 f32 = 50.3MB
    u16*   midb     = qcam;              // qcam/qsat dead after op-pair (MTOT*512 bf16)

    dim3 blk(256);
    ZOff zz{0, 0, 0, 0, 0, 0, 0, 0, 0};

    hipMemsetAsync(pad, 0, padBytes, stream);
    tcvt_k<<<dim3(4, 256, 4), blk, 0, stream>>>(cam_bev, sat_bev, qcam, qsat);
    repack_all<<<4746, blk, 0, stream>>>(c2s_vp_w, c2s_op_w, s2c_vp_w, s2c_op_w,
                                         ffn1_w, ffn2_w, c2s_off_w, c2s_attw_w,
                                         s2c_off_w, s2c_attw_w, g1_w, g2_w,
                                         c2s_vp_b, s2c_vp_b, c2s_op_b, s2c_op_b,
                                         c2s_off_b, c2s_attw_b, s2c_off_b, s2c_attw_b,
                                         ln1_g, ln1_b, ln2_g, ln2_b,
                                         wbase, biasbf);

    // ---------- value projections (z=0: kv=sat, z=1: kv=cam) ----------
    {
        ZOff zo{ -(long)MTOT * CCn, 65536, 256, 0, 0, (long)MTOT * CCn, 0, 0, 0 };
        mgemm<128, 128, 2, 0, 256><<<dim3(2, 256, 2), blk, 0, stream>>>(
            qsat, wvp, biasbf, 256, 256,
            nullptr, nullptr, valb, nullptr, nullptr, nullptr, nullptr, 0, zo);
    }
    // ---------- offset+attw projections (z=0: q=cam, z=1: q=sat) ----------
    {
        ZOff zo{ (long)MTOT * CCn, 32768, 0, (long)MTOT * 64, (long)MTOT * 32, 0, 0, 96, 0 };
        mgemm<128, 128, 2, 2, 256><<<dim3(1, 256, 2), blk, 0, stream>>>(
            qcam, woa, nullptr, 256, 128,
            offb, attwb, nullptr, nullptr, nullptr, biasbf + 1024, biasbf + 1088, 0, zo);
    }
    // ---------- deformable sampling (both streams, thread = row-head) ----------
    sample_k<<<dim3(1024, 1, 2), blk, 0, stream>>>(valb, offb, attwb, sampb);
    // ---------- output projections + residual + LN -> pad image ----------
    {
        ZOff zo{ (long)MTOT * CCn, 65536, 256, 0, 0, 0, (long)MTOT * CCn, 512, 256 };
        mgemm<64, 256, 4, 7, 256><<<dim3(1, 512, 2), blk, 0, stream>>>(
            sampb, wop, biasbf + 512, 256, 256,
            nullptr, nullptr, pad, nullptr, qcam, biasbf + 1216, biasbf + 1472, 0, zo);
    }
    // ---------- gating conv: implicit GEMM, BK=64, split-K=3, f32 partials ----
    conv_k<3><<<dim3(1, 256, 3), blk, 0, stream>>>(pad, wcv, convpart);
    combine_k<<<4096, blk, 0, stream>>>(convpart, bn_g, bn_b, hbuf);

    // ---------- 1x1 conv + sigmoid + gated fusion (bf16 out only) ----------
    mgemm<128, 128, 2, 4, 128><<<dim3(2, 256, 1), blk, 0, stream>>>(
        hbuf, wg2, g2_b, 128, 256,
        nullptr, nullptr, fused_bf, pad, nullptr, nullptr, nullptr, 0, zz);

    // ---------- FFN ----------
    mgemm<128, 128, 2, 5, 256><<<dim3(4, 256, 1), blk, 0, stream>>>(
        fused_bf, wf1, ffn1_b, 256, 512,
        nullptr, nullptr, midb, nullptr, nullptr, nullptr, nullptr, 0, zz);
    // ffn2 + final LN + transpose to (B,C,N) + cam residual (EPI 9, bf16 resid)
    mgemm<64, 256, 4, 9, 512><<<dim3(1, 512, 1), blk, 0, stream>>>(
        midb, wf2, ffn2_b, 512, 256,
        (float*)d_out, (float*)cam_bev, nullptr, nullptr, fused_bf, lnf_g, lnf_b, 0, zz);
}

// Round 10
// 305.981 us; speedup vs baseline: 5.6869x; 1.0543x over previous
//
#include <hip/hip_runtime.h>
#include <hip/hip_bf16.h>
#include <cstddef>

#define BBn  2
#define CCn  256
#define HHn  128
#define WWn  128
#define NNn  (HHn*WWn)        // 16384
#define MTOT (BBn*NNn)        // 32768
#define PADW 130

typedef unsigned short u16;
typedef __attribute__((ext_vector_type(8))) short bf8v;
typedef __attribute__((ext_vector_type(8))) unsigned short u16x8;
typedef __attribute__((ext_vector_type(4))) float f4v;

typedef __attribute__((address_space(1))) const void gvoid_t;
typedef __attribute__((address_space(3))) void svoid_t;
#define ASYNC16(g, l) __builtin_amdgcn_global_load_lds((gvoid_t*)(g), (svoid_t*)(l), 16, 0, 0)

__device__ __forceinline__ u16 f2bf(float f) {
    __hip_bfloat16 h = __float2bfloat16(f);
    return *reinterpret_cast<u16*>(&h);
}
__device__ __forceinline__ float bf2f(u16 h) {
    return __uint_as_float(((unsigned)h) << 16);
}

// z-offsets (elements), applied scaled by blockIdx.z
struct ZOff {
    long a, w, bia, f1, f2, b1, r, p;
    int ch;
};

// ---------------------------------------------------------------------------
// bf16 MFMA GEMM, tile BM x BN, BK=32, 4 waves arranged WRxWC (WR=4/WC).
// A[M,KK] bf16 row-major (stride KK). Wt[Nc,ldw] bf16 pre-transposed.
// EPI: 0 bf16+bias | 2 off/attw split | 4 sigmoid-gate (bf16 out)
//      5 ReLU->bf16
//      7 resid(bf16)-init + rowLN -> pad bf16 | 9 resid(bf16)-init + rowLN -> (B,C,N) + cam
// ---------------------------------------------------------------------------
template<int BM, int BN, int WC, int EPI, int KK>
__global__ __launch_bounds__(256)
void mgemm(const u16* __restrict__ A, const u16* __restrict__ Wt,
           const float* __restrict__ bias, int ldw, int Nc,
           float* __restrict__ outf, float* __restrict__ outf2,
           u16* __restrict__ outb, const u16* __restrict__ img,
           const void* __restrict__ resid,
           const float* __restrict__ p0, const float* __restrict__ p1,
           int choff, ZOff zo)
{
    constexpr int WR = 4 / WC;
    constexpr int MROWS = BM / WR;       // rows per wave
    constexpr int MI = MROWS / 16;
    constexpr int AT = BM / 64;          // A staging chunks per thread
    constexpr int BT = BN / 64;

    __shared__ __align__(16) u16 As[BM * 32];
    __shared__ __align__(16) u16 Bs[BN * 32];
    __shared__ float red[4][64][2];      // LN cross-wave partials (EPI 7/9)

    const int z = blockIdx.z;
    if (z) {
        A += (long)z * zo.a; Wt += (long)z * zo.w;
        if (bias)  bias  += (long)z * zo.bia;
        if (outf)  outf  += (long)z * zo.f1;
        if (outf2) outf2 += (long)z * zo.f2;
        if (outb)  outb  += (long)z * zo.b1;
        if (p0)    p0    += (long)z * zo.p;
        if (p1)    p1    += (long)z * zo.p;
        choff += z * zo.ch;
    }

    const int tid  = threadIdx.x;
    const int lane = tid & 63;
    const int w    = tid >> 6;
    const int wr   = w / WC, wc = w % WC;
    const int by = blockIdx.y;
    const int m0 = by * BM;
    const int n0 = blockIdx.x * BN;
    const int lr = lane & 15, lq = lane >> 4;
    const int kb = lq * 8;

    // staging source pointers
    const u16* gA[AT];
    #pragma unroll
    for (int t = 0; t < AT; ++t) {
        int c = t * 256 + tid; int row = c >> 2; int part = c & 3;
        gA[t] = A + (size_t)(m0 + row) * KK + part * 8;
    }
    const u16* gB[BT];
    #pragma unroll
    for (int t = 0; t < BT; ++t) {
        int c = t * 256 + tid; int row = c >> 2; int part = c & 3;
        gB[t] = Wt + (size_t)(n0 + row) * ldw + part * 8;
    }

    // accumulator (residual+bias init for LN epilogues; WR==1 there)
    f4v acc[MI][4];
    if constexpr (EPI == 7 || EPI == 9) {
        const u16* r16 = (const u16*)resid + (EPI == 7 ? (long)z * zo.r : 0);
        #pragma unroll
        for (int j = 0; j < 4; ++j) {
            int n = wc * 64 + j * 16 + lr;
            float bj = bias[n];
            #pragma unroll
            for (int i = 0; i < MI; ++i)
                #pragma unroll
                for (int r = 0; r < 4; ++r) {
                    int m = m0 + i * 16 + lq * 4 + r;
                    acc[i][j][r] = bf2f(r16[(size_t)m * 256 + n]) + bj;
                }
        }
    } else {
        #pragma unroll
        for (int i = 0; i < MI; ++i)
            #pragma unroll
            for (int j = 0; j < 4; ++j)
                acc[i][j] = (f4v){0.f, 0.f, 0.f, 0.f};
    }

    for (int k0 = 0; k0 < KK; k0 += 32) {
        #pragma unroll
        for (int t = 0; t < AT; ++t)
            ASYNC16(gA[t] + k0, (u16*)As + (t * 256 + tid) * 8);
        #pragma unroll
        for (int t = 0; t < BT; ++t)
            ASYNC16(gB[t] + k0, (u16*)Bs + (t * 256 + tid) * 8);
        __syncthreads();

        bf8v af[MI], bv[4];
        #pragma unroll
        for (int i = 0; i < MI; ++i)
            af[i] = *(const bf8v*)&As[(wr * MROWS + i * 16 + lr) * 32 + kb];
        #pragma unroll
        for (int j = 0; j < 4; ++j)
            bv[j] = *(const bf8v*)&Bs[(wc * 64 + j * 16 + lr) * 32 + kb];
        #pragma unroll
        for (int i = 0; i < MI; ++i)
            #pragma unroll
            for (int j = 0; j < 4; ++j)
                acc[i][j] = __builtin_amdgcn_mfma_f32_16x16x32_bf16(af[i], bv[j], acc[i][j], 0, 0, 0);
        __syncthreads();
    }

    // -------------------- epilogue --------------------
    if constexpr (EPI == 7 || EPI == 9) {
        float g4[4], b4[4];
        #pragma unroll
        for (int j = 0; j < 4; ++j) {
            int n = wc * 64 + j * 16 + lr;
            g4[j] = p0[n]; b4[j] = p1[n];
        }
        #pragma unroll
        for (int i = 0; i < MI; ++i)
            #pragma unroll
            for (int r = 0; r < 4; ++r) {
                float p = 0.f, p2 = 0.f;
                #pragma unroll
                for (int j = 0; j < 4; ++j) { float v = acc[i][j][r]; p += v; p2 += v * v; }
                p += __shfl_xor(p, 1, 16);  p2 += __shfl_xor(p2, 1, 16);
                p += __shfl_xor(p, 2, 16);  p2 += __shfl_xor(p2, 2, 16);
                p += __shfl_xor(p, 4, 16);  p2 += __shfl_xor(p2, 4, 16);
                p += __shfl_xor(p, 8, 16);  p2 += __shfl_xor(p2, 8, 16);
                if (lr == 0) {
                    int row = i * 16 + lq * 4 + r;
                    red[w][row][0] = p; red[w][row][1] = p2;
                }
            }
        __syncthreads();
        #pragma unroll
        for (int i = 0; i < MI; ++i) {
            float mean4[4], rstd4[4];
            #pragma unroll
            for (int r = 0; r < 4; ++r) {
                int row = i * 16 + lq * 4 + r;
                float s  = red[0][row][0] + red[1][row][0] + red[2][row][0] + red[3][row][0];
                float s2 = red[0][row][1] + red[1][row][1] + red[2][row][1] + red[3][row][1];
                float mean = s * (1.f / 256.f);
                float var  = s2 * (1.f / 256.f) - mean * mean;
                mean4[r] = mean;
                rstd4[r] = rsqrtf(var + 1e-5f);
            }
            if constexpr (EPI == 7) {
                #pragma unroll
                for (int r = 0; r < 4; ++r) {
                    int m = m0 + i * 16 + lq * 4 + r;
                    int b = m >> 14, sp = m & (NNn - 1);
                    size_t pb = (((size_t)b * PADW + (sp >> 7) + 1) * PADW + (sp & 127) + 1) * 512 + choff;
                    #pragma unroll
                    for (int j = 0; j < 4; ++j) {
                        int n = wc * 64 + j * 16 + lr;
                        outb[pb + n] = f2bf((acc[i][j][r] - mean4[r]) * rstd4[r] * g4[j] + b4[j]);
                    }
                }
            } else {
                // transposed write to (B,C,N) + cam residual (outf2 = cam_bev)
                int mb = m0 + i * 16 + lq * 4;
                int b = mb >> 14, sp = mb & (NNn - 1);
                #pragma unroll
                for (int j = 0; j < 4; ++j) {
                    int n = wc * 64 + j * 16 + lr;
                    size_t oi = ((size_t)b * 256 + n) * NNn + sp;
                    float4 cv = *(const float4*)&outf2[oi];
                    float4 o;
                    o.x = (acc[i][j][0] - mean4[0]) * rstd4[0] * g4[j] + b4[j] + cv.x;
                    o.y = (acc[i][j][1] - mean4[1]) * rstd4[1] * g4[j] + b4[j] + cv.y;
                    o.z = (acc[i][j][2] - mean4[2]) * rstd4[2] * g4[j] + b4[j] + cv.z;
                    o.w = (acc[i][j][3] - mean4[3]) * rstd4[3] * g4[j] + b4[j] + cv.w;
                    *(float4*)&outf[oi] = o;
                }
            }
        }
        return;
    }

    float bj[4]; int ncol[4];
    #pragma unroll
    for (int j = 0; j < 4; ++j) {
        int n = n0 + wc * 64 + j * 16 + lr;
        ncol[j] = n;
        if constexpr (EPI == 0 || EPI == 4 || EPI == 5) bj[j] = bias[n];
    }
    #pragma unroll
    for (int i = 0; i < MI; ++i) {
        #pragma unroll
        for (int r = 0; r < 4; ++r) {
            int m = m0 + wr * MROWS + i * 16 + lq * 4 + r;
            size_t pb = 0;
            if constexpr (EPI == 4) {
                int b = m >> 14, sp = m & (NNn - 1);
                pb = (((size_t)b * PADW + (sp >> 7) + 1) * PADW + (sp & 127) + 1) * 512;
            }
            #pragma unroll
            for (int j = 0; j < 4; ++j) {
                int n = ncol[j];
                float v = acc[i][j][r];
                size_t oi = (size_t)m * Nc + n;
                if constexpr (EPI == 0) {
                    outb[oi] = f2bf(v + bj[j]);
                } else if constexpr (EPI == 2) {
                    if (n < 64)      outf [(size_t)m * 64 + n]        = v + p0[n];
                    else if (n < 96) outf2[(size_t)m * 32 + (n - 64)] = v + p1[n - 64];
                } else if constexpr (EPI == 4) {
                    float vv = v + bj[j];
                    float g = 1.f / (1.f + __expf(-vv));
                    float f = g * bf2f(img[pb + n]) + (1.f - g) * bf2f(img[pb + 256 + n]);
                    outb[oi] = f2bf(f);
                } else if constexpr (EPI == 5) {
                    outb[oi] = f2bf(fmaxf(v + bj[j], 0.f));
                }
            }
        }
    }
}

// ---------------------------------------------------------------------------
// dedicated conv kernel: 128x128 tile, BK=64 (32 MFMA per barrier-pair),
// both-sides XOR swizzle (source chunk ^= row&7; fragment read same XOR).
// grid (1, 256, 3): z = tap-triple, f32 partial out.
// ---------------------------------------------------------------------------
template<int TAPS>
__global__ __launch_bounds__(256)
void conv_k(const u16* __restrict__ img, const u16* __restrict__ Wt,
            float* __restrict__ outp)
{
    __shared__ __align__(16) u16 As[128 * 64];
    __shared__ __align__(16) u16 Bs[128 * 64];

    const int z = blockIdx.z;
    outp += (size_t)z * MTOT * 128;
    const int tid = threadIdx.x;
    const int lane = tid & 63;
    const int w = tid >> 6;
    const int wr = w >> 1, wc = w & 1;
    int by = blockIdx.y;
    by = ((by & 7) << 5) | (by >> 3);       // XCD swizzle (256 = 8*32)
    const int m0 = by * 128;
    const int lr = lane & 15, lq = lane >> 4;

    // staging: 4 chunks/thread for A and B; chunk c -> row=c>>3, part=c&7
    // source k-chunk pre-swizzled: pg = part ^ (row&7); LDS dest linear.
    long cbA[4]; int pgA[4]; const u16* wB[4]; int ldsOff[4];
    #pragma unroll
    for (int t = 0; t < 4; ++t) {
        int c = t * 256 + tid;
        int row = c >> 3, part = c & 7;
        int pg = part ^ (row & 7);
        ldsOff[t] = c * 8;
        int m = m0 + row; int b = m >> 14; int sp = m & (NNn - 1);
        cbA[t] = ((long)b * PADW + (sp >> 7)) * PADW + (sp & 127);
        pgA[t] = pg;
        wB[t] = Wt + (size_t)row * 4608 + pg * 8;
    }

    f4v acc[4][4];
    #pragma unroll
    for (int i = 0; i < 4; ++i)
        #pragma unroll
        for (int j = 0; j < 4; ++j)
            acc[i][j] = (f4v){0.f, 0.f, 0.f, 0.f};

    const int tap0 = z * TAPS;
    #pragma unroll
    for (int tt = 0; tt < TAPS; ++tt) {
        int tap = tap0 + tt;
        int dy = tap / 3, dx = tap - dy * 3;
        const u16* bpA[4]; const u16* bpB[4];
        #pragma unroll
        for (int t = 0; t < 4; ++t) {
            bpA[t] = img + (size_t)(cbA[t] + dy * PADW + dx) * 512 + pgA[t] * 8;
            bpB[t] = wB[t] + tap * 512;
        }
        #pragma unroll 2
        for (int ci = 0; ci < 512; ci += 64) {
            #pragma unroll
            for (int t = 0; t < 4; ++t)
                ASYNC16(bpA[t] + ci, (u16*)As + ldsOff[t]);
            #pragma unroll
            for (int t = 0; t < 4; ++t)
                ASYNC16(bpB[t] + ci, (u16*)Bs + ldsOff[t]);
            __syncthreads();
            #pragma unroll
            for (int kk = 0; kk < 2; ++kk) {
                bf8v af[4], bv[4];
                #pragma unroll
                for (int i = 0; i < 4; ++i) {
                    int row = wr * 64 + i * 16 + lr;
                    af[i] = *(const bf8v*)&As[(row * 8 + ((kk * 4 + lq) ^ (row & 7))) * 8];
                }
                #pragma unroll
                for (int j = 0; j < 4; ++j) {
                    int row = wc * 64 + j * 16 + lr;
                    bv[j] = *(const bf8v*)&Bs[(row * 8 + ((kk * 4 + lq) ^ (row & 7))) * 8];
                }
                #pragma unroll
                for (int i = 0; i < 4; ++i)
                    #pragma unroll
                    for (int j = 0; j < 4; ++j)
                        acc[i][j] = __builtin_amdgcn_mfma_f32_16x16x32_bf16(af[i], bv[j], acc[i][j], 0, 0, 0);
            }
            __syncthreads();
        }
    }

    #pragma unroll
    for (int i = 0; i < 4; ++i)
        #pragma unroll
        for (int r = 0; r < 4; ++r) {
            int m = m0 + wr * 64 + i * 16 + lq * 4 + r;
            #pragma unroll
            for (int j = 0; j < 4; ++j) {
                int n = wc * 64 + j * 16 + lr;
                outp[(size_t)m * 128 + n] = acc[i][j][r];
            }
        }
}

// ---------------------------------------------------------------------------
// split-K combine (3 partials) + BN + ReLU -> bf16
// ---------------------------------------------------------------------------
__global__ __launch_bounds__(256)
void combine_k(const float* __restrict__ part, const float* __restrict__ bng,
               const float* __restrict__ bnb, u16* __restrict__ hb)
{
    const float bnscale = rsqrtf(1.0f + 1e-5f);
    int i = (blockIdx.x * 256 + threadIdx.x) * 4;   // over MTOT*128
    int n = i & 127;
    float4 a = *(const float4*)&part[i];
    float4 b = *(const float4*)&part[(size_t)MTOT * 128 + i];
    float4 c = *(const float4*)&part[(size_t)MTOT * 256 + i];
    ushort4 o;
    o.x = f2bf(fmaxf((a.x + b.x + c.x) * bnscale * bng[n + 0] + bnb[n + 0], 0.f));
    o.y = f2bf(fmaxf((a.y + b.y + c.y) * bnscale * bng[n + 1] + bnb[n + 1], 0.f));
    o.z = f2bf(fmaxf((a.z + b.z + c.z) * bnscale * bng[n + 2] + bnb[n + 2], 0.f));
    o.w = f2bf(fmaxf((a.w + b.w + c.w) * bnscale * bng[n + 3] + bnb[n + 3], 0.f));
    *(ushort4*)&hb[i] = o;
}

// ---------------------------------------------------------------------------
// bev (B,C,N) f32 -> (B*N, C) bf16 ; z: 0-1 cam batches, 2-3 sat batches
// ---------------------------------------------------------------------------
__global__ __launch_bounds__(256)
void tcvt_k(const float* __restrict__ cam, const float* __restrict__ sat,
            u16* __restrict__ qcam, u16* __restrict__ qsat)
{
    __shared__ float t[64][65];
    int z = blockIdx.z;
    const float* src = (z < 2) ? cam : sat;
    u16* dst = (z < 2) ? qcam : qsat;
    int b = z & 1;
    int c0 = blockIdx.x * 64, sp0 = blockIdx.y * 64;
    #pragma unroll
    for (int it = 0; it < 16; ++it) {
        int idx = it * 256 + threadIdx.x;
        int cl = idx >> 6, sl = idx & 63;
        t[cl][sl] = src[((size_t)(b * CCn + c0 + cl)) * NNn + sp0 + sl];
    }
    __syncthreads();
    #pragma unroll
    for (int it = 0; it < 16; ++it) {
        int idx = it * 256 + threadIdx.x;
        int sl = idx >> 6, cl = idx & 63;
        dst[((size_t)(b * NNn + sp0 + sl)) * CCn + c0 + cl] = f2bf(t[cl][sl]);
    }
}

// ---------------------------------------------------------------------------
// deformable sampling, two-phase:
//  phase 1: 32 leader lanes compute per-(row,head) descriptors (16 corners:
//           clamped addr + weight, weight=0 if OOB) into LDS.
//  phase 2: 8 lanes per (row,head), 4 channels each -> coalesced 64B gathers.
// z = blockIdx.z selects c2s / s2c stream. block = 32 row-heads.
// ---------------------------------------------------------------------------
__global__ __launch_bounds__(256)
void sample_k(const u16* __restrict__ val, const float* __restrict__ off,
              const float* __restrict__ lg, u16* __restrict__ outp)
{
    __shared__ uint2 desc[32][17];     // padded stride: avoid fixed-k bank camp

    int z = blockIdx.z;
    val  += (size_t)z * MTOT * CCn;
    off  += (size_t)z * MTOT * 64;
    lg   += (size_t)z * MTOT * 32;
    outp += (size_t)z * MTOT * CCn;

    const int tid = threadIdx.x;
    const int rh0 = blockIdx.x * 32;           // first row-head of block

    if (tid < 32) {
        int rhg = rh0 + tid;
        int h = rhg & 7, rn = rhg >> 3;
        int n = rn & (NNn - 1), b = rn >> 14;
        int yp = n >> 7, xp = n & 127;

        const float* ofp = off + (size_t)rn * 64 + h * 8;
        const float* lgp = lg  + (size_t)rn * 32 + h * 4;
        float4 of0 = *(const float4*)ofp;
        float4 of1 = *(const float4*)(ofp + 4);
        float4 lgv = *(const float4*)lgp;
        float ofx[4] = { of0.x, of0.z, of1.x, of1.z };
        float ofy[4] = { of0.y, of0.w, of1.y, of1.w };

        float mx = fmaxf(fmaxf(lgv.x, lgv.y), fmaxf(lgv.z, lgv.w));
        float e0 = __expf(lgv.x - mx), e1 = __expf(lgv.y - mx);
        float e2 = __expf(lgv.z - mx), e3 = __expf(lgv.w - mx);
        float inv = 1.f / (e0 + e1 + e2 + e3);
        float aw[4] = { e0 * inv, e1 * inv, e2 * inv, e3 * inv };

        unsigned hb = (unsigned)(b * NNn) * 256u + h * 32;
        #pragma unroll
        for (int p = 0; p < 4; ++p) {
            float xs = (float)xp + ofx[p];
            float ys = (float)yp + ofy[p];
            float x0f = floorf(xs), y0f = floorf(ys);
            float lx = xs - x0f, ly = ys - y0f;
            int x0 = (int)x0f, y0 = (int)y0f;
            #pragma unroll
            for (int c = 0; c < 4; ++c) {
                int xi = x0 + (c & 1), yi = y0 + (c >> 1);
                bool valid = (xi >= 0) & (xi < WWn) & (yi >= 0) & (yi < HHn);
                float wgt = valid
                    ? aw[p] * ((c & 1) ? lx : 1.f - lx) * ((c >> 1) ? ly : 1.f - ly)
                    : 0.f;
                int xc = min(max(xi, 0), WWn - 1);
                int yc = min(max(yi, 0), HHn - 1);
                unsigned addr = hb + (unsigned)(yc * WWn + xc) * 256u;
                desc[tid][p * 4 + c] = make_uint2(addr, __float_as_uint(wgt));
            }
        }
    }
    __syncthreads();

    const int rh = tid >> 3;                   // 0..31
    const int q  = tid & 7;                    // channel quad
    const int rhg = rh0 + rh;
    const int h = rhg & 7, rn = rhg >> 3;

    float a0 = 0.f, a1 = 0.f, a2 = 0.f, a3 = 0.f;
    #pragma unroll
    for (int k = 0; k < 16; ++k) {
        uint2 d = desc[rh][k];
        float wgt = __uint_as_float(d.y);
        ushort4 v = *(const ushort4*)(val + d.x + q * 4);
        a0 += wgt * bf2f(v.x);
        a1 += wgt * bf2f(v.y);
        a2 += wgt * bf2f(v.z);
        a3 += wgt * bf2f(v.w);
    }
    ushort4 o;
    o.x = f2bf(a0); o.y = f2bf(a1); o.z = f2bf(a2); o.w = f2bf(a3);
    *(ushort4*)(outp + (size_t)rn * CCn + h * 32 + q * 4) = o;
}

// ---------------------------------------------------------------------------
// all weight repacks + bias/LN packing in one kernel (layouts in comments of r3)
// ---------------------------------------------------------------------------
__global__ __launch_bounds__(256)
void repack_all(const float* __restrict__ vp1, const float* __restrict__ op1,
                const float* __restrict__ vp2, const float* __restrict__ op2,
                const float* __restrict__ f1w, const float* __restrict__ f2w,
                const float* __restrict__ of1, const float* __restrict__ aw1,
                const float* __restrict__ of2, const float* __restrict__ aw2,
                const float* __restrict__ g1,  const float* __restrict__ g2,
                const float* __restrict__ vpb1, const float* __restrict__ vpb2,
                const float* __restrict__ opb1, const float* __restrict__ opb2,
                const float* __restrict__ ofb1, const float* __restrict__ awb1,
                const float* __restrict__ ofb2, const float* __restrict__ awb2,
                const float* __restrict__ l1g, const float* __restrict__ l1b,
                const float* __restrict__ l2g, const float* __restrict__ l2b,
                u16* __restrict__ wb, float* __restrict__ bb)
{
    int i = blockIdx.x * 256 + threadIdx.x;
    if (i >= 1212416 + 2240) return;
    if (i >= 1212416) {
        int j = i - 1212416;
        float v;
        if      (j < 256)  v = vpb1[j];
        else if (j < 512)  v = vpb2[j - 256];
        else if (j < 768)  v = opb1[j - 512];
        else if (j < 1024) v = opb2[j - 768];
        else if (j < 1088) v = ofb1[j - 1024];
        else if (j < 1120) v = awb1[j - 1088];
        else if (j < 1184) v = ofb2[j - 1120];
        else if (j < 1216) v = awb2[j - 1184];
        else if (j < 1472) v = l1g[j - 1216];
        else if (j < 1728) v = l1b[j - 1472];
        else if (j < 1984) v = l2g[j - 1728];
        else               v = l2b[j - 1984];
        bb[j] = v;
        return;
    }
    float v;
    if (i < 262144) {
        const float* src[4] = { vp1, vp2, op1, op2 };
        int q = i >> 16, j = i & 65535;
        int n = j >> 8, k = j & 255;
        v = src[q][(size_t)k * 256 + n];
    } else if (i < 393216) {
        int j = i - 262144; int n = j >> 8, k = j & 255;      // [512][256]
        v = f1w[(size_t)k * 512 + n];
    } else if (i < 524288) {
        int j = i - 393216; int n = j >> 9, k = j & 511;      // [256][512]
        v = f2w[(size_t)k * 256 + n];
    } else if (i < 589824) {
        int jj = i - 524288; int hh = jj >> 15; int j = jj & 32767;
        int n = j >> 8, k = j & 255;                          // [128][256]
        const float* ofw = hh ? of2 : of1;
        const float* aww = hh ? aw2 : aw1;
        if (n < 64)      v = ofw[(size_t)k * 64 + n];
        else if (n < 96) v = aww[(size_t)k * 32 + (n - 64)];
        else             v = 0.f;
    } else if (i < 1179648) {
        int j = i - 589824; int co = j / 4608, k = j - co * 4608;
        int tap = k >> 9, ci = k & 511;
        v = g1[((size_t)co * 512 + ci) * 9 + tap];
    } else {
        int j = i - 1179648; int n = j >> 7, k = j & 127;     // [256][128]
        v = g2[(size_t)n * 128 + k];
    }
    wb[i] = f2bf(v);
}

// ---------------------------------------------------------------------------
extern "C" void kernel_launch(void* const* d_in, const int* in_sizes, int n_in,
                              void* d_out, int out_size, void* d_ws, size_t ws_size,
                              hipStream_t stream)
{
    const float* cam_bev   = (const float*)d_in[0];
    const float* sat_bev   = (const float*)d_in[1];
    const float* c2s_off_w  = (const float*)d_in[2];
    const float* c2s_off_b  = (const float*)d_in[3];
    const float* c2s_attw_w = (const float*)d_in[4];
    const float* c2s_attw_b = (const float*)d_in[5];
    const float* c2s_vp_w   = (const float*)d_in[6];
    const float* c2s_vp_b   = (const float*)d_in[7];
    const float* c2s_op_w   = (const float*)d_in[8];
    const float* c2s_op_b   = (const float*)d_in[9];
    const float* s2c_off_w  = (const float*)d_in[10];
    const float* s2c_off_b  = (const float*)d_in[11];
    const float* s2c_attw_w = (const float*)d_in[12];
    const float* s2c_attw_b = (const float*)d_in[13];
    const float* s2c_vp_w   = (const float*)d_in[14];
    const float* s2c_vp_b   = (const float*)d_in[15];
    const float* s2c_op_w   = (const float*)d_in[16];
    const float* s2c_op_b   = (const float*)d_in[17];
    const float* ln1_g = (const float*)d_in[18];
    const float* ln1_b = (const float*)d_in[19];
    const float* ln2_g = (const float*)d_in[20];
    const float* ln2_b = (const float*)d_in[21];
    const float* lnf_g = (const float*)d_in[22];
    const float* lnf_b = (const float*)d_in[23];
    const float* ffn1_w = (const float*)d_in[24];
    const float* ffn1_b = (const float*)d_in[25];
    const float* ffn2_w = (const float*)d_in[26];
    const float* ffn2_b = (const float*)d_in[27];
    const float* g1_w  = (const float*)d_in[28];
    const float* bn_g  = (const float*)d_in[29];
    const float* bn_b  = (const float*)d_in[30];
    const float* g2_w  = (const float*)d_in[31];
    const float* g2_b  = (const float*)d_in[32];

    char* base = (char*)d_ws;
    size_t off = 0;
    auto alloc = [&](size_t bytes) -> void* {
        void* p = base + off;
        off += (bytes + 255) & ~(size_t)255;
        return p;
    };

    u16*   qcam   = (u16*)  alloc((size_t)MTOT * CCn * 2 * 2);   // qcam|qsat contiguous
    u16*   qsat   = qcam + (size_t)MTOT * CCn;
    u16*   valb   = (u16*)  alloc((size_t)MTOT * CCn * 2 * 2);   // pair
    u16*   sampb  = (u16*)  alloc((size_t)MTOT * CCn * 2 * 2);   // pair (33.55MB)
    float* offb   = (float*)alloc((size_t)MTOT * 64 * 4 * 2);    // pair (16.78MB)
    float* attwb  = (float*)alloc((size_t)MTOT * 32 * 4 * 2);    // pair
    size_t padBytes = (size_t)BBn * PADW * PADW * 512 * 2;       // 34.6MB
    u16*   pad    = (u16*)  alloc(padBytes);
    u16*   hbuf   = (u16*)  alloc((size_t)MTOT * 128 * 2);
    u16*   wbase  = (u16*)  alloc((size_t)1212416 * 2);
    float* biasbf = (float*)alloc((size_t)2240 * 4);
    // weight slices
    u16* wvp = wbase;                 // pair, stride 65536
    u16* wop = wbase + 131072;        // pair, stride 65536
    u16* wf1 = wbase + 262144;
    u16* wf2 = wbase + 393216;
    u16* woa = wbase + 524288;        // pair, stride 32768
    u16* wcv = wbase + 589824;
    u16* wg2 = wbase + 1179648;
    // aliases (temporally disjoint)
    u16*   fused_bf = valb;              // valb dead after sampling
    float* convpart = (float*)sampb;     // sampb+offb dead after op-pair: 3x MTOT*128 f32 = 50.3MB
    u16*   midb     = qcam;              // qcam/qsat dead after op-pair (MTOT*512 bf16)

    dim3 blk(256);
    ZOff zz{0, 0, 0, 0, 0, 0, 0, 0, 0};

    hipMemsetAsync(pad, 0, padBytes, stream);
    tcvt_k<<<dim3(4, 256, 4), blk, 0, stream>>>(cam_bev, sat_bev, qcam, qsat);
    repack_all<<<4746, blk, 0, stream>>>(c2s_vp_w, c2s_op_w, s2c_vp_w, s2c_op_w,
                                         ffn1_w, ffn2_w, c2s_off_w, c2s_attw_w,
                                         s2c_off_w, s2c_attw_w, g1_w, g2_w,
                                         c2s_vp_b, s2c_vp_b, c2s_op_b, s2c_op_b,
                                         c2s_off_b, c2s_attw_b, s2c_off_b, s2c_attw_b,
                                         ln1_g, ln1_b, ln2_g, ln2_b,
                                         wbase, biasbf);

    // ---------- value projections (z=0: kv=sat, z=1: kv=cam) ----------
    {
        ZOff zo{ -(long)MTOT * CCn, 65536, 256, 0, 0, (long)MTOT * CCn, 0, 0, 0 };
        mgemm<128, 128, 2, 0, 256><<<dim3(2, 256, 2), blk, 0, stream>>>(
            qsat, wvp, biasbf, 256, 256,
            nullptr, nullptr, valb, nullptr, nullptr, nullptr, nullptr, 0, zo);
    }
    // ---------- offset+attw projections (z=0: q=cam, z=1: q=sat) ----------
    {
        ZOff zo{ (long)MTOT * CCn, 32768, 0, (long)MTOT * 64, (long)MTOT * 32, 0, 0, 96, 0 };
        mgemm<128, 128, 2, 2, 256><<<dim3(1, 256, 2), blk, 0, stream>>>(
            qcam, woa, nullptr, 256, 128,
            offb, attwb, nullptr, nullptr, nullptr, biasbf + 1024, biasbf + 1088, 0, zo);
    }
    // ---------- deformable sampling (both streams, 2-phase, block = 32 rh) ----
    sample_k<<<dim3(8192, 1, 2), blk, 0, stream>>>(valb, offb, attwb, sampb);
    // ---------- output projections + residual + LN -> pad image ----------
    {
        ZOff zo{ (long)MTOT * CCn, 65536, 256, 0, 0, 0, (long)MTOT * CCn, 512, 256 };
        mgemm<64, 256, 4, 7, 256><<<dim3(1, 512, 2), blk, 0, stream>>>(
            sampb, wop, biasbf + 512, 256, 256,
            nullptr, nullptr, pad, nullptr, qcam, biasbf + 1216, biasbf + 1472, 0, zo);
    }
    // ---------- gating conv: implicit GEMM, BK=64, split-K=3, f32 partials ----
    conv_k<3><<<dim3(1, 256, 3), blk, 0, stream>>>(pad, wcv, convpart);
    combine_k<<<4096, blk, 0, stream>>>(convpart, bn_g, bn_b, hbuf);

    // ---------- 1x1 conv + sigmoid + gated fusion (bf16 out only) ----------
    mgemm<128, 128, 2, 4, 128><<<dim3(2, 256, 1), blk, 0, stream>>>(
        hbuf, wg2, g2_b, 128, 256,
        nullptr, nullptr, fused_bf, pad, nullptr, nullptr, nullptr, 0, zz);

    // ---------- FFN ----------
    mgemm<128, 128, 2, 5, 256><<<dim3(4, 256, 1), blk, 0, stream>>>(
        fused_bf, wf1, ffn1_b, 256, 512,
        nullptr, nullptr, midb, nullptr, nullptr, nullptr, nullptr, 0, zz);
    // ffn2 + final LN + transpose to (B,C,N) + cam residual (EPI 9, bf16 resid)
    mgemm<64, 256, 4, 9, 512><<<dim3(1, 512, 1), blk, 0, stream>>>(
        midb, wf2, ffn2_b, 512, 256,
        (float*)d_out, (float*)cam_bev, nullptr, nullptr, fused_bf, lnf_g, lnf_b, 0, zz);
}

// Round 11
// 298.702 us; speedup vs baseline: 5.8255x; 1.0244x over previous
//
#include <hip/hip_runtime.h>
#include <hip/hip_bf16.h>
#include <cstddef>

#define BBn  2
#define CCn  256
#define HHn  128
#define WWn  128
#define NNn  (HHn*WWn)        // 16384
#define MTOT (BBn*NNn)        // 32768
#define PADW 130

typedef unsigned short u16;
typedef __attribute__((ext_vector_type(8))) short bf8v;
typedef __attribute__((ext_vector_type(8))) unsigned short u16x8;
typedef __attribute__((ext_vector_type(4))) float f4v;

typedef __attribute__((address_space(1))) const void gvoid_t;
typedef __attribute__((address_space(3))) void svoid_t;
#define ASYNC16(g, l) __builtin_amdgcn_global_load_lds((gvoid_t*)(g), (svoid_t*)(l), 16, 0, 0)

__device__ __forceinline__ u16 f2bf(float f) {
    __hip_bfloat16 h = __float2bfloat16(f);
    return *reinterpret_cast<u16*>(&h);
}
__device__ __forceinline__ float bf2f(u16 h) {
    return __uint_as_float(((unsigned)h) << 16);
}

// z-offsets (elements), applied scaled by blockIdx.z
struct ZOff {
    long a, w, bia, f1, f2, b1, r, p;
    int ch;
};

// ---------------------------------------------------------------------------
// bf16 MFMA GEMM, tile BM x BN, BK=32, double-buffered LDS (stage-ahead),
// both-sides XOR swizzle: chunk' = chunk ^ ((row>>1)&3).
// A[M,KK] bf16 row-major. Wt[Nc,ldw] bf16 pre-transposed.
// EPI: 0 bf16+bias | 2 off/attw split | 4 sigmoid-gate (bf16 out)
//      5 ReLU->bf16
//      7 resid(bf16)-init + rowLN -> pad bf16 | 9 resid(bf16)-init + rowLN -> (B,C,N) + cam
// ---------------------------------------------------------------------------
template<int BM, int BN, int WC, int EPI, int KK>
__global__ __launch_bounds__(256)
void mgemm(const u16* __restrict__ A, const u16* __restrict__ Wt,
           const float* __restrict__ bias, int ldw, int Nc,
           float* __restrict__ outf, float* __restrict__ outf2,
           u16* __restrict__ outb, const u16* __restrict__ img,
           const void* __restrict__ resid,
           const float* __restrict__ p0, const float* __restrict__ p1,
           int choff, ZOff zo)
{
    constexpr int WR = 4 / WC;
    constexpr int MROWS = BM / WR;       // rows per wave
    constexpr int MI = MROWS / 16;
    constexpr int AT = BM / 64;          // A staging chunks per thread
    constexpr int BT = BN / 64;
    constexpr int NSTEPS = KK / 32;

    __shared__ __align__(16) u16 As[2 * BM * 32];
    __shared__ __align__(16) u16 Bs[2 * BN * 32];
    __shared__ float red[4][64][2];      // LN cross-wave partials (EPI 7/9)

    const int z = blockIdx.z;
    if (z) {
        A += (long)z * zo.a; Wt += (long)z * zo.w;
        if (bias)  bias  += (long)z * zo.bia;
        if (outf)  outf  += (long)z * zo.f1;
        if (outf2) outf2 += (long)z * zo.f2;
        if (outb)  outb  += (long)z * zo.b1;
        if (p0)    p0    += (long)z * zo.p;
        if (p1)    p1    += (long)z * zo.p;
        choff += z * zo.ch;
    }

    const int tid  = threadIdx.x;
    const int lane = tid & 63;
    const int w    = tid >> 6;
    const int wr   = w / WC, wc = w % WC;
    const int by = blockIdx.y;
    const int m0 = by * BM;
    const int n0 = blockIdx.x * BN;
    const int lr = lane & 15, lq = lane >> 4;

    // staging source pointers (source chunk pre-swizzled; LDS dest linear)
    const u16* gA[AT]; int loA[AT];
    #pragma unroll
    for (int t = 0; t < AT; ++t) {
        int c = t * 256 + tid; int row = c >> 2; int part = c & 3;
        int pg = part ^ ((row >> 1) & 3);
        gA[t] = A + (size_t)(m0 + row) * KK + pg * 8;
        loA[t] = c * 8;
    }
    const u16* gB[BT]; int loB[BT];
    #pragma unroll
    for (int t = 0; t < BT; ++t) {
        int c = t * 256 + tid; int row = c >> 2; int part = c & 3;
        int pg = part ^ ((row >> 1) & 3);
        gB[t] = Wt + (size_t)(n0 + row) * ldw + pg * 8;
        loB[t] = c * 8;
    }

    // accumulator (residual+bias init for LN epilogues; WR==1 there)
    f4v acc[MI][4];
    if constexpr (EPI == 7 || EPI == 9) {
        const u16* r16 = (const u16*)resid + (EPI == 7 ? (long)z * zo.r : 0);
        #pragma unroll
        for (int j = 0; j < 4; ++j) {
            int n = wc * 64 + j * 16 + lr;
            float bj = bias[n];
            #pragma unroll
            for (int i = 0; i < MI; ++i)
                #pragma unroll
                for (int r = 0; r < 4; ++r) {
                    int m = m0 + i * 16 + lq * 4 + r;
                    acc[i][j][r] = bf2f(r16[(size_t)m * 256 + n]) + bj;
                }
        }
    } else {
        #pragma unroll
        for (int i = 0; i < MI; ++i)
            #pragma unroll
            for (int j = 0; j < 4; ++j)
                acc[i][j] = (f4v){0.f, 0.f, 0.f, 0.f};
    }

    auto stageG = [&](int s, int buf) {
        int k0 = s * 32;
        #pragma unroll
        for (int t = 0; t < AT; ++t)
            ASYNC16(gA[t] + k0, (u16*)As + buf * (BM * 32) + loA[t]);
        #pragma unroll
        for (int t = 0; t < BT; ++t)
            ASYNC16(gB[t] + k0, (u16*)Bs + buf * (BN * 32) + loB[t]);
    };
    auto computeStep = [&](int s) {
        const u16* Ab = As + (s & 1) * (BM * 32);
        const u16* Bb = Bs + (s & 1) * (BN * 32);
        bf8v af[MI], bv[4];
        #pragma unroll
        for (int i = 0; i < MI; ++i) {
            int row = wr * MROWS + i * 16 + lr;
            af[i] = *(const bf8v*)&Ab[row * 32 + ((lq ^ ((row >> 1) & 3)) << 3)];
        }
        #pragma unroll
        for (int j = 0; j < 4; ++j) {
            int row = wc * 64 + j * 16 + lr;
            bv[j] = *(const bf8v*)&Bb[row * 32 + ((lq ^ ((row >> 1) & 3)) << 3)];
        }
        #pragma unroll
        for (int i = 0; i < MI; ++i)
            #pragma unroll
            for (int j = 0; j < 4; ++j)
                acc[i][j] = __builtin_amdgcn_mfma_f32_16x16x32_bf16(af[i], bv[j], acc[i][j], 0, 0, 0);
    };

    stageG(0, 0);
    __syncthreads();
    for (int s = 0; s < NSTEPS - 1; ++s) {
        stageG(s + 1, (s + 1) & 1);
        computeStep(s);
        __syncthreads();
    }
    computeStep(NSTEPS - 1);

    // -------------------- epilogue --------------------
    if constexpr (EPI == 7 || EPI == 9) {
        float g4[4], b4[4];
        #pragma unroll
        for (int j = 0; j < 4; ++j) {
            int n = wc * 64 + j * 16 + lr;
            g4[j] = p0[n]; b4[j] = p1[n];
        }
        #pragma unroll
        for (int i = 0; i < MI; ++i)
            #pragma unroll
            for (int r = 0; r < 4; ++r) {
                float p = 0.f, p2 = 0.f;
                #pragma unroll
                for (int j = 0; j < 4; ++j) { float v = acc[i][j][r]; p += v; p2 += v * v; }
                p += __shfl_xor(p, 1, 16);  p2 += __shfl_xor(p2, 1, 16);
                p += __shfl_xor(p, 2, 16);  p2 += __shfl_xor(p2, 2, 16);
                p += __shfl_xor(p, 4, 16);  p2 += __shfl_xor(p2, 4, 16);
                p += __shfl_xor(p, 8, 16);  p2 += __shfl_xor(p2, 8, 16);
                if (lr == 0) {
                    int row = i * 16 + lq * 4 + r;
                    red[w][row][0] = p; red[w][row][1] = p2;
                }
            }
        __syncthreads();
        #pragma unroll
        for (int i = 0; i < MI; ++i) {
            float mean4[4], rstd4[4];
            #pragma unroll
            for (int r = 0; r < 4; ++r) {
                int row = i * 16 + lq * 4 + r;
                float s  = red[0][row][0] + red[1][row][0] + red[2][row][0] + red[3][row][0];
                float s2 = red[0][row][1] + red[1][row][1] + red[2][row][1] + red[3][row][1];
                float mean = s * (1.f / 256.f);
                float var  = s2 * (1.f / 256.f) - mean * mean;
                mean4[r] = mean;
                rstd4[r] = rsqrtf(var + 1e-5f);
            }
            if constexpr (EPI == 7) {
                #pragma unroll
                for (int r = 0; r < 4; ++r) {
                    int m = m0 + i * 16 + lq * 4 + r;
                    int b = m >> 14, sp = m & (NNn - 1);
                    size_t pb = (((size_t)b * PADW + (sp >> 7) + 1) * PADW + (sp & 127) + 1) * 512 + choff;
                    #pragma unroll
                    for (int j = 0; j < 4; ++j) {
                        int n = wc * 64 + j * 16 + lr;
                        outb[pb + n] = f2bf((acc[i][j][r] - mean4[r]) * rstd4[r] * g4[j] + b4[j]);
                    }
                }
            } else {
                // transposed write to (B,C,N) + cam residual (outf2 = cam_bev)
                int mb = m0 + i * 16 + lq * 4;
                int b = mb >> 14, sp = mb & (NNn - 1);
                #pragma unroll
                for (int j = 0; j < 4; ++j) {
                    int n = wc * 64 + j * 16 + lr;
                    size_t oi = ((size_t)b * 256 + n) * NNn + sp;
                    float4 cv = *(const float4*)&outf2[oi];
                    float4 o;
                    o.x = (acc[i][j][0] - mean4[0]) * rstd4[0] * g4[j] + b4[j] + cv.x;
                    o.y = (acc[i][j][1] - mean4[1]) * rstd4[1] * g4[j] + b4[j] + cv.y;
                    o.z = (acc[i][j][2] - mean4[2]) * rstd4[2] * g4[j] + b4[j] + cv.z;
                    o.w = (acc[i][j][3] - mean4[3]) * rstd4[3] * g4[j] + b4[j] + cv.w;
                    *(float4*)&outf[oi] = o;
                }
            }
        }
        return;
    }

    float bj[4]; int ncol[4];
    #pragma unroll
    for (int j = 0; j < 4; ++j) {
        int n = n0 + wc * 64 + j * 16 + lr;
        ncol[j] = n;
        if constexpr (EPI == 0 || EPI == 4 || EPI == 5) bj[j] = bias[n];
    }
    #pragma unroll
    for (int i = 0; i < MI; ++i) {
        #pragma unroll
        for (int r = 0; r < 4; ++r) {
            int m = m0 + wr * MROWS + i * 16 + lq * 4 + r;
            size_t pb = 0;
            if constexpr (EPI == 4) {
                int b = m >> 14, sp = m & (NNn - 1);
                pb = (((size_t)b * PADW + (sp >> 7) + 1) * PADW + (sp & 127) + 1) * 512;
            }
            #pragma unroll
            for (int j = 0; j < 4; ++j) {
                int n = ncol[j];
                float v = acc[i][j][r];
                size_t oi = (size_t)m * Nc + n;
                if constexpr (EPI == 0) {
                    outb[oi] = f2bf(v + bj[j]);
                } else if constexpr (EPI == 2) {
                    if (n < 64)      outf [(size_t)m * 64 + n]        = v + p0[n];
                    else if (n < 96) outf2[(size_t)m * 32 + (n - 64)] = v + p1[n - 64];
                } else if constexpr (EPI == 4) {
                    float vv = v + bj[j];
                    float g = 1.f / (1.f + __expf(-vv));
                    float f = g * bf2f(img[pb + n]) + (1.f - g) * bf2f(img[pb + 256 + n]);
                    outb[oi] = f2bf(f);
                } else if constexpr (EPI == 5) {
                    outb[oi] = f2bf(fmaxf(v + bj[j], 0.f));
                }
            }
        }
    }
}

// ---------------------------------------------------------------------------
// dedicated conv kernel: 128x128 tile, BK=32, double-buffered stage-ahead,
// both-sides XOR swizzle (chunk ^= (row>>1)&3). grid (1, 256, 3): z = taps.
// ---------------------------------------------------------------------------
template<int TAPS>
__global__ __launch_bounds__(256)
void conv_k(const u16* __restrict__ img, const u16* __restrict__ Wt,
            float* __restrict__ outp)
{
    constexpr int NS = TAPS * 16;
    __shared__ __align__(16) u16 As[2 * 128 * 32];
    __shared__ __align__(16) u16 Bs[2 * 128 * 32];

    const int z = blockIdx.z;
    outp += (size_t)z * MTOT * 128;
    const int tid = threadIdx.x;
    const int lane = tid & 63;
    const int w = tid >> 6;
    const int wr = w >> 1, wc = w & 1;
    int by = blockIdx.y;
    by = ((by & 7) << 5) | (by >> 3);       // XCD swizzle (256 = 8*32)
    const int m0 = by * 128;
    const int lr = lane & 15, lq = lane >> 4;

    // staging: 2 chunks/thread each; c = t*256+tid, row=c>>2, part=c&3
    const u16* abase[2]; const u16* bbase[2]; int ldsOff[2];
    #pragma unroll
    for (int t = 0; t < 2; ++t) {
        int c = t * 256 + tid;
        int row = c >> 2, part = c & 3;
        int pg = part ^ ((row >> 1) & 3);
        ldsOff[t] = c * 8;
        int m = m0 + row; int b = m >> 14; int sp = m & (NNn - 1);
        long cb = ((long)b * PADW + (sp >> 7)) * PADW + (sp & 127);
        abase[t] = img + cb * 512 + pg * 8;
        bbase[t] = Wt + (size_t)row * 4608 + pg * 8;
    }

    long adel[TAPS]; int bdel[TAPS];
    #pragma unroll
    for (int tt = 0; tt < TAPS; ++tt) {
        int tap = z * TAPS + tt;
        int dy = tap / 3, dx = tap - dy * 3;
        adel[tt] = (long)(dy * PADW + dx) * 512;
        bdel[tt] = tap * 512;
    }

    f4v acc[4][4];
    #pragma unroll
    for (int i = 0; i < 4; ++i)
        #pragma unroll
        for (int j = 0; j < 4; ++j)
            acc[i][j] = (f4v){0.f, 0.f, 0.f, 0.f};

    auto stage = [&](int s, int buf) {
        int tt = s >> 4;
        int ci = (s & 15) * 32;
        #pragma unroll
        for (int t = 0; t < 2; ++t) {
            ASYNC16(abase[t] + adel[tt] + ci, (u16*)As + buf * (128 * 32) + ldsOff[t]);
            ASYNC16(bbase[t] + bdel[tt] + ci, (u16*)Bs + buf * (128 * 32) + ldsOff[t]);
        }
    };
    auto computeStep = [&](int s) {
        const u16* Ab = As + (s & 1) * (128 * 32);
        const u16* Bb = Bs + (s & 1) * (128 * 32);
        bf8v af[4], bv[4];
        #pragma unroll
        for (int i = 0; i < 4; ++i) {
            int row = wr * 64 + i * 16 + lr;
            af[i] = *(const bf8v*)&Ab[row * 32 + ((lq ^ ((row >> 1) & 3)) << 3)];
        }
        #pragma unroll
        for (int j = 0; j < 4; ++j) {
            int row = wc * 64 + j * 16 + lr;
            bv[j] = *(const bf8v*)&Bb[row * 32 + ((lq ^ ((row >> 1) & 3)) << 3)];
        }
        #pragma unroll
        for (int i = 0; i < 4; ++i)
            #pragma unroll
            for (int j = 0; j < 4; ++j)
                acc[i][j] = __builtin_amdgcn_mfma_f32_16x16x32_bf16(af[i], bv[j], acc[i][j], 0, 0, 0);
    };

    stage(0, 0);
    __syncthreads();
    #pragma unroll
    for (int s = 0; s < NS - 1; ++s) {
        stage(s + 1, (s + 1) & 1);
        computeStep(s);
        __syncthreads();
    }
    computeStep(NS - 1);

    #pragma unroll
    for (int i = 0; i < 4; ++i)
        #pragma unroll
        for (int r = 0; r < 4; ++r) {
            int m = m0 + wr * 64 + i * 16 + lq * 4 + r;
            #pragma unroll
            for (int j = 0; j < 4; ++j) {
                int n = wc * 64 + j * 16 + lr;
                outp[(size_t)m * 128 + n] = acc[i][j][r];
            }
        }
}

// ---------------------------------------------------------------------------
// split-K combine (3 partials) + BN + ReLU -> bf16
// ---------------------------------------------------------------------------
__global__ __launch_bounds__(256)
void combine_k(const float* __restrict__ part, const float* __restrict__ bng,
               const float* __restrict__ bnb, u16* __restrict__ hb)
{
    const float bnscale = rsqrtf(1.0f + 1e-5f);
    int i = (blockIdx.x * 256 + threadIdx.x) * 4;   // over MTOT*128
    int n = i & 127;
    float4 a = *(const float4*)&part[i];
    float4 b = *(const float4*)&part[(size_t)MTOT * 128 + i];
    float4 c = *(const float4*)&part[(size_t)MTOT * 256 + i];
    ushort4 o;
    o.x = f2bf(fmaxf((a.x + b.x + c.x) * bnscale * bng[n + 0] + bnb[n + 0], 0.f));
    o.y = f2bf(fmaxf((a.y + b.y + c.y) * bnscale * bng[n + 1] + bnb[n + 1], 0.f));
    o.z = f2bf(fmaxf((a.z + b.z + c.z) * bnscale * bng[n + 2] + bnb[n + 2], 0.f));
    o.w = f2bf(fmaxf((a.w + b.w + c.w) * bnscale * bng[n + 3] + bnb[n + 3], 0.f));
    *(ushort4*)&hb[i] = o;
}

// ---------------------------------------------------------------------------
// bev (B,C,N) f32 -> (B*N, C) bf16 ; z: 0-1 cam batches, 2-3 sat batches
// ---------------------------------------------------------------------------
__global__ __launch_bounds__(256)
void tcvt_k(const float* __restrict__ cam, const float* __restrict__ sat,
            u16* __restrict__ qcam, u16* __restrict__ qsat)
{
    __shared__ float t[64][65];
    int z = blockIdx.z;
    const float* src = (z < 2) ? cam : sat;
    u16* dst = (z < 2) ? qcam : qsat;
    int b = z & 1;
    int c0 = blockIdx.x * 64, sp0 = blockIdx.y * 64;
    #pragma unroll
    for (int it = 0; it < 16; ++it) {
        int idx = it * 256 + threadIdx.x;
        int cl = idx >> 6, sl = idx & 63;
        t[cl][sl] = src[((size_t)(b * CCn + c0 + cl)) * NNn + sp0 + sl];
    }
    __syncthreads();
    #pragma unroll
    for (int it = 0; it < 16; ++it) {
        int idx = it * 256 + threadIdx.x;
        int sl = idx >> 6, cl = idx & 63;
        dst[((size_t)(b * NNn + sp0 + sl)) * CCn + c0 + cl] = f2bf(t[cl][sl]);
    }
}

// ---------------------------------------------------------------------------
// deformable sampling, two-phase (descriptors in LDS, coalesced gathers).
// ---------------------------------------------------------------------------
__global__ __launch_bounds__(256)
void sample_k(const u16* __restrict__ val, const float* __restrict__ off,
              const float* __restrict__ lg, u16* __restrict__ outp)
{
    __shared__ uint2 desc[32][17];     // padded stride: avoid fixed-k bank camp

    int z = blockIdx.z;
    val  += (size_t)z * MTOT * CCn;
    off  += (size_t)z * MTOT * 64;
    lg   += (size_t)z * MTOT * 32;
    outp += (size_t)z * MTOT * CCn;

    const int tid = threadIdx.x;
    const int rh0 = blockIdx.x * 32;           // first row-head of block

    if (tid < 32) {
        int rhg = rh0 + tid;
        int h = rhg & 7, rn = rhg >> 3;
        int n = rn & (NNn - 1), b = rn >> 14;
        int yp = n >> 7, xp = n & 127;

        const float* ofp = off + (size_t)rn * 64 + h * 8;
        const float* lgp = lg  + (size_t)rn * 32 + h * 4;
        float4 of0 = *(const float4*)ofp;
        float4 of1 = *(const float4*)(ofp + 4);
        float4 lgv = *(const float4*)lgp;
        float ofx[4] = { of0.x, of0.z, of1.x, of1.z };
        float ofy[4] = { of0.y, of0.w, of1.y, of1.w };

        float mx = fmaxf(fmaxf(lgv.x, lgv.y), fmaxf(lgv.z, lgv.w));
        float e0 = __expf(lgv.x - mx), e1 = __expf(lgv.y - mx);
        float e2 = __expf(lgv.z - mx), e3 = __expf(lgv.w - mx);
        float inv = 1.f / (e0 + e1 + e2 + e3);
        float aw[4] = { e0 * inv, e1 * inv, e2 * inv, e3 * inv };

        unsigned hb = (unsigned)(b * NNn) * 256u + h * 32;
        #pragma unroll
        for (int p = 0; p < 4; ++p) {
            float xs = (float)xp + ofx[p];
            float ys = (float)yp + ofy[p];
            float x0f = floorf(xs), y0f = floorf(ys);
            float lx = xs - x0f, ly = ys - y0f;
            int x0 = (int)x0f, y0 = (int)y0f;
            #pragma unroll
            for (int c = 0; c < 4; ++c) {
                int xi = x0 + (c & 1), yi = y0 + (c >> 1);
                bool valid = (xi >= 0) & (xi < WWn) & (yi >= 0) & (yi < HHn);
                float wgt = valid
                    ? aw[p] * ((c & 1) ? lx : 1.f - lx) * ((c >> 1) ? ly : 1.f - ly)
                    : 0.f;
                int xc = min(max(xi, 0), WWn - 1);
                int yc = min(max(yi, 0), HHn - 1);
                unsigned addr = hb + (unsigned)(yc * WWn + xc) * 256u;
                desc[tid][p * 4 + c] = make_uint2(addr, __float_as_uint(wgt));
            }
        }
    }
    __syncthreads();

    const int rh = tid >> 3;                   // 0..31
    const int q  = tid & 7;                    // channel quad
    const int rhg = rh0 + rh;
    const int h = rhg & 7, rn = rhg >> 3;

    float a0 = 0.f, a1 = 0.f, a2 = 0.f, a3 = 0.f;
    #pragma unroll
    for (int k = 0; k < 16; ++k) {
        uint2 d = desc[rh][k];
        float wgt = __uint_as_float(d.y);
        ushort4 v = *(const ushort4*)(val + d.x + q * 4);
        a0 += wgt * bf2f(v.x);
        a1 += wgt * bf2f(v.y);
        a2 += wgt * bf2f(v.z);
        a3 += wgt * bf2f(v.w);
    }
    ushort4 o;
    o.x = f2bf(a0); o.y = f2bf(a1); o.z = f2bf(a2); o.w = f2bf(a3);
    *(ushort4*)(outp + (size_t)rn * CCn + h * 32 + q * 4) = o;
}

// ---------------------------------------------------------------------------
// all weight repacks + bias/LN packing in one kernel (layouts in comments of r3)
// ---------------------------------------------------------------------------
__global__ __launch_bounds__(256)
void repack_all(const float* __restrict__ vp1, const float* __restrict__ op1,
                const float* __restrict__ vp2, const float* __restrict__ op2,
                const float* __restrict__ f1w, const float* __restrict__ f2w,
                const float* __restrict__ of1, const float* __restrict__ aw1,
                const float* __restrict__ of2, const float* __restrict__ aw2,
                const float* __restrict__ g1,  const float* __restrict__ g2,
                const float* __restrict__ vpb1, const float* __restrict__ vpb2,
                const float* __restrict__ opb1, const float* __restrict__ opb2,
                const float* __restrict__ ofb1, const float* __restrict__ awb1,
                const float* __restrict__ ofb2, const float* __restrict__ awb2,
                const float* __restrict__ l1g, const float* __restrict__ l1b,
                const float* __restrict__ l2g, const float* __restrict__ l2b,
                u16* __restrict__ wb, float* __restrict__ bb)
{
    int i = blockIdx.x * 256 + threadIdx.x;
    if (i >= 1212416 + 2240) return;
    if (i >= 1212416) {
        int j = i - 1212416;
        float v;
        if      (j < 256)  v = vpb1[j];
        else if (j < 512)  v = vpb2[j - 256];
        else if (j < 768)  v = opb1[j - 512];
        else if (j < 1024) v = opb2[j - 768];
        else if (j < 1088) v = ofb1[j - 1024];
        else if (j < 1120) v = awb1[j - 1088];
        else if (j < 1184) v = ofb2[j - 1120];
        else if (j < 1216) v = awb2[j - 1184];
        else if (j < 1472) v = l1g[j - 1216];
        else if (j < 1728) v = l1b[j - 1472];
        else if (j < 1984) v = l2g[j - 1728];
        else               v = l2b[j - 1984];
        bb[j] = v;
        return;
    }
    float v;
    if (i < 262144) {
        const float* src[4] = { vp1, vp2, op1, op2 };
        int q = i >> 16, j = i & 65535;
        int n = j >> 8, k = j & 255;
        v = src[q][(size_t)k * 256 + n];
    } else if (i < 393216) {
        int j = i - 262144; int n = j >> 8, k = j & 255;      // [512][256]
        v = f1w[(size_t)k * 512 + n];
    } else if (i < 524288) {
        int j = i - 393216; int n = j >> 9, k = j & 511;      // [256][512]
        v = f2w[(size_t)k * 256 + n];
    } else if (i < 589824) {
        int jj = i - 524288; int hh = jj >> 15; int j = jj & 32767;
        int n = j >> 8, k = j & 255;                          // [128][256]
        const float* ofw = hh ? of2 : of1;
        const float* aww = hh ? aw2 : aw1;
        if (n < 64)      v = ofw[(size_t)k * 64 + n];
        else if (n < 96) v = aww[(size_t)k * 32 + (n - 64)];
        else             v = 0.f;
    } else if (i < 1179648) {
        int j = i - 589824; int co = j / 4608, k = j - co * 4608;
        int tap = k >> 9, ci = k & 511;
        v = g1[((size_t)co * 512 + ci) * 9 + tap];
    } else {
        int j = i - 1179648; int n = j >> 7, k = j & 127;     // [256][128]
        v = g2[(size_t)n * 128 + k];
    }
    wb[i] = f2bf(v);
}

// ---------------------------------------------------------------------------
extern "C" void kernel_launch(void* const* d_in, const int* in_sizes, int n_in,
                              void* d_out, int out_size, void* d_ws, size_t ws_size,
                              hipStream_t stream)
{
    const float* cam_bev   = (const float*)d_in[0];
    const float* sat_bev   = (const float*)d_in[1];
    const float* c2s_off_w  = (const float*)d_in[2];
    const float* c2s_off_b  = (const float*)d_in[3];
    const float* c2s_attw_w = (const float*)d_in[4];
    const float* c2s_attw_b = (const float*)d_in[5];
    const float* c2s_vp_w   = (const float*)d_in[6];
    const float* c2s_vp_b   = (const float*)d_in[7];
    const float* c2s_op_w   = (const float*)d_in[8];
    const float* c2s_op_b   = (const float*)d_in[9];
    const float* s2c_off_w  = (const float*)d_in[10];
    const float* s2c_off_b  = (const float*)d_in[11];
    const float* s2c_attw_w = (const float*)d_in[12];
    const float* s2c_attw_b = (const float*)d_in[13];
    const float* s2c_vp_w   = (const float*)d_in[14];
    const float* s2c_vp_b   = (const float*)d_in[15];
    const float* s2c_op_w   = (const float*)d_in[16];
    const float* s2c_op_b   = (const float*)d_in[17];
    const float* ln1_g = (const float*)d_in[18];
    const float* ln1_b = (const float*)d_in[19];
    const float* ln2_g = (const float*)d_in[20];
    const float* ln2_b = (const float*)d_in[21];
    const float* lnf_g = (const float*)d_in[22];
    const float* lnf_b = (const float*)d_in[23];
    const float* ffn1_w = (const float*)d_in[24];
    const float* ffn1_b = (const float*)d_in[25];
    const float* ffn2_w = (const float*)d_in[26];
    const float* ffn2_b = (const float*)d_in[27];
    const float* g1_w  = (const float*)d_in[28];
    const float* bn_g  = (const float*)d_in[29];
    const float* bn_b  = (const float*)d_in[30];
    const float* g2_w  = (const float*)d_in[31];
    const float* g2_b  = (const float*)d_in[32];

    char* base = (char*)d_ws;
    size_t off = 0;
    auto alloc = [&](size_t bytes) -> void* {
        void* p = base + off;
        off += (bytes + 255) & ~(size_t)255;
        return p;
    };

    u16*   qcam   = (u16*)  alloc((size_t)MTOT * CCn * 2 * 2);   // qcam|qsat contiguous
    u16*   qsat   = qcam + (size_t)MTOT * CCn;
    u16*   valb   = (u16*)  alloc((size_t)MTOT * CCn * 2 * 2);   // pair
    u16*   sampb  = (u16*)  alloc((size_t)MTOT * CCn * 2 * 2);   // pair (33.55MB)
    float* offb   = (float*)alloc((size_t)MTOT * 64 * 4 * 2);    // pair (16.78MB)
    float* attwb  = (float*)alloc((size_t)MTOT * 32 * 4 * 2);    // pair
    size_t padBytes = (size_t)BBn * PADW * PADW * 512 * 2;       // 34.6MB
    u16*   pad    = (u16*)  alloc(padBytes);
    u16*   hbuf   = (u16*)  alloc((size_t)MTOT * 128 * 2);
    u16*   wbase  = (u16*)  alloc((size_t)1212416 * 2);
    float* biasbf = (float*)alloc((size_t)2240 * 4);
    // weight slices
    u16* wvp = wbase;                 // pair, stride 65536
    u16* wop = wbase + 131072;        // pair, stride 65536
    u16* wf1 = wbase + 262144;
    u16* wf2 = wbase + 393216;
    u16* woa = wbase + 524288;        // pair, stride 32768
    u16* wcv = wbase + 589824;
    u16* wg2 = wbase + 1179648;
    // aliases (temporally disjoint)
    u16*   fused_bf = valb;              // valb dead after sampling
    float* convpart = (float*)sampb;     // sampb+offb dead after op-pair: 3x MTOT*128 f32 = 50.3MB
    u16*   midb     = qcam;              // qcam/qsat dead after op-pair (MTOT*512 bf16)

    dim3 blk(256);
    ZOff zz{0, 0, 0, 0, 0, 0, 0, 0, 0};

    hipMemsetAsync(pad, 0, padBytes, stream);
    tcvt_k<<<dim3(4, 256, 4), blk, 0, stream>>>(cam_bev, sat_bev, qcam, qsat);
    repack_all<<<4746, blk, 0, stream>>>(c2s_vp_w, c2s_op_w, s2c_vp_w, s2c_op_w,
                                         ffn1_w, ffn2_w, c2s_off_w, c2s_attw_w,
                                         s2c_off_w, s2c_attw_w, g1_w, g2_w,
                                         c2s_vp_b, s2c_vp_b, c2s_op_b, s2c_op_b,
                                         c2s_off_b, c2s_attw_b, s2c_off_b, s2c_attw_b,
                                         ln1_g, ln1_b, ln2_g, ln2_b,
                                         wbase, biasbf);

    // ---------- value projections (z=0: kv=sat, z=1: kv=cam) ----------
    {
        ZOff zo{ -(long)MTOT * CCn, 65536, 256, 0, 0, (long)MTOT * CCn, 0, 0, 0 };
        mgemm<128, 128, 2, 0, 256><<<dim3(2, 256, 2), blk, 0, stream>>>(
            qsat, wvp, biasbf, 256, 256,
            nullptr, nullptr, valb, nullptr, nullptr, nullptr, nullptr, 0, zo);
    }
    // ---------- offset+attw projections (z=0: q=cam, z=1: q=sat) ----------
    {
        ZOff zo{ (long)MTOT * CCn, 32768, 0, (long)MTOT * 64, (long)MTOT * 32, 0, 0, 96, 0 };
        mgemm<128, 128, 2, 2, 256><<<dim3(1, 256, 2), blk, 0, stream>>>(
            qcam, woa, nullptr, 256, 128,
            offb, attwb, nullptr, nullptr, nullptr, biasbf + 1024, biasbf + 1088, 0, zo);
    }
    // ---------- deformable sampling (both streams, 2-phase, block = 32 rh) ----
    sample_k<<<dim3(8192, 1, 2), blk, 0, stream>>>(valb, offb, attwb, sampb);
    // ---------- output projections + residual + LN -> pad image ----------
    {
        ZOff zo{ (long)MTOT * CCn, 65536, 256, 0, 0, 0, (long)MTOT * CCn, 512, 256 };
        mgemm<64, 256, 4, 7, 256><<<dim3(1, 512, 2), blk, 0, stream>>>(
            sampb, wop, biasbf + 512, 256, 256,
            nullptr, nullptr, pad, nullptr, qcam, biasbf + 1216, biasbf + 1472, 0, zo);
    }
    // ---------- gating conv: implicit GEMM, dbuf BK=32, split-K=3 ----------
    conv_k<3><<<dim3(1, 256, 3), blk, 0, stream>>>(pad, wcv, convpart);
    combine_k<<<4096, blk, 0, stream>>>(convpart, bn_g, bn_b, hbuf);

    // ---------- 1x1 conv + sigmoid + gated fusion (bf16 out only) ----------
    mgemm<128, 128, 2, 4, 128><<<dim3(2, 256, 1), blk, 0, stream>>>(
        hbuf, wg2, g2_b, 128, 256,
        nullptr, nullptr, fused_bf, pad, nullptr, nullptr, nullptr, 0, zz);

    // ---------- FFN ----------
    mgemm<128, 128, 2, 5, 256><<<dim3(4, 256, 1), blk, 0, stream>>>(
        fused_bf, wf1, ffn1_b, 256, 512,
        nullptr, nullptr, midb, nullptr, nullptr, nullptr, nullptr, 0, zz);
    // ffn2 + final LN + transpose to (B,C,N) + cam residual (EPI 9, bf16 resid)
    mgemm<64, 256, 4, 9, 512><<<dim3(1, 512, 1), blk, 0, stream>>>(
        midb, wf2, ffn2_b, 512, 256,
        (float*)d_out, (float*)cam_bev, nullptr, nullptr, fused_bf, lnf_g, lnf_b, 0, zz);
}

// Round 12
// 296.646 us; speedup vs baseline: 5.8659x; 1.0069x over previous
//
#include <hip/hip_runtime.h>
#include <hip/hip_bf16.h>
#include <cstddef>

#define BBn  2
#define CCn  256
#define HHn  128
#define WWn  128
#define NNn  (HHn*WWn)        // 16384
#define MTOT (BBn*NNn)        // 32768
#define PADW 130

typedef unsigned short u16;
typedef __attribute__((ext_vector_type(8))) short bf8v;
typedef __attribute__((ext_vector_type(8))) unsigned short u16x8;
typedef __attribute__((ext_vector_type(4))) float f4v;

typedef __attribute__((address_space(1))) const void gvoid_t;
typedef __attribute__((address_space(3))) void svoid_t;
#define ASYNC16(g, l) __builtin_amdgcn_global_load_lds((gvoid_t*)(g), (svoid_t*)(l), 16, 0, 0)

__device__ __forceinline__ u16 f2bf(float f) {
    __hip_bfloat16 h = __float2bfloat16(f);
    return *reinterpret_cast<u16*>(&h);
}
__device__ __forceinline__ float bf2f(u16 h) {
    return __uint_as_float(((unsigned)h) << 16);
}

// z-offsets (elements), applied scaled by blockIdx.z
struct ZOff {
    long a, w, bia, f1, f2, b1, r, p;
    int ch;
};

// ---------------------------------------------------------------------------
// bf16 MFMA GEMM, tile BM x BN, BK=32, double-buffered LDS (stage-ahead),
// both-sides XOR swizzle: chunk' = chunk ^ ((row>>1)&3).
// A[M,KK] bf16 row-major. Wt[Nc,ldw] bf16 pre-transposed.
// EPI: 0 bf16+bias | 2 off/attw split | 4 sigmoid-gate (bf16 out)
//      5 ReLU->bf16
//      7 resid(bf16)-init + rowLN -> pad bf16 | 9 resid(bf16)-init + rowLN -> (B,C,N) + cam
// ---------------------------------------------------------------------------
template<int BM, int BN, int WC, int EPI, int KK>
__global__ __launch_bounds__(256)
void mgemm(const u16* __restrict__ A, const u16* __restrict__ Wt,
           const float* __restrict__ bias, int ldw, int Nc,
           float* __restrict__ outf, float* __restrict__ outf2,
           u16* __restrict__ outb, const u16* __restrict__ img,
           const void* __restrict__ resid,
           const float* __restrict__ p0, const float* __restrict__ p1,
           int choff, ZOff zo)
{
    constexpr int WR = 4 / WC;
    constexpr int MROWS = BM / WR;       // rows per wave
    constexpr int MI = MROWS / 16;
    constexpr int AT = BM / 64;          // A staging chunks per thread
    constexpr int BT = BN / 64;
    constexpr int NSTEPS = KK / 32;

    __shared__ __align__(16) u16 As[2 * BM * 32];
    __shared__ __align__(16) u16 Bs[2 * BN * 32];
    __shared__ float red[4][64][2];      // LN cross-wave partials (EPI 7/9)

    const int z = blockIdx.z;
    if (z) {
        A += (long)z * zo.a; Wt += (long)z * zo.w;
        if (bias)  bias  += (long)z * zo.bia;
        if (outf)  outf  += (long)z * zo.f1;
        if (outf2) outf2 += (long)z * zo.f2;
        if (outb)  outb  += (long)z * zo.b1;
        if (p0)    p0    += (long)z * zo.p;
        if (p1)    p1    += (long)z * zo.p;
        choff += z * zo.ch;
    }

    const int tid  = threadIdx.x;
    const int lane = tid & 63;
    const int w    = tid >> 6;
    const int wr   = w / WC, wc = w % WC;
    const int by = blockIdx.y;
    const int m0 = by * BM;
    const int n0 = blockIdx.x * BN;
    const int lr = lane & 15, lq = lane >> 4;

    // staging source pointers (source chunk pre-swizzled; LDS dest linear)
    const u16* gA[AT]; int loA[AT];
    #pragma unroll
    for (int t = 0; t < AT; ++t) {
        int c = t * 256 + tid; int row = c >> 2; int part = c & 3;
        int pg = part ^ ((row >> 1) & 3);
        gA[t] = A + (size_t)(m0 + row) * KK + pg * 8;
        loA[t] = c * 8;
    }
    const u16* gB[BT]; int loB[BT];
    #pragma unroll
    for (int t = 0; t < BT; ++t) {
        int c = t * 256 + tid; int row = c >> 2; int part = c & 3;
        int pg = part ^ ((row >> 1) & 3);
        gB[t] = Wt + (size_t)(n0 + row) * ldw + pg * 8;
        loB[t] = c * 8;
    }

    // accumulator (residual+bias init for LN epilogues; WR==1 there)
    f4v acc[MI][4];
    if constexpr (EPI == 7 || EPI == 9) {
        const u16* r16 = (const u16*)resid + (EPI == 7 ? (long)z * zo.r : 0);
        #pragma unroll
        for (int j = 0; j < 4; ++j) {
            int n = wc * 64 + j * 16 + lr;
            float bj = bias[n];
            #pragma unroll
            for (int i = 0; i < MI; ++i)
                #pragma unroll
                for (int r = 0; r < 4; ++r) {
                    int m = m0 + i * 16 + lq * 4 + r;
                    acc[i][j][r] = bf2f(r16[(size_t)m * 256 + n]) + bj;
                }
        }
    } else {
        #pragma unroll
        for (int i = 0; i < MI; ++i)
            #pragma unroll
            for (int j = 0; j < 4; ++j)
                acc[i][j] = (f4v){0.f, 0.f, 0.f, 0.f};
    }

    auto stageG = [&](int s, int buf) {
        int k0 = s * 32;
        #pragma unroll
        for (int t = 0; t < AT; ++t)
            ASYNC16(gA[t] + k0, (u16*)As + buf * (BM * 32) + loA[t]);
        #pragma unroll
        for (int t = 0; t < BT; ++t)
            ASYNC16(gB[t] + k0, (u16*)Bs + buf * (BN * 32) + loB[t]);
    };
    auto computeStep = [&](int s) {
        const u16* Ab = As + (s & 1) * (BM * 32);
        const u16* Bb = Bs + (s & 1) * (BN * 32);
        bf8v af[MI], bv[4];
        #pragma unroll
        for (int i = 0; i < MI; ++i) {
            int row = wr * MROWS + i * 16 + lr;
            af[i] = *(const bf8v*)&Ab[row * 32 + ((lq ^ ((row >> 1) & 3)) << 3)];
        }
        #pragma unroll
        for (int j = 0; j < 4; ++j) {
            int row = wc * 64 + j * 16 + lr;
            bv[j] = *(const bf8v*)&Bb[row * 32 + ((lq ^ ((row >> 1) & 3)) << 3)];
        }
        #pragma unroll
        for (int i = 0; i < MI; ++i)
            #pragma unroll
            for (int j = 0; j < 4; ++j)
                acc[i][j] = __builtin_amdgcn_mfma_f32_16x16x32_bf16(af[i], bv[j], acc[i][j], 0, 0, 0);
    };

    stageG(0, 0);
    __syncthreads();
    for (int s = 0; s < NSTEPS - 1; ++s) {
        stageG(s + 1, (s + 1) & 1);
        computeStep(s);
        __syncthreads();
    }
    computeStep(NSTEPS - 1);

    // -------------------- epilogue --------------------
    if constexpr (EPI == 7 || EPI == 9) {
        float g4[4], b4[4];
        #pragma unroll
        for (int j = 0; j < 4; ++j) {
            int n = wc * 64 + j * 16 + lr;
            g4[j] = p0[n]; b4[j] = p1[n];
        }
        #pragma unroll
        for (int i = 0; i < MI; ++i)
            #pragma unroll
            for (int r = 0; r < 4; ++r) {
                float p = 0.f, p2 = 0.f;
                #pragma unroll
                for (int j = 0; j < 4; ++j) { float v = acc[i][j][r]; p += v; p2 += v * v; }
                p += __shfl_xor(p, 1, 16);  p2 += __shfl_xor(p2, 1, 16);
                p += __shfl_xor(p, 2, 16);  p2 += __shfl_xor(p2, 2, 16);
                p += __shfl_xor(p, 4, 16);  p2 += __shfl_xor(p2, 4, 16);
                p += __shfl_xor(p, 8, 16);  p2 += __shfl_xor(p2, 8, 16);
                if (lr == 0) {
                    int row = i * 16 + lq * 4 + r;
                    red[w][row][0] = p; red[w][row][1] = p2;
                }
            }
        __syncthreads();
        #pragma unroll
        for (int i = 0; i < MI; ++i) {
            float mean4[4], rstd4[4];
            #pragma unroll
            for (int r = 0; r < 4; ++r) {
                int row = i * 16 + lq * 4 + r;
                float s  = red[0][row][0] + red[1][row][0] + red[2][row][0] + red[3][row][0];
                float s2 = red[0][row][1] + red[1][row][1] + red[2][row][1] + red[3][row][1];
                float mean = s * (1.f / 256.f);
                float var  = s2 * (1.f / 256.f) - mean * mean;
                mean4[r] = mean;
                rstd4[r] = rsqrtf(var + 1e-5f);
            }
            if constexpr (EPI == 7) {
                #pragma unroll
                for (int r = 0; r < 4; ++r) {
                    int m = m0 + i * 16 + lq * 4 + r;
                    int b = m >> 14, sp = m & (NNn - 1);
                    size_t pb = (((size_t)b * PADW + (sp >> 7) + 1) * PADW + (sp & 127) + 1) * 512 + choff;
                    #pragma unroll
                    for (int j = 0; j < 4; ++j) {
                        int n = wc * 64 + j * 16 + lr;
                        outb[pb + n] = f2bf((acc[i][j][r] - mean4[r]) * rstd4[r] * g4[j] + b4[j]);
                    }
                }
            } else {
                // transposed write to (B,C,N) + cam residual (outf2 = cam_bev)
                int mb = m0 + i * 16 + lq * 4;
                int b = mb >> 14, sp = mb & (NNn - 1);
                #pragma unroll
                for (int j = 0; j < 4; ++j) {
                    int n = wc * 64 + j * 16 + lr;
                    size_t oi = ((size_t)b * 256 + n) * NNn + sp;
                    float4 cv = *(const float4*)&outf2[oi];
                    float4 o;
                    o.x = (acc[i][j][0] - mean4[0]) * rstd4[0] * g4[j] + b4[j] + cv.x;
                    o.y = (acc[i][j][1] - mean4[1]) * rstd4[1] * g4[j] + b4[j] + cv.y;
                    o.z = (acc[i][j][2] - mean4[2]) * rstd4[2] * g4[j] + b4[j] + cv.z;
                    o.w = (acc[i][j][3] - mean4[3]) * rstd4[3] * g4[j] + b4[j] + cv.w;
                    *(float4*)&outf[oi] = o;
                }
            }
        }
        return;
    }

    float bj[4]; int ncol[4];
    #pragma unroll
    for (int j = 0; j < 4; ++j) {
        int n = n0 + wc * 64 + j * 16 + lr;
        ncol[j] = n;
        if constexpr (EPI == 0 || EPI == 4 || EPI == 5) bj[j] = bias[n];
    }
    #pragma unroll
    for (int i = 0; i < MI; ++i) {
        #pragma unroll
        for (int r = 0; r < 4; ++r) {
            int m = m0 + wr * MROWS + i * 16 + lq * 4 + r;
            size_t pb = 0;
            if constexpr (EPI == 4) {
                int b = m >> 14, sp = m & (NNn - 1);
                pb = (((size_t)b * PADW + (sp >> 7) + 1) * PADW + (sp & 127) + 1) * 512;
            }
            #pragma unroll
            for (int j = 0; j < 4; ++j) {
                int n = ncol[j];
                float v = acc[i][j][r];
                size_t oi = (size_t)m * Nc + n;
                if constexpr (EPI == 0) {
                    outb[oi] = f2bf(v + bj[j]);
                } else if constexpr (EPI == 2) {
                    if (n < 64)      outf [(size_t)m * 64 + n]        = v + p0[n];
                    else if (n < 96) outf2[(size_t)m * 32 + (n - 64)] = v + p1[n - 64];
                } else if constexpr (EPI == 4) {
                    float vv = v + bj[j];
                    float g = 1.f / (1.f + __expf(-vv));
                    float f = g * bf2f(img[pb + n]) + (1.f - g) * bf2f(img[pb + 256 + n]);
                    outb[oi] = f2bf(f);
                } else if constexpr (EPI == 5) {
                    outb[oi] = f2bf(fmaxf(v + bj[j], 0.f));
                }
            }
        }
    }
}

// ---------------------------------------------------------------------------
// dedicated conv kernel: 128x128 tile, BK=32, 2-deep counted-vmcnt pipeline
// (raw s_barrier; vmcnt(4) steady state, never a full drain in the loop).
// both-sides XOR swizzle (chunk ^= (row>>1)&3). grid (1, 256, 3): z = taps.
// ---------------------------------------------------------------------------
template<int TAPS>
__global__ __launch_bounds__(256)
void conv_k(const u16* __restrict__ img, const u16* __restrict__ Wt,
            float* __restrict__ outp)
{
    constexpr int NS = TAPS * 16;
    __shared__ __align__(16) u16 As[2 * 128 * 32];
    __shared__ __align__(16) u16 Bs[2 * 128 * 32];

    const int z = blockIdx.z;
    outp += (size_t)z * MTOT * 128;
    const int tid = threadIdx.x;
    const int lane = tid & 63;
    const int w = tid >> 6;
    const int wr = w >> 1, wc = w & 1;
    int by = blockIdx.y;
    by = ((by & 7) << 5) | (by >> 3);       // XCD swizzle (256 = 8*32)
    const int m0 = by * 128;
    const int lr = lane & 15, lq = lane >> 4;

    // staging: 2 chunks/thread each; c = t*256+tid, row=c>>2, part=c&3
    const u16* abase[2]; const u16* bbase[2]; int ldsOff[2];
    #pragma unroll
    for (int t = 0; t < 2; ++t) {
        int c = t * 256 + tid;
        int row = c >> 2, part = c & 3;
        int pg = part ^ ((row >> 1) & 3);
        ldsOff[t] = c * 8;
        int m = m0 + row; int b = m >> 14; int sp = m & (NNn - 1);
        long cb = ((long)b * PADW + (sp >> 7)) * PADW + (sp & 127);
        abase[t] = img + cb * 512 + pg * 8;
        bbase[t] = Wt + (size_t)row * 4608 + pg * 8;
    }

    long adel[TAPS]; int bdel[TAPS];
    #pragma unroll
    for (int tt = 0; tt < TAPS; ++tt) {
        int tap = z * TAPS + tt;
        int dy = tap / 3, dx = tap - dy * 3;
        adel[tt] = (long)(dy * PADW + dx) * 512;
        bdel[tt] = tap * 512;
    }

    f4v acc[4][4];
    #pragma unroll
    for (int i = 0; i < 4; ++i)
        #pragma unroll
        for (int j = 0; j < 4; ++j)
            acc[i][j] = (f4v){0.f, 0.f, 0.f, 0.f};

    auto stage = [&](int s, int buf) {
        int tt = s >> 4;
        int ci = (s & 15) * 32;
        #pragma unroll
        for (int t = 0; t < 2; ++t) {
            ASYNC16(abase[t] + adel[tt] + ci, (u16*)As + buf * (128 * 32) + ldsOff[t]);
            ASYNC16(bbase[t] + bdel[tt] + ci, (u16*)Bs + buf * (128 * 32) + ldsOff[t]);
        }
    };
    auto computeStep = [&](int s) {
        const u16* Ab = As + (s & 1) * (128 * 32);
        const u16* Bb = Bs + (s & 1) * (128 * 32);
        bf8v af[4], bv[4];
        #pragma unroll
        for (int i = 0; i < 4; ++i) {
            int row = wr * 64 + i * 16 + lr;
            af[i] = *(const bf8v*)&Ab[row * 32 + ((lq ^ ((row >> 1) & 3)) << 3)];
        }
        #pragma unroll
        for (int j = 0; j < 4; ++j) {
            int row = wc * 64 + j * 16 + lr;
            bv[j] = *(const bf8v*)&Bb[row * 32 + ((lq ^ ((row >> 1) & 3)) << 3)];
        }
        #pragma unroll
        for (int i = 0; i < 4; ++i)
            #pragma unroll
            for (int j = 0; j < 4; ++j)
                acc[i][j] = __builtin_amdgcn_mfma_f32_16x16x32_bf16(af[i], bv[j], acc[i][j], 0, 0, 0);
    };

    // 2-deep counted-vmcnt pipeline: 4 loads/thread per stage.
    stage(0, 0);
    stage(1, 1);
    asm volatile("s_waitcnt vmcnt(4)" ::: "memory");   // stage(0) landed (mine)
    __builtin_amdgcn_s_barrier();                      // everyone's stage(0) landed
    #pragma unroll 4
    for (int s = 0; s < NS; ++s) {
        computeStep(s);
        asm volatile("s_waitcnt lgkmcnt(0)" ::: "memory");
        __builtin_amdgcn_sched_barrier(0);
        __builtin_amdgcn_s_barrier();                  // all done READING buf s&1
        if (s + 2 < NS) {
            stage(s + 2, s & 1);                       // refill freed buffer
            __builtin_amdgcn_sched_barrier(0);
            asm volatile("s_waitcnt vmcnt(4)" ::: "memory");   // stage(s+1) landed
        } else {
            asm volatile("s_waitcnt vmcnt(0)" ::: "memory");   // tail drain
        }
        __builtin_amdgcn_s_barrier();                  // everyone's next buf ready
    }

    #pragma unroll
    for (int i = 0; i < 4; ++i)
        #pragma unroll
        for (int r = 0; r < 4; ++r) {
            int m = m0 + wr * 64 + i * 16 + lq * 4 + r;
            #pragma unroll
            for (int j = 0; j < 4; ++j) {
                int n = wc * 64 + j * 16 + lr;
                outp[(size_t)m * 128 + n] = acc[i][j][r];
            }
        }
}

// ---------------------------------------------------------------------------
// split-K combine (3 partials) + BN + ReLU -> bf16
// ---------------------------------------------------------------------------
__global__ __launch_bounds__(256)
void combine_k(const float* __restrict__ part, const float* __restrict__ bng,
               const float* __restrict__ bnb, u16* __restrict__ hb)
{
    const float bnscale = rsqrtf(1.0f + 1e-5f);
    int i = (blockIdx.x * 256 + threadIdx.x) * 4;   // over MTOT*128
    int n = i & 127;
    float4 a = *(const float4*)&part[i];
    float4 b = *(const float4*)&part[(size_t)MTOT * 128 + i];
    float4 c = *(const float4*)&part[(size_t)MTOT * 256 + i];
    ushort4 o;
    o.x = f2bf(fmaxf((a.x + b.x + c.x) * bnscale * bng[n + 0] + bnb[n + 0], 0.f));
    o.y = f2bf(fmaxf((a.y + b.y + c.y) * bnscale * bng[n + 1] + bnb[n + 1], 0.f));
    o.z = f2bf(fmaxf((a.z + b.z + c.z) * bnscale * bng[n + 2] + bnb[n + 2], 0.f));
    o.w = f2bf(fmaxf((a.w + b.w + c.w) * bnscale * bng[n + 3] + bnb[n + 3], 0.f));
    *(ushort4*)&hb[i] = o;
}

// ---------------------------------------------------------------------------
// zero only the 1-px border ring of the padded image (interior is fully
// overwritten by the LN epilogues). 528384 elems = 66048 threads x 8.
// ---------------------------------------------------------------------------
__global__ __launch_bounds__(256)
void zring_k(u16* __restrict__ pad)
{
    int i = blockIdx.x * 256 + threadIdx.x;
    if (i >= 66048) return;
    int e = i * 8;
    const int per_b = 264192;
    int b = e / per_b; int r = e - b * per_b;
    long off;
    if (r < 66560)       { int x = r >> 9, c = r & 511;                 off = (((long)b * PADW + 0)   * PADW + x)   * 512 + c; }
    else if (r < 133120) { int r2 = r - 66560;  int x = r2 >> 9, c = r2 & 511; off = (((long)b * PADW + 129) * PADW + x)   * 512 + c; }
    else if (r < 198656) { int r2 = r - 133120; int y = (r2 >> 9) + 1, c = r2 & 511; off = (((long)b * PADW + y)   * PADW + 0)   * 512 + c; }
    else                 { int r2 = r - 198656; int y = (r2 >> 9) + 1, c = r2 & 511; off = (((long)b * PADW + y)   * PADW + 129) * 512 + c; }
    *(u16x8*)(pad + off) = (u16x8){0, 0, 0, 0, 0, 0, 0, 0};
}

// ---------------------------------------------------------------------------
// bev (B,C,N) f32 -> (B*N, C) bf16 ; z: 0-1 cam batches, 2-3 sat batches
// ---------------------------------------------------------------------------
__global__ __launch_bounds__(256)
void tcvt_k(const float* __restrict__ cam, const float* __restrict__ sat,
            u16* __restrict__ qcam, u16* __restrict__ qsat)
{
    __shared__ float t[64][65];
    int z = blockIdx.z;
    const float* src = (z < 2) ? cam : sat;
    u16* dst = (z < 2) ? qcam : qsat;
    int b = z & 1;
    int c0 = blockIdx.x * 64, sp0 = blockIdx.y * 64;
    #pragma unroll
    for (int it = 0; it < 16; ++it) {
        int idx = it * 256 + threadIdx.x;
        int cl = idx >> 6, sl = idx & 63;
        t[cl][sl] = src[((size_t)(b * CCn + c0 + cl)) * NNn + sp0 + sl];
    }
    __syncthreads();
    #pragma unroll
    for (int it = 0; it < 16; ++it) {
        int idx = it * 256 + threadIdx.x;
        int sl = idx >> 6, cl = idx & 63;
        dst[((size_t)(b * NNn + sp0 + sl)) * CCn + c0 + cl] = f2bf(t[cl][sl]);
    }
}

// ---------------------------------------------------------------------------
// deformable sampling, two-phase (descriptors in LDS, coalesced gathers).
// ---------------------------------------------------------------------------
__global__ __launch_bounds__(256)
void sample_k(const u16* __restrict__ val, const float* __restrict__ off,
              const float* __restrict__ lg, u16* __restrict__ outp)
{
    __shared__ uint2 desc[32][17];     // padded stride: avoid fixed-k bank camp

    int z = blockIdx.z;
    val  += (size_t)z * MTOT * CCn;
    off  += (size_t)z * MTOT * 64;
    lg   += (size_t)z * MTOT * 32;
    outp += (size_t)z * MTOT * CCn;

    const int tid = threadIdx.x;
    const int rh0 = blockIdx.x * 32;           // first row-head of block

    if (tid < 32) {
        int rhg = rh0 + tid;
        int h = rhg & 7, rn = rhg >> 3;
        int n = rn & (NNn - 1), b = rn >> 14;
        int yp = n >> 7, xp = n & 127;

        const float* ofp = off + (size_t)rn * 64 + h * 8;
        const float* lgp = lg  + (size_t)rn * 32 + h * 4;
        float4 of0 = *(const float4*)ofp;
        float4 of1 = *(const float4*)(ofp + 4);
        float4 lgv = *(const float4*)lgp;
        float ofx[4] = { of0.x, of0.z, of1.x, of1.z };
        float ofy[4] = { of0.y, of0.w, of1.y, of1.w };

        float mx = fmaxf(fmaxf(lgv.x, lgv.y), fmaxf(lgv.z, lgv.w));
        float e0 = __expf(lgv.x - mx), e1 = __expf(lgv.y - mx);
        float e2 = __expf(lgv.z - mx), e3 = __expf(lgv.w - mx);
        float inv = 1.f / (e0 + e1 + e2 + e3);
        float aw[4] = { e0 * inv, e1 * inv, e2 * inv, e3 * inv };

        unsigned hb = (unsigned)(b * NNn) * 256u + h * 32;
        #pragma unroll
        for (int p = 0; p < 4; ++p) {
            float xs = (float)xp + ofx[p];
            float ys = (float)yp + ofy[p];
            float x0f = floorf(xs), y0f = floorf(ys);
            float lx = xs - x0f, ly = ys - y0f;
            int x0 = (int)x0f, y0 = (int)y0f;
            #pragma unroll
            for (int c = 0; c < 4; ++c) {
                int xi = x0 + (c & 1), yi = y0 + (c >> 1);
                bool valid = (xi >= 0) & (xi < WWn) & (yi >= 0) & (yi < HHn);
                float wgt = valid
                    ? aw[p] * ((c & 1) ? lx : 1.f - lx) * ((c >> 1) ? ly : 1.f - ly)
                    : 0.f;
                int xc = min(max(xi, 0), WWn - 1);
                int yc = min(max(yi, 0), HHn - 1);
                unsigned addr = hb + (unsigned)(yc * WWn + xc) * 256u;
                desc[tid][p * 4 + c] = make_uint2(addr, __float_as_uint(wgt));
            }
        }
    }
    __syncthreads();

    const int rh = tid >> 3;                   // 0..31
    const int q  = tid & 7;                    // channel quad
    const int rhg = rh0 + rh;
    const int h = rhg & 7, rn = rhg >> 3;

    float a0 = 0.f, a1 = 0.f, a2 = 0.f, a3 = 0.f;
    #pragma unroll
    for (int k = 0; k < 16; ++k) {
        uint2 d = desc[rh][k];
        float wgt = __uint_as_float(d.y);
        ushort4 v = *(const ushort4*)(val + d.x + q * 4);
        a0 += wgt * bf2f(v.x);
        a1 += wgt * bf2f(v.y);
        a2 += wgt * bf2f(v.z);
        a3 += wgt * bf2f(v.w);
    }
    ushort4 o;
    o.x = f2bf(a0); o.y = f2bf(a1); o.z = f2bf(a2); o.w = f2bf(a3);
    *(ushort4*)(outp + (size_t)rn * CCn + h * 32 + q * 4) = o;
}

// ---------------------------------------------------------------------------
// all weight repacks + bias/LN packing in one kernel (layouts in comments of r3)
// ---------------------------------------------------------------------------
__global__ __launch_bounds__(256)
void repack_all(const float* __restrict__ vp1, const float* __restrict__ op1,
                const float* __restrict__ vp2, const float* __restrict__ op2,
                const float* __restrict__ f1w, const float* __restrict__ f2w,
                const float* __restrict__ of1, const float* __restrict__ aw1,
                const float* __restrict__ of2, const float* __restrict__ aw2,
                const float* __restrict__ g1,  const float* __restrict__ g2,
                const float* __restrict__ vpb1, const float* __restrict__ vpb2,
                const float* __restrict__ opb1, const float* __restrict__ opb2,
                const float* __restrict__ ofb1, const float* __restrict__ awb1,
                const float* __restrict__ ofb2, const float* __restrict__ awb2,
                const float* __restrict__ l1g, const float* __restrict__ l1b,
                const float* __restrict__ l2g, const float* __restrict__ l2b,
                u16* __restrict__ wb, float* __restrict__ bb)
{
    int i = blockIdx.x * 256 + threadIdx.x;
    if (i >= 1212416 + 2240) return;
    if (i >= 1212416) {
        int j = i - 1212416;
        float v;
        if      (j < 256)  v = vpb1[j];
        else if (j < 512)  v = vpb2[j - 256];
        else if (j < 768)  v = opb1[j - 512];
        else if (j < 1024) v = opb2[j - 768];
        else if (j < 1088) v = ofb1[j - 1024];
        else if (j < 1120) v = awb1[j - 1088];
        else if (j < 1184) v = ofb2[j - 1120];
        else if (j < 1216) v = awb2[j - 1184];
        else if (j < 1472) v = l1g[j - 1216];
        else if (j < 1728) v = l1b[j - 1472];
        else if (j < 1984) v = l2g[j - 1728];
        else               v = l2b[j - 1984];
        bb[j] = v;
        return;
    }
    float v;
    if (i < 262144) {
        const float* src[4] = { vp1, vp2, op1, op2 };
        int q = i >> 16, j = i & 65535;
        int n = j >> 8, k = j & 255;
        v = src[q][(size_t)k * 256 + n];
    } else if (i < 393216) {
        int j = i - 262144; int n = j >> 8, k = j & 255;      // [512][256]
        v = f1w[(size_t)k * 512 + n];
    } else if (i < 524288) {
        int j = i - 393216; int n = j >> 9, k = j & 511;      // [256][512]
        v = f2w[(size_t)k * 256 + n];
    } else if (i < 589824) {
        int jj = i - 524288; int hh = jj >> 15; int j = jj & 32767;
        int n = j >> 8, k = j & 255;                          // [128][256]
        const float* ofw = hh ? of2 : of1;
        const float* aww = hh ? aw2 : aw1;
        if (n < 64)      v = ofw[(size_t)k * 64 + n];
        else if (n < 96) v = aww[(size_t)k * 32 + (n - 64)];
        else             v = 0.f;
    } else if (i < 1179648) {
        int j = i - 589824; int co = j / 4608, k = j - co * 4608;
        int tap = k >> 9, ci = k & 511;
        v = g1[((size_t)co * 512 + ci) * 9 + tap];
    } else {
        int j = i - 1179648; int n = j >> 7, k = j & 127;     // [256][128]
        v = g2[(size_t)n * 128 + k];
    }
    wb[i] = f2bf(v);
}

// ---------------------------------------------------------------------------
extern "C" void kernel_launch(void* const* d_in, const int* in_sizes, int n_in,
                              void* d_out, int out_size, void* d_ws, size_t ws_size,
                              hipStream_t stream)
{
    const float* cam_bev   = (const float*)d_in[0];
    const float* sat_bev   = (const float*)d_in[1];
    const float* c2s_off_w  = (const float*)d_in[2];
    const float* c2s_off_b  = (const float*)d_in[3];
    const float* c2s_attw_w = (const float*)d_in[4];
    const float* c2s_attw_b = (const float*)d_in[5];
    const float* c2s_vp_w   = (const float*)d_in[6];
    const float* c2s_vp_b   = (const float*)d_in[7];
    const float* c2s_op_w   = (const float*)d_in[8];
    const float* c2s_op_b   = (const float*)d_in[9];
    const float* s2c_off_w  = (const float*)d_in[10];
    const float* s2c_off_b  = (const float*)d_in[11];
    const float* s2c_attw_w = (const float*)d_in[12];
    const float* s2c_attw_b = (const float*)d_in[13];
    const float* s2c_vp_w   = (const float*)d_in[14];
    const float* s2c_vp_b   = (const float*)d_in[15];
    const float* s2c_op_w   = (const float*)d_in[16];
    const float* s2c_op_b   = (const float*)d_in[17];
    const float* ln1_g = (const float*)d_in[18];
    const float* ln1_b = (const float*)d_in[19];
    const float* ln2_g = (const float*)d_in[20];
    const float* ln2_b = (const float*)d_in[21];
    const float* lnf_g = (const float*)d_in[22];
    const float* lnf_b = (const float*)d_in[23];
    const float* ffn1_w = (const float*)d_in[24];
    const float* ffn1_b = (const float*)d_in[25];
    const float* ffn2_w = (const float*)d_in[26];
    const float* ffn2_b = (const float*)d_in[27];
    const float* g1_w  = (const float*)d_in[28];
    const float* bn_g  = (const float*)d_in[29];
    const float* bn_b  = (const float*)d_in[30];
    const float* g2_w  = (const float*)d_in[31];
    const float* g2_b  = (const float*)d_in[32];

    char* base = (char*)d_ws;
    size_t off = 0;
    auto alloc = [&](size_t bytes) -> void* {
        void* p = base + off;
        off += (bytes + 255) & ~(size_t)255;
        return p;
    };

    u16*   qcam   = (u16*)  alloc((size_t)MTOT * CCn * 2 * 2);   // qcam|qsat contiguous
    u16*   qsat   = qcam + (size_t)MTOT * CCn;
    u16*   valb   = (u16*)  alloc((size_t)MTOT * CCn * 2 * 2);   // pair
    u16*   sampb  = (u16*)  alloc((size_t)MTOT * CCn * 2 * 2);   // pair (33.55MB)
    float* offb   = (float*)alloc((size_t)MTOT * 64 * 4 * 2);    // pair (16.78MB)
    float* attwb  = (float*)alloc((size_t)MTOT * 32 * 4 * 2);    // pair
    size_t padBytes = (size_t)BBn * PADW * PADW * 512 * 2;       // 34.6MB
    u16*   pad    = (u16*)  alloc(padBytes);
    u16*   hbuf   = (u16*)  alloc((size_t)MTOT * 128 * 2);
    u16*   wbase  = (u16*)  alloc((size_t)1212416 * 2);
    float* biasbf = (float*)alloc((size_t)2240 * 4);
    // weight slices
    u16* wvp = wbase;                 // pair, stride 65536
    u16* wop = wbase + 131072;        // pair, stride 65536
    u16* wf1 = wbase + 262144;
    u16* wf2 = wbase + 393216;
    u16* woa = wbase + 524288;        // pair, stride 32768
    u16* wcv = wbase + 589824;
    u16* wg2 = wbase + 1179648;
    // aliases (temporally disjoint)
    u16*   fused_bf = valb;              // valb dead after sampling
    float* convpart = (float*)sampb;     // sampb+offb dead after op-pair: 3x MTOT*128 f32 = 50.3MB
    u16*   midb     = qcam;              // qcam/qsat dead after op-pair (MTOT*512 bf16)

    dim3 blk(256);
    ZOff zz{0, 0, 0, 0, 0, 0, 0, 0, 0};

    zring_k<<<258, blk, 0, stream>>>(pad);
    tcvt_k<<<dim3(4, 256, 4), blk, 0, stream>>>(cam_bev, sat_bev, qcam, qsat);
    repack_all<<<4746, blk, 0, stream>>>(c2s_vp_w, c2s_op_w, s2c_vp_w, s2c_op_w,
                                         ffn1_w, ffn2_w, c2s_off_w, c2s_attw_w,
                                         s2c_off_w, s2c_attw_w, g1_w, g2_w,
                                         c2s_vp_b, s2c_vp_b, c2s_op_b, s2c_op_b,
                                         c2s_off_b, c2s_attw_b, s2c_off_b, s2c_attw_b,
                                         ln1_g, ln1_b, ln2_g, ln2_b,
                                         wbase, biasbf);

    // ---------- value projections (z=0: kv=sat, z=1: kv=cam) ----------
    {
        ZOff zo{ -(long)MTOT * CCn, 65536, 256, 0, 0, (long)MTOT * CCn, 0, 0, 0 };
        mgemm<128, 128, 2, 0, 256><<<dim3(2, 256, 2), blk, 0, stream>>>(
            qsat, wvp, biasbf, 256, 256,
            nullptr, nullptr, valb, nullptr, nullptr, nullptr, nullptr, 0, zo);
    }
    // ---------- offset+attw projections (z=0: q=cam, z=1: q=sat) ----------
    {
        ZOff zo{ (long)MTOT * CCn, 32768, 0, (long)MTOT * 64, (long)MTOT * 32, 0, 0, 96, 0 };
        mgemm<128, 128, 2, 2, 256><<<dim3(1, 256, 2), blk, 0, stream>>>(
            qcam, woa, nullptr, 256, 128,
            offb, attwb, nullptr, nullptr, nullptr, biasbf + 1024, biasbf + 1088, 0, zo);
    }
    // ---------- deformable sampling (both streams, 2-phase, block = 32 rh) ----
    sample_k<<<dim3(8192, 1, 2), blk, 0, stream>>>(valb, offb, attwb, sampb);
    // ---------- output projections + residual + LN -> pad image ----------
    {
        ZOff zo{ (long)MTOT * CCn, 65536, 256, 0, 0, 0, (long)MTOT * CCn, 512, 256 };
        mgemm<64, 256, 4, 7, 256><<<dim3(1, 512, 2), blk, 0, stream>>>(
            sampb, wop, biasbf + 512, 256, 256,
            nullptr, nullptr, pad, nullptr, qcam, biasbf + 1216, biasbf + 1472, 0, zo);
    }
    // ---------- gating conv: counted-vmcnt pipeline, split-K=3 ----------
    conv_k<3><<<dim3(1, 256, 3), blk, 0, stream>>>(pad, wcv, convpart);
    combine_k<<<4096, blk, 0, stream>>>(convpart, bn_g, bn_b, hbuf);

    // ---------- 1x1 conv + sigmoid + gated fusion (bf16 out only) ----------
    mgemm<128, 128, 2, 4, 128><<<dim3(2, 256, 1), blk, 0, stream>>>(
        hbuf, wg2, g2_b, 128, 256,
        nullptr, nullptr, fused_bf, pad, nullptr, nullptr, nullptr, 0, zz);

    // ---------- FFN ----------
    mgemm<128, 128, 2, 5, 256><<<dim3(4, 256, 1), blk, 0, stream>>>(
        fused_bf, wf1, ffn1_b, 256, 512,
        nullptr, nullptr, midb, nullptr, nullptr, nullptr, nullptr, 0, zz);
    // ffn2 + final LN + transpose to (B,C,N) + cam residual (EPI 9, bf16 resid)
    mgemm<64, 256, 4, 9, 512><<<dim3(1, 512, 1), blk, 0, stream>>>(
        midb, wf2, ffn2_b, 512, 256,
        (float*)d_out, (float*)cam_bev, nullptr, nullptr, fused_bf, lnf_g, lnf_b, 0, zz);
}